// Round 7
// baseline (1410.136 us; speedup 1.0000x reference)
//
#include <hip/hip_runtime.h>
#include <hip/hip_bf16.h>
#include <math.h>

// VNLayer: N=20000 nodes, E=240000 edges, H=256, SD=128, C=4, FEAT=480
// Round 7: cooperative LDS weight staging. Every K=32 step, the 256 threads
// stage the 16KB weight tile (256 cols x 32 k) global->reg->LDS with
// issue-early/write-late split; MFMA B-operands read from LDS (contiguous
// b128 pattern). Kills the per-wave serial L2 load chain that capped
// round 4-6 at ~554us / 11% MfmaUtil. Applied to k_edge and k_node.

#define FEAT 480
#define HDIM 256
#define SDIM 128
#define MSTR 264    // LDS A row stride (ushorts); 528B, 16B-aligned rows

// bf16 weight arena offsets (ushort elements)
#define OW1   0          // [256][416]
#define OW2   106496     // [256][256]
#define OVR1  172032
#define ORV1  237568
#define OVR2  303104     // [16][256]
#define ORV2  307200     // [16][256]
#define OFT1  311296
#define OFT2  376832
#define OF2T1 442368
#define OF2T2 507904     // [128][256]
#define OVF1  540672
#define OVF2  606208
#define OWTOT 671744

typedef __attribute__((ext_vector_type(8))) short bf16x8;
typedef __attribute__((ext_vector_type(4))) float f32x4;

__device__ __forceinline__ float silu_f(float x) {
    return x / (1.0f + __expf(-x));
}
__device__ __forceinline__ ushort f2b(float v) {
    __hip_bfloat16 h = __float2bfloat16(v);
    return *(ushort*)&h;
}
__device__ __forceinline__ float b2f(ushort u) {
    union { unsigned int i; float f; } c;
    c.i = ((unsigned int)u) << 16;
    return c.f;
}

// ---- weight tile staging: thread t handles 16B chunks j = t + 256*i ----
// source element (col = j>>2) * KT + ks*32 + (j&3)*8 ; LDS linear byte j*16.
#define STAGE_LD(GP, KT, KS, G)                                                \
    _Pragma("unroll")                                                          \
    for (int i_ = 0; i_ < 4; ++i_) {                                           \
        const int j_ = t + i_ * 256;                                           \
        G[i_] = *(const uint4*)&(GP)[(size_t)(j_ >> 2) * (KT) + (KS) * 32 + (j_ & 3) * 8]; \
    }

#define STAGE_ST(G)                                                            \
    _Pragma("unroll")                                                          \
    for (int i_ = 0; i_ < 4; ++i_) {                                           \
        *(uint4*)&WT[(t + i_ * 256) * 8] = G[i_];                              \
    }

// K=256 GEMM: A from LDS (SRC, stride MSTR), B staged through WT.
// Uses names: t, lr, lk, colBase, acc, WT.
#define KLOOP_ST(SRC, GP)                                                      \
    {                                                                          \
        uint4 g_[4];                                                           \
        STAGE_LD(GP, 256, 0, g_);                                              \
        _Pragma("unroll")                                                      \
        for (int mt = 0; mt < 2; ++mt)                                         \
            _Pragma("unroll")                                                  \
            for (int nt = 0; nt < 4; ++nt) acc[mt][nt] = (f32x4)0.f;           \
        STAGE_ST(g_);                                                          \
        __syncthreads();                                                       \
        _Pragma("unroll")                                                      \
        for (int ks = 0; ks < 8; ++ks) {                                       \
            uint4 gn_[4];                                                      \
            if (ks < 7) { STAGE_LD(GP, 256, ks + 1, gn_); }                    \
            const bf16x8 a0 = *(const bf16x8*)&(SRC)[lr * MSTR + ks * 32 + lk * 8];        \
            const bf16x8 a1 = *(const bf16x8*)&(SRC)[(lr + 16) * MSTR + ks * 32 + lk * 8]; \
            _Pragma("unroll")                                                  \
            for (int nt = 0; nt < 4; ++nt) {                                   \
                const int c_ = colBase + nt * 16 + lr;                         \
                const bf16x8 b = *(const bf16x8*)&WT[c_ * 32 + lk * 8];        \
                acc[0][nt] = __builtin_amdgcn_mfma_f32_16x16x32_bf16(a0, b, acc[0][nt], 0, 0, 0); \
                acc[1][nt] = __builtin_amdgcn_mfma_f32_16x16x32_bf16(a1, b, acc[1][nt], 0, 0, 0); \
            }                                                                  \
            __syncthreads();                                                   \
            if (ks < 7) { STAGE_ST(gn_); __syncthreads(); }                    \
        }                                                                      \
    }

// silu epilogue into an LDS bf16 matrix
#define EPI_SILU(DST, BIAS)                                                    \
    _Pragma("unroll")                                                          \
    for (int nt = 0; nt < 4; ++nt) {                                           \
        const int col = colBase + nt * 16 + lr;                                \
        const float bb = (BIAS)[col];                                          \
        _Pragma("unroll")                                                      \
        for (int mt = 0; mt < 2; ++mt)                                         \
            _Pragma("unroll")                                                  \
            for (int r = 0; r < 4; ++r) {                                      \
                const int row = mt * 16 + lk * 4 + r;                          \
                (DST)[row * MSTR + col] = f2b(silu_f(acc[mt][nt][r] + bb));    \
            }                                                                  \
    }

// ---------------------------------------------------------------- CSR build
__global__ __launch_bounds__(256) void k_count(
    const int* __restrict__ eidx, int* __restrict__ cnt_i, int E)
{
    const int e = blockIdx.x * 256 + threadIdx.x;
    if (e < E) atomicAdd(&cnt_i[eidx[e]], 1);
}

__global__ __launch_bounds__(1024) void k_scan(
    const int* __restrict__ cnt_i, int* __restrict__ rowstart,
    float* __restrict__ cntf, int Nn)
{
    __shared__ int sh[1024];
    __shared__ int carry_s;
    const int t = threadIdx.x;
    if (t == 0) carry_s = 0;
    __syncthreads();
    const int nch = (Nn + 1023) / 1024;
    for (int ch = 0; ch < nch; ++ch) {
        const int i = ch * 1024 + t;
        const int v = (i < Nn) ? cnt_i[i] : 0;
        sh[t] = v;
        __syncthreads();
        for (int off = 1; off < 1024; off <<= 1) {
            const int add = (t >= off) ? sh[t - off] : 0;
            __syncthreads();
            sh[t] += add;
            __syncthreads();
        }
        const int incl = sh[t];
        const int carry = carry_s;
        if (i < Nn) {
            rowstart[i + 1] = carry + incl;
            cntf[i] = fmaxf((float)v, 1.0f);
        }
        __syncthreads();
        if (t == 1023) carry_s = carry + incl;
        __syncthreads();
    }
    if (t == 0) rowstart[0] = 0;
}

__global__ __launch_bounds__(256) void k_place(
    const int* __restrict__ eidx, const int* __restrict__ rowstart,
    int* __restrict__ cursor, int* __restrict__ elist, int E)
{
    const int e = blockIdx.x * 256 + threadIdx.x;
    if (e < E) {
        const int r = eidx[e];
        const int p = atomicAdd(&cursor[r], 1);
        elist[rowstart[r] + p] = e;
    }
}

// ---------------------------------------------------------------- k_wprep
__global__ __launch_bounds__(256) void k_wprep(
    const float* __restrict__ w1, const float* __restrict__ w2,
    const float* __restrict__ vrw1, const float* __restrict__ rvw1,
    const float* __restrict__ vrw2, const float* __restrict__ rvw2,
    const float* __restrict__ ftw1, const float* __restrict__ ftw2,
    const float* __restrict__ f2tw1, const float* __restrict__ f2tw2,
    const float* __restrict__ vfw1, const float* __restrict__ vfw2,
    ushort* __restrict__ wb)
{
    const int idx = blockIdx.x * 256 + threadIdx.x;
    if (idx >= OWTOT) return;
    ushort v;
    if (idx < OW2) {
        const int n = idx / 416, k = idx % 416;
        v = (k < 400) ? f2b(w1[(size_t)k * 256 + n]) : (ushort)0;
    } else if (idx < OVR1) {
        const int o = idx - OW2;  v = f2b(w2[(size_t)(o & 255) * 256 + (o >> 8)]);
    } else if (idx < ORV1) {
        const int o = idx - OVR1; v = f2b(vrw1[(size_t)(o & 255) * 256 + (o >> 8)]);
    } else if (idx < OVR2) {
        const int o = idx - ORV1; v = f2b(rvw1[(size_t)(o & 255) * 256 + (o >> 8)]);
    } else if (idx < ORV2) {
        const int o = idx - OVR2; const int c = o >> 8, k = o & 255;
        v = (c < 4) ? f2b(vrw2[(size_t)k * 4 + c]) : (ushort)0;
    } else if (idx < OFT1) {
        const int o = idx - ORV2; v = f2b(rvw2[(size_t)(o & 255) * 16 + (o >> 8)]);
    } else if (idx < OFT2) {
        const int o = idx - OFT1; v = f2b(ftw1[(size_t)(o & 255) * 256 + (o >> 8)]);
    } else if (idx < OF2T1) {
        const int o = idx - OFT2; v = f2b(ftw2[(size_t)(o & 255) * 256 + (o >> 8)]);
    } else if (idx < OF2T2) {
        const int o = idx - OF2T1; v = f2b(f2tw1[(size_t)(o & 255) * 256 + (o >> 8)]);
    } else if (idx < OVF1) {
        const int o = idx - OF2T2; v = f2b(f2tw2[(size_t)(o & 255) * 128 + (o >> 8)]);
    } else if (idx < OVF2) {
        const int o = idx - OVF1; v = f2b(vfw1[(size_t)(o & 255) * 256 + (o >> 8)]);
    } else {
        const int o = idx - OVF2; v = f2b(vfw2[(size_t)(o & 255) * 256 + (o >> 8)]);
    }
    wb[idx] = v;
}

// ---------------------------------------------------------------- k_vnb
__global__ __launch_bounds__(256) void k_vnb(
    const float* __restrict__ vn_feat, ushort* __restrict__ vnb, int total4)
{
    const int i = blockIdx.x * 256 + threadIdx.x;
    if (i >= total4) return;
    const float4 v = *(const float4*)&vn_feat[(size_t)i * 4];
    ushort4 o;
    o.x = f2b(v.x); o.y = f2b(v.y); o.z = f2b(v.z); o.w = f2b(v.w);
    *(ushort4*)&vnb[(size_t)i * 4] = o;
}

// ---------------------------------------------------------------- k_nfs
__global__ __launch_bounds__(256) void k_nfs(
    const float* __restrict__ node_feat, const float* __restrict__ w_scalar,
    ushort* __restrict__ nfsb)
{
    __shared__ float At[32][20];
    __shared__ float Wt[16][128];
    const int t  = threadIdx.x;
    const int m0 = blockIdx.x * 32;
    const int c4 = (t & 31) * 4;
    const int rg = t >> 5;
    float acc[4][4] = {};
    for (int k0 = 0; k0 < 128; k0 += 16) {
        if (t < 128) {
            const int r = t >> 2, kk = (t & 3) * 4;
            *(float4*)&At[r][kk] =
                *(const float4*)&node_feat[(size_t)(m0 + r) * FEAT + k0 + kk];
        }
        #pragma unroll
        for (int i = 0; i < 2; ++i) {
            const int p  = t + i * 256;
            const int wr = p >> 5, wc = (p & 31) * 4;
            *(float4*)&Wt[wr][wc] =
                *(const float4*)&w_scalar[(size_t)(k0 + wr) * SDIM + wc];
        }
        __syncthreads();
        #pragma unroll
        for (int kk = 0; kk < 16; ++kk) {
            const float4 w = *(const float4*)&Wt[kk][c4];
            #pragma unroll
            for (int j = 0; j < 4; ++j) {
                const float a = At[rg * 4 + j][kk];
                acc[j][0] = fmaf(a, w.x, acc[j][0]);
                acc[j][1] = fmaf(a, w.y, acc[j][1]);
                acc[j][2] = fmaf(a, w.z, acc[j][2]);
                acc[j][3] = fmaf(a, w.w, acc[j][3]);
            }
        }
        __syncthreads();
    }
    const float s = 0.08838834764831845f;
    #pragma unroll
    for (int j = 0; j < 4; ++j) {
        ushort4 o;
        o.x = f2b(acc[j][0] * s); o.y = f2b(acc[j][1] * s);
        o.z = f2b(acc[j][2] * s); o.w = f2b(acc[j][3] * s);
        *(ushort4*)&nfsb[(size_t)(m0 + rg * 4 + j) * SDIM + c4] = o;
    }
}

// ---------------------------------------------------------------- k_edge
// 32 row-sorted edges/block, 256 threads = 4 waves. LDS = 52,992 B -> 3 blk/CU.
__global__ __launch_bounds__(256, 3) void k_edge(
    const ushort* __restrict__ nfsb, const ushort* __restrict__ vnb,
    const float* __restrict__ node_pos, const float* __restrict__ vn_pos,
    const int* __restrict__ eidx, const int* __restrict__ elist,
    const ushort* __restrict__ wb,
    const float* __restrict__ b1, const float* __restrict__ b2,
    const float* __restrict__ vrb1, const float* __restrict__ vrb2,
    const float* __restrict__ rvb1, const float* __restrict__ rvb2,
    float* __restrict__ agg_feat, float* __restrict__ agg_vr,
    float* __restrict__ agg_rv, int E)
{
    __shared__ ushort Mg[32 * MSTR];   // 16.9 KB msg; first 1KB doubles as ipB
    __shared__ ushort Hd[32 * MSTR];   // 16.9 KB hidden
    __shared__ ushort WT[8192];        // 16 KB weight tile (256 cols x 32 k)
    __shared__ float wvrS[32][4];
    __shared__ float wrvS[32][16];
    __shared__ int rowi[32], coli[32];

    const int t  = threadIdx.x;
    const int e0 = blockIdx.x * 32;
    const int wv = t >> 6;
    const int lane = t & 63;
    const int lr = lane & 15;
    const int lk = lane >> 4;
    const int colBase = wv * 64;
    ushort* ipB = Mg;                  // overlay: live only during cm1

    const ushort* w1t   = wb + OW1;

    float dnr[12];                     // per-edge dn, lives in t<32 registers

    // ---- geometry (t<32), row-sorted edges ----
    if (t < 32) {
        const int e = elist[e0 + t];
        const int r = eidx[e];
        const int c = eidx[E + e];
        rowi[t] = r; coli[t] = c;
        const float px = node_pos[r * 3 + 0];
        const float py = node_pos[r * 3 + 1];
        const float pz = node_pos[r * 3 + 2];
        float d[4][3];
        #pragma unroll
        for (int ch = 0; ch < 4; ++ch) {
            d[ch][0] = px - vn_pos[(size_t)c * 12 + ch * 3 + 0];
            d[ch][1] = py - vn_pos[(size_t)c * 12 + ch * 3 + 1];
            d[ch][2] = pz - vn_pos[(size_t)c * 12 + ch * 3 + 2];
        }
        float ss = 0.f, ipv[16];
        #pragma unroll
        for (int ci = 0; ci < 4; ++ci)
            #pragma unroll
            for (int ck = 0; ck < 4; ++ck) {
                const float v = d[ci][0]*d[ck][0] + d[ci][1]*d[ck][1] + d[ci][2]*d[ck][2];
                ipv[ci * 4 + ck] = v; ss += v * v;
            }
        const float inrm = 1.0f / fmaxf(sqrtf(ss), 1e-8f);
        #pragma unroll
        for (int i = 0; i < 16; ++i) ipB[t * 16 + i] = f2b(ipv[i] * inrm);
        #pragma unroll
        for (int ch = 0; ch < 4; ++ch) {
            const float nn = sqrtf(d[ch][0]*d[ch][0] + d[ch][1]*d[ch][1] + d[ch][2]*d[ch][2]);
            const float s = 1.0f / fmaxf(nn, 1e-8f);
            dnr[ch * 3 + 0] = d[ch][0] * s;
            dnr[ch * 3 + 1] = d[ch][1] * s;
            dnr[ch * 3 + 2] = d[ch][2] * s;
        }
    }
    __syncthreads();

    const ushort* nA0 = nfsb + (size_t)rowi[lr]      * SDIM + lk * 8;
    const ushort* nA1 = nfsb + (size_t)rowi[lr + 16] * SDIM + lk * 8;
    const ushort* vA0 = vnb  + (size_t)coli[lr]      * HDIM + lk * 8;
    const ushort* vA1 = vnb  + (size_t)coli[lr + 16] * HDIM + lk * 8;

#define CM1_A(KS, A0, A1)                                                      \
    if ((KS) < 4)       { A0 = *(const bf16x8*)(nA0 + (KS) * 32);              \
                          A1 = *(const bf16x8*)(nA1 + (KS) * 32); }            \
    else if ((KS) < 12) { A0 = *(const bf16x8*)(vA0 + (KS) * 32 - 128);        \
                          A1 = *(const bf16x8*)(vA1 + (KS) * 32 - 128); }      \
    else if (lk < 2)    { A0 = *(const bf16x8*)&ipB[lr * 16 + lk * 8];         \
                          A1 = *(const bf16x8*)&ipB[(lr + 16) * 16 + lk * 8]; }\
    else                { A0 = (bf16x8)(short)0; A1 = (bf16x8)(short)0; }

    f32x4 acc[2][4];

    // ===== cm layer 1 (K=416, 13 staged ks, A prefetched) =====
    {
        uint4 g_[4];
        STAGE_LD(w1t, 416, 0, g_);
        #pragma unroll
        for (int mt = 0; mt < 2; ++mt)
            #pragma unroll
            for (int nt = 0; nt < 4; ++nt) acc[mt][nt] = (f32x4)0.f;
        bf16x8 a0c, a1c;
        CM1_A(0, a0c, a1c);
        STAGE_ST(g_);
        __syncthreads();
        #pragma unroll
        for (int ks = 0; ks < 13; ++ks) {
            uint4 gn_[4];
            bf16x8 a0n, a1n;
            if (ks < 12) {
                STAGE_LD(w1t, 416, ks + 1, gn_);
                CM1_A(ks + 1, a0n, a1n);
            }
            #pragma unroll
            for (int nt = 0; nt < 4; ++nt) {
                const int c_ = colBase + nt * 16 + lr;
                const bf16x8 b = *(const bf16x8*)&WT[c_ * 32 + lk * 8];
                acc[0][nt] = __builtin_amdgcn_mfma_f32_16x16x32_bf16(a0c, b, acc[0][nt], 0, 0, 0);
                acc[1][nt] = __builtin_amdgcn_mfma_f32_16x16x32_bf16(a1c, b, acc[1][nt], 0, 0, 0);
            }
            __syncthreads();
            if (ks < 12) {
                STAGE_ST(gn_);
                __syncthreads();
                a0c = a0n; a1c = a1n;
            }
        }
    }
    EPI_SILU(Hd, b1);
    __syncthreads();

    // ===== cm layer 2 -> msg =====
    KLOOP_ST(Hd, wb + OW2);
    #pragma unroll
    for (int nt = 0; nt < 4; ++nt) {
        const int col = colBase + nt * 16 + lr;
        const float bb = b2[col];
        #pragma unroll
        for (int mt = 0; mt < 2; ++mt)
            #pragma unroll
            for (int r = 0; r < 4; ++r) {
                const int row = mt * 16 + lk * 4 + r;
                Mg[row * MSTR + col] = f2b(acc[mt][nt][r] + bb);
            }
    }
    __syncthreads();

    // ===== segmented reduction msg -> agg_feat (thread t = column t) =====
    {
        float s = 0.f;
        int prev = rowi[0];
        for (int r = 0; r < 32; ++r) {
            const int rr = rowi[r];
            if (rr != prev) {
                atomicAdd(&agg_feat[(size_t)prev * HDIM + t], s);
                s = 0.f; prev = rr;
            }
            s += b2f(Mg[r * MSTR + t]);
        }
        atomicAdd(&agg_feat[(size_t)prev * HDIM + t], s);
    }

    // ===== vr layer 1 =====
    KLOOP_ST(Mg, wb + OVR1);
    EPI_SILU(Hd, vrb1);
    __syncthreads();

    // ===== vr layer 2 (wave 0, N=4 padded to 16) =====
    if (wv == 0) {
        const ushort* vrw2t = wb + OVR2;
        f32x4 a2[2]; a2[0] = (f32x4)0.f; a2[1] = (f32x4)0.f;
        #pragma unroll
        for (int ks = 0; ks < 8; ++ks) {
            const bf16x8 a0 = *(const bf16x8*)&Hd[lr * MSTR + ks * 32 + lk * 8];
            const bf16x8 a1 = *(const bf16x8*)&Hd[(lr + 16) * MSTR + ks * 32 + lk * 8];
            const bf16x8 b  = *(const bf16x8*)&vrw2t[(size_t)lr * 256 + ks * 32 + lk * 8];
            a2[0] = __builtin_amdgcn_mfma_f32_16x16x32_bf16(a0, b, a2[0], 0, 0, 0);
            a2[1] = __builtin_amdgcn_mfma_f32_16x16x32_bf16(a1, b, a2[1], 0, 0, 0);
        }
        if (lr < 4) {
            const float bb = vrb2[lr];
            #pragma unroll
            for (int mt = 0; mt < 2; ++mt)
                #pragma unroll
                for (int r = 0; r < 4; ++r)
                    wvrS[mt * 16 + lk * 4 + r][lr] = a2[mt][r] + bb;
        }
    }
    __syncthreads();

    // ===== rv layer 1 =====
    KLOOP_ST(Mg, wb + ORV1);
    EPI_SILU(Hd, rvb1);
    __syncthreads();

    // ===== rv layer 2 (wave 0, N=16) =====
    if (wv == 0) {
        const ushort* rvw2t = wb + ORV2;
        f32x4 a2[2]; a2[0] = (f32x4)0.f; a2[1] = (f32x4)0.f;
        #pragma unroll
        for (int ks = 0; ks < 8; ++ks) {
            const bf16x8 a0 = *(const bf16x8*)&Hd[lr * MSTR + ks * 32 + lk * 8];
            const bf16x8 a1 = *(const bf16x8*)&Hd[(lr + 16) * MSTR + ks * 32 + lk * 8];
            const bf16x8 b  = *(const bf16x8*)&rvw2t[(size_t)lr * 256 + ks * 32 + lk * 8];
            a2[0] = __builtin_amdgcn_mfma_f32_16x16x32_bf16(a0, b, a2[0], 0, 0, 0);
            a2[1] = __builtin_amdgcn_mfma_f32_16x16x32_bf16(a1, b, a2[1], 0, 0, 0);
        }
        const float bb = rvb2[lr];
        #pragma unroll
        for (int mt = 0; mt < 2; ++mt)
            #pragma unroll
            for (int r = 0; r < 4; ++r)
                wrvS[mt * 16 + lk * 4 + r][lr] = a2[mt][r] + bb;
    }
    __syncthreads();

    // ===== per-edge geometric update (t<32, dn in registers) =====
    if (t < 32) {
        float wvv[4], wrr[16], ev[15];
        #pragma unroll
        for (int c = 0; c < 4; ++c)  wvv[c] = wvrS[t][c];
        #pragma unroll
        for (int i = 0; i < 16; ++i) wrr[i] = wrvS[t][i];
        #pragma unroll
        for (int j = 0; j < 3; ++j) {
            float v = 0.f;
            #pragma unroll
            for (int c = 0; c < 4; ++c) v = fmaf(wvv[c], dnr[c * 3 + j], v);
            ev[j] = 0.5f * v;
        }
        #pragma unroll
        for (int u = 0; u < 4; ++u)
            #pragma unroll
            for (int j = 0; j < 3; ++j) {
                float v = 0.f;
                #pragma unroll
                for (int c = 0; c < 4; ++c) v = fmaf(wrr[c * 4 + u], dnr[c * 3 + j], v);
                ev[3 + u * 3 + j] = -0.5f * v;
            }
        #pragma unroll
        for (int i = 0; i < 15; ++i) wrvS[t][i] = ev[i];
    }
    __syncthreads();

    // ===== segmented reduction vr/rv (t<15) =====
    if (t < 15) {
        float s = 0.f;
        int prev = rowi[0];
        for (int r = 0; r < 32; ++r) {
            const int rr = rowi[r];
            if (rr != prev) {
                if (t < 3) atomicAdd(&agg_vr[(size_t)prev * 3 + t], s);
                else       atomicAdd(&agg_rv[(size_t)prev * 12 + (t - 3)], s);
                s = 0.f; prev = rr;
            }
            s += wrvS[r][t];
        }
        if (t < 3) atomicAdd(&agg_vr[(size_t)prev * 3 + t], s);
        else       atomicAdd(&agg_rv[(size_t)prev * 12 + (t - 3)], s);
    }
#undef CM1_A
}

// ---------------------------------------------------------------- k_node
// 32 nodes/block (625 blocks), 256 threads = 4 waves, staged weights.
__global__ __launch_bounds__(256, 3) void k_node(
    const float* __restrict__ node_feat, const float* __restrict__ node_pos,
    const float* __restrict__ vn_feat, const float* __restrict__ vn_pos,
    const float* __restrict__ agg_feat, const float* __restrict__ agg_vr,
    const float* __restrict__ agg_rv, const float* __restrict__ cntf,
    const ushort* __restrict__ wb,
    const float* __restrict__ ftb1, const float* __restrict__ ftb2,
    const float* __restrict__ f2tb1, const float* __restrict__ f2tb2,
    const float* __restrict__ vfb1, const float* __restrict__ vfb2,
    float* __restrict__ out, int Nn)
{
    __shared__ ushort Ab[32 * MSTR];
    __shared__ ushort Hd[32 * MSTR];
    __shared__ ushort WT[8192];
    __shared__ float rc[32];
    const int t  = threadIdx.x;
    const int n0 = blockIdx.x * 32;
    const int wv = t >> 6;
    const int lane = t & 63;
    const int lr = lane & 15;
    const int lk = lane >> 4;
    const int colBase = wv * 64;

    float* nf_out = out;
    float* np_out = out + (size_t)Nn * FEAT;
    float* vf_out = np_out + (size_t)Nn * 3;
    float* vp_out = vf_out + (size_t)Nn * HDIM;

    if (t < 32) rc[t] = 1.0f / fmaxf(cntf[n0 + t], 1.0f);
    __syncthreads();
    #pragma unroll
    for (int i = 0; i < 8; ++i) {
        const int p = t + i * 256;
        const int r = p >> 6, cc = (p & 63) * 4;
        float4 v = *(const float4*)&agg_feat[(size_t)(n0 + r) * HDIM + cc];
        const float s = rc[r];
        ushort4 o;
        o.x = f2b(v.x * s); o.y = f2b(v.y * s);
        o.z = f2b(v.z * s); o.w = f2b(v.w * s);
        *(ushort4*)&Ab[r * MSTR + cc] = o;
    }
    __syncthreads();

    f32x4 acc[2][4];

    // ---- vf MLP ----
    KLOOP_ST(Ab, wb + OVF1);
    EPI_SILU(Hd, vfb1);
    __syncthreads();
    KLOOP_ST(Hd, wb + OVF2);
    #pragma unroll
    for (int nt = 0; nt < 4; ++nt) {
        const int col = colBase + nt * 16 + lr;
        const float bb = vfb2[col];
        #pragma unroll
        for (int mt = 0; mt < 2; ++mt)
            #pragma unroll
            for (int r = 0; r < 4; ++r) {
                const int row = mt * 16 + lk * 4 + r;
                const size_t o = (size_t)(n0 + row) * HDIM + col;
                vf_out[o] = vn_feat[o] + acc[mt][nt][r] + bb;
            }
    }
    __syncthreads();

    // ---- ft MLP ----
    KLOOP_ST(Ab, wb + OFT1);
    EPI_SILU(Hd, ftb1);
    __syncthreads();
    KLOOP_ST(Hd, wb + OFT2);
    #pragma unroll
    for (int nt = 0; nt < 4; ++nt) {               // x2 -> Ab (bf16)
        const int col = colBase + nt * 16 + lr;
        const float bb = ftb2[col];
        #pragma unroll
        for (int mt = 0; mt < 2; ++mt)
            #pragma unroll
            for (int r = 0; r < 4; ++r) {
                const int row = mt * 16 + lk * 4 + r;
                Ab[row * MSTR + col] = f2b(acc[mt][nt][r] + bb);
            }
    }
    __syncthreads();

    // ---- f2t MLP ----
    KLOOP_ST(Ab, wb + OF2T1);
    EPI_SILU(Hd, f2tb1);
    __syncthreads();
    {   // layer 2, N=128: 4 waves x 32 cols, B direct (8KB, L2-hot)
        const ushort* w2p = wb + OF2T2;
        const int colB2 = wv * 32;
        f32x4 a2[2][2];
        #pragma unroll
        for (int mt = 0; mt < 2; ++mt)
            #pragma unroll
            for (int nt = 0; nt < 2; ++nt) a2[mt][nt] = (f32x4)0.f;
        #pragma unroll
        for (int ks = 0; ks < 8; ++ks) {
            const int k0 = ks * 32 + lk * 8;
            const bf16x8 a0 = *(const bf16x8*)&Hd[lr * MSTR + k0];
            const bf16x8 a1 = *(const bf16x8*)&Hd[(lr + 16) * MSTR + k0];
            const bf16x8 w0 = *(const bf16x8*)&w2p[(size_t)(colB2 + lr) * 256 + k0];
            const bf16x8 w1v = *(const bf16x8*)&w2p[(size_t)(colB2 + 16 + lr) * 256 + k0];
            a2[0][0] = __builtin_amdgcn_mfma_f32_16x16x32_bf16(a0, w0, a2[0][0], 0, 0, 0);
            a2[1][0] = __builtin_amdgcn_mfma_f32_16x16x32_bf16(a1, w0, a2[1][0], 0, 0, 0);
            a2[0][1] = __builtin_amdgcn_mfma_f32_16x16x32_bf16(a0, w1v, a2[0][1], 0, 0, 0);
            a2[1][1] = __builtin_amdgcn_mfma_f32_16x16x32_bf16(a1, w1v, a2[1][1], 0, 0, 0);
        }
        #pragma unroll
        for (int nt = 0; nt < 2; ++nt) {
            const int col = colB2 + nt * 16 + lr;
            const float bb = f2tb2[col];
            #pragma unroll
            for (int mt = 0; mt < 2; ++mt)
                #pragma unroll
                for (int r = 0; r < 4; ++r) {
                    const int row = mt * 16 + lk * 4 + r;
                    const size_t o = (size_t)(n0 + row) * FEAT + col;
                    nf_out[o] = node_feat[o] + a2[mt][nt][r] + bb;
                }
        }
    }

    // passthrough cols 128..479
    for (int p = t; p < 32 * 88; p += 256) {
        const int r = p / 88;
        const int cc = 128 + (p % 88) * 4;
        const size_t o = (size_t)(n0 + r) * FEAT + cc;
        *(float4*)&nf_out[o] = *(const float4*)&node_feat[o];
    }
    if (t < 32) {
        const int n = n0 + t;
        const float s = rc[t];
        #pragma unroll
        for (int j = 0; j < 3; ++j)
            np_out[(size_t)n * 3 + j] = node_pos[(size_t)n * 3 + j] + agg_vr[(size_t)n * 3 + j] * s;
        #pragma unroll
        for (int j = 0; j < 12; ++j)
            vp_out[(size_t)n * 12 + j] = vn_pos[(size_t)n * 12 + j] + agg_rv[(size_t)n * 12 + j] * s;
    }
}

// ---------------------------------------------------------------- launch
extern "C" void kernel_launch(void* const* d_in, const int* in_sizes, int n_in,
                              void* d_out, int out_size, void* d_ws, size_t ws_size,
                              hipStream_t stream)
{
    (void)n_in; (void)out_size; (void)ws_size;
    const float* node_feat = (const float*)d_in[0];
    const float* node_pos  = (const float*)d_in[1];
    const float* vn_feat   = (const float*)d_in[2];
    const float* vn_pos    = (const float*)d_in[3];
    const int*   eidx      = (const int*)d_in[4];
    const float* w_scalar  = (const float*)d_in[5];
    const float* cm_w1  = (const float*)d_in[6];
    const float* cm_b1  = (const float*)d_in[7];
    const float* cm_w2  = (const float*)d_in[8];
    const float* cm_b2  = (const float*)d_in[9];
    const float* vr_w1  = (const float*)d_in[10];
    const float* vr_b1  = (const float*)d_in[11];
    const float* vr_w2  = (const float*)d_in[12];
    const float* vr_b2  = (const float*)d_in[13];
    const float* rv_w1  = (const float*)d_in[14];
    const float* rv_b1  = (const float*)d_in[15];
    const float* rv_w2  = (const float*)d_in[16];
    const float* rv_b2  = (const float*)d_in[17];
    const float* ft_w1  = (const float*)d_in[18];
    const float* ft_b1  = (const float*)d_in[19];
    const float* ft_w2  = (const float*)d_in[20];
    const float* ft_b2  = (const float*)d_in[21];
    const float* f2t_w1 = (const float*)d_in[22];
    const float* f2t_b1 = (const float*)d_in[23];
    const float* f2t_w2 = (const float*)d_in[24];
    const float* f2t_b2 = (const float*)d_in[25];
    const float* vf_w1  = (const float*)d_in[26];
    const float* vf_b1  = (const float*)d_in[27];
    const float* vf_w2  = (const float*)d_in[28];
    const float* vf_b2  = (const float*)d_in[29];

    const int Nn = in_sizes[0] / FEAT;        // 20000
    const int E  = in_sizes[4] / 2;           // 240000

    // workspace layout
    float* ws       = (float*)d_ws;
    float* agg_feat = ws;                                // Nn*256 (zeroed)
    float* agg_vr   = agg_feat + (size_t)Nn * HDIM;      // Nn*3   (zeroed)
    float* agg_rv   = agg_vr   + (size_t)Nn * 3;         // Nn*12  (zeroed)
    float* cntf     = agg_rv   + (size_t)Nn * 12;        // Nn     (zeroed)
    int*   cnt_i    = (int*)(cntf + Nn);                 // Nn     (zeroed)
    int*   cursor   = cnt_i + Nn;                        // Nn     (zeroed)
    int*   rowstart = cursor + Nn;                       // Nn+16
    int*   elist    = rowstart + Nn + 16;                // E
    ushort* nfsb = (ushort*)(elist + E);                 // Nn*128
    ushort* vnb  = nfsb + (size_t)Nn * SDIM;             // Nn*256
    ushort* wb   = vnb  + (size_t)Nn * HDIM;             // OWTOT

    const size_t zero_bytes = (size_t)Nn * (HDIM + 3 + 12 + 1 + 2) * sizeof(float);
    hipMemsetAsync(agg_feat, 0, zero_bytes, stream);

    const int eg = (E + 255) / 256;
    k_count<<<eg, 256, 0, stream>>>(eidx, cnt_i, E);
    k_scan<<<1, 1024, 0, stream>>>(cnt_i, rowstart, cntf, Nn);
    k_place<<<eg, 256, 0, stream>>>(eidx, rowstart, cursor, elist, E);
    k_wprep<<<(OWTOT + 255) / 256, 256, 0, stream>>>(
        cm_w1, cm_w2, vr_w1, rv_w1, vr_w2, rv_w2,
        ft_w1, ft_w2, f2t_w1, f2t_w2, vf_w1, vf_w2, wb);
    k_vnb<<<(Nn * 64 + 255) / 256, 256, 0, stream>>>(vn_feat, vnb, Nn * 64);
    k_nfs<<<Nn / 32, 256, 0, stream>>>(node_feat, w_scalar, nfsb);
    k_edge<<<E / 32, 256, 0, stream>>>(nfsb, vnb, node_pos, vn_pos, eidx, elist,
                                       wb, cm_b1, cm_b2, vr_b1, vr_b2, rv_b1, rv_b2,
                                       agg_feat, agg_vr, agg_rv, E);
    k_node<<<Nn / 32, 256, 0, stream>>>(node_feat, node_pos, vn_feat, vn_pos,
                                        agg_feat, agg_vr, agg_rv, cntf, wb,
                                        ft_b1, ft_b2, f2t_b1, f2t_b2, vf_b1, vf_b2,
                                        (float*)d_out, Nn);
}

// Round 8
// 515.756 us; speedup vs baseline: 2.7341x; 2.7341x over previous
//
#include <hip/hip_runtime.h>
#include <hip/hip_bf16.h>
#include <math.h>

// VNLayer: N=20000 nodes, E=240000 edges, H=256, SD=128, C=4, FEAT=480
// Round 8: revert to round-6 structure (round 7 spilled to scratch and
// regressed). Single change vs round 6: weights repacked in MFMA-FRAGMENT
// order [n-tile][k-step][lane][16B] so every B load is ONE contiguous,
// coalesced 1KiB read (base + lane*16) instead of a 16-line strided gather.
// Per-lane fragment contents identical to round 6 -> same numerics.

#define FEAT 480
#define HDIM 256
#define SDIM 128
#define MSTR 264    // LDS A row stride (ushorts)

// bf16 weight arena offsets (ushort elements) -- frag-packed regions
#define OW1   0          // cm1 : 16 nt x 13 ks x 512
#define OW2   106496     // cm2 : 16 x 8 x 512
#define OVR1  172032
#define ORV1  237568
#define OVR2  303104     // vr2 : 1 x 8 x 512 (cols>=4 zero)
#define ORV2  307200     // rv2 : 1 x 8 x 512
#define OFT1  311296
#define OFT2  376832
#define OF2T1 442368
#define OF2T2 507904     // f2t2: 8 nt x 8 ks x 512
#define OVF1  540672
#define OVF2  606208
#define OWTOT 671744

typedef __attribute__((ext_vector_type(8))) short bf16x8;
typedef __attribute__((ext_vector_type(4))) float f32x4;

__device__ __forceinline__ float silu_f(float x) {
    return x / (1.0f + __expf(-x));
}
__device__ __forceinline__ ushort f2b(float v) {
    __hip_bfloat16 h = __float2bfloat16(v);
    return *(ushort*)&h;
}
__device__ __forceinline__ float b2f(ushort u) {
    union { unsigned int i; float f; } c;
    c.i = ((unsigned int)u) << 16;
    return c.f;
}

// K=256 GEMM: A from LDS (stride MSTR), B frag-packed (coalesced 1KB loads).
// Uses names: lane, lr, lk, wv, acc.
#define KLOOP_FR(SRC, WP)                                                      \
    {                                                                          \
        _Pragma("unroll")                                                      \
        for (int mt = 0; mt < 2; ++mt)                                         \
            _Pragma("unroll")                                                  \
            for (int nt = 0; nt < 4; ++nt) acc[mt][nt] = (f32x4)0.f;           \
        _Pragma("unroll")                                                      \
        for (int ks = 0; ks < 8; ++ks) {                                       \
            const bf16x8 a0 = *(const bf16x8*)&(SRC)[lr * MSTR + ks * 32 + lk * 8];        \
            const bf16x8 a1 = *(const bf16x8*)&(SRC)[(lr + 16) * MSTR + ks * 32 + lk * 8]; \
            _Pragma("unroll")                                                  \
            for (int nt = 0; nt < 4; ++nt) {                                   \
                const bf16x8 b = *(const bf16x8*)&(WP)[(size_t)(((wv * 4 + nt) * 8 + ks) * 512) + lane * 8]; \
                acc[0][nt] = __builtin_amdgcn_mfma_f32_16x16x32_bf16(a0, b, acc[0][nt], 0, 0, 0); \
                acc[1][nt] = __builtin_amdgcn_mfma_f32_16x16x32_bf16(a1, b, acc[1][nt], 0, 0, 0); \
            }                                                                  \
        }                                                                      \
    }

// silu epilogue into an LDS bf16 matrix
#define EPI_SILU(DST, BIAS)                                                    \
    _Pragma("unroll")                                                          \
    for (int nt = 0; nt < 4; ++nt) {                                           \
        const int col = colBase + nt * 16 + lr;                                \
        const float bb = (BIAS)[col];                                          \
        _Pragma("unroll")                                                      \
        for (int mt = 0; mt < 2; ++mt)                                         \
            _Pragma("unroll")                                                  \
            for (int r = 0; r < 4; ++r) {                                      \
                const int row = mt * 16 + lk * 4 + r;                          \
                (DST)[row * MSTR + col] = f2b(silu_f(acc[mt][nt][r] + bb));    \
            }                                                                  \
    }

// ---------------------------------------------------------------- CSR build
__global__ __launch_bounds__(256) void k_count(
    const int* __restrict__ eidx, int* __restrict__ cnt_i, int E)
{
    const int e = blockIdx.x * 256 + threadIdx.x;
    if (e < E) atomicAdd(&cnt_i[eidx[e]], 1);
}

__global__ __launch_bounds__(1024) void k_scan(
    const int* __restrict__ cnt_i, int* __restrict__ rowstart,
    float* __restrict__ cntf, int Nn)
{
    __shared__ int sh[1024];
    __shared__ int carry_s;
    const int t = threadIdx.x;
    if (t == 0) carry_s = 0;
    __syncthreads();
    const int nch = (Nn + 1023) / 1024;
    for (int ch = 0; ch < nch; ++ch) {
        const int i = ch * 1024 + t;
        const int v = (i < Nn) ? cnt_i[i] : 0;
        sh[t] = v;
        __syncthreads();
        for (int off = 1; off < 1024; off <<= 1) {
            const int add = (t >= off) ? sh[t - off] : 0;
            __syncthreads();
            sh[t] += add;
            __syncthreads();
        }
        const int incl = sh[t];
        const int carry = carry_s;
        if (i < Nn) {
            rowstart[i + 1] = carry + incl;
            cntf[i] = fmaxf((float)v, 1.0f);
        }
        __syncthreads();
        if (t == 1023) carry_s = carry + incl;
        __syncthreads();
    }
    if (t == 0) rowstart[0] = 0;
}

__global__ __launch_bounds__(256) void k_place(
    const int* __restrict__ eidx, const int* __restrict__ rowstart,
    int* __restrict__ cursor, int* __restrict__ elist, int E)
{
    const int e = blockIdx.x * 256 + threadIdx.x;
    if (e < E) {
        const int r = eidx[e];
        const int p = atomicAdd(&cursor[r], 1);
        elist[rowstart[r] + p] = e;
    }
}

// ---------------------------------------------------------------- k_wprep
// Frag-packed bf16 weights: region offset o -> f=o>>9 (frag), l=(o>>3)&63
// (lane), e=o&7 (elem). For 256-col GEMMs: nt=f/ksTot, ks=f%ksTot,
// col=nt*16+(l&15), k=ks*32+(l>>4)*8+e; value = w[k][col].
__global__ __launch_bounds__(256) void k_wprep(
    const float* __restrict__ w1, const float* __restrict__ w2,
    const float* __restrict__ vrw1, const float* __restrict__ rvw1,
    const float* __restrict__ vrw2, const float* __restrict__ rvw2,
    const float* __restrict__ ftw1, const float* __restrict__ ftw2,
    const float* __restrict__ f2tw1, const float* __restrict__ f2tw2,
    const float* __restrict__ vfw1, const float* __restrict__ vfw2,
    ushort* __restrict__ wb)
{
    const int idx = blockIdx.x * 256 + threadIdx.x;
    if (idx >= OWTOT) return;
    ushort v;
    if (idx < OW2) {                      // cm1: ksTot=13, k<400 else pad 0
        const int o = idx, f = o >> 9, l = (o >> 3) & 63, e = o & 7;
        const int nt = f / 13, ks = f % 13;
        const int col = nt * 16 + (l & 15);
        const int k = ks * 32 + ((l >> 4) << 3) + e;
        v = (k < 400) ? f2b(w1[(size_t)k * 256 + col]) : (ushort)0;
    } else if (idx < OVR1) {              // cm2
        const int o = idx - OW2, f = o >> 9, l = (o >> 3) & 63, e = o & 7;
        const int col = (f >> 3) * 16 + (l & 15);
        const int k = (f & 7) * 32 + ((l >> 4) << 3) + e;
        v = f2b(w2[(size_t)k * 256 + col]);
    } else if (idx < ORV1) {              // vr1
        const int o = idx - OVR1, f = o >> 9, l = (o >> 3) & 63, e = o & 7;
        const int col = (f >> 3) * 16 + (l & 15);
        const int k = (f & 7) * 32 + ((l >> 4) << 3) + e;
        v = f2b(vrw1[(size_t)k * 256 + col]);
    } else if (idx < OVR2) {              // rv1
        const int o = idx - ORV1, f = o >> 9, l = (o >> 3) & 63, e = o & 7;
        const int col = (f >> 3) * 16 + (l & 15);
        const int k = (f & 7) * 32 + ((l >> 4) << 3) + e;
        v = f2b(rvw1[(size_t)k * 256 + col]);
    } else if (idx < ORV2) {              // vr2: 1 nt, cols>=4 zero
        const int o = idx - OVR2, f = o >> 9, l = (o >> 3) & 63, e = o & 7;
        const int col = l & 15;
        const int k = f * 32 + ((l >> 4) << 3) + e;
        v = (col < 4) ? f2b(vrw2[(size_t)k * 4 + col]) : (ushort)0;
    } else if (idx < OFT1) {              // rv2: 1 nt, 16 cols
        const int o = idx - ORV2, f = o >> 9, l = (o >> 3) & 63, e = o & 7;
        const int col = l & 15;
        const int k = f * 32 + ((l >> 4) << 3) + e;
        v = f2b(rvw2[(size_t)k * 16 + col]);
    } else if (idx < OFT2) {              // ft1
        const int o = idx - OFT1, f = o >> 9, l = (o >> 3) & 63, e = o & 7;
        const int col = (f >> 3) * 16 + (l & 15);
        const int k = (f & 7) * 32 + ((l >> 4) << 3) + e;
        v = f2b(ftw1[(size_t)k * 256 + col]);
    } else if (idx < OF2T1) {             // ft2
        const int o = idx - OFT2, f = o >> 9, l = (o >> 3) & 63, e = o & 7;
        const int col = (f >> 3) * 16 + (l & 15);
        const int k = (f & 7) * 32 + ((l >> 4) << 3) + e;
        v = f2b(ftw2[(size_t)k * 256 + col]);
    } else if (idx < OF2T2) {             // f2t1
        const int o = idx - OF2T1, f = o >> 9, l = (o >> 3) & 63, e = o & 7;
        const int col = (f >> 3) * 16 + (l & 15);
        const int k = (f & 7) * 32 + ((l >> 4) << 3) + e;
        v = f2b(f2tw1[(size_t)k * 256 + col]);
    } else if (idx < OVF1) {              // f2t2: 8 nt, 128 cols
        const int o = idx - OF2T2, f = o >> 9, l = (o >> 3) & 63, e = o & 7;
        const int col = (f >> 3) * 16 + (l & 15);
        const int k = (f & 7) * 32 + ((l >> 4) << 3) + e;
        v = f2b(f2tw2[(size_t)k * 128 + col]);
    } else if (idx < OVF2) {              // vf1
        const int o = idx - OVF1, f = o >> 9, l = (o >> 3) & 63, e = o & 7;
        const int col = (f >> 3) * 16 + (l & 15);
        const int k = (f & 7) * 32 + ((l >> 4) << 3) + e;
        v = f2b(vfw1[(size_t)k * 256 + col]);
    } else {                              // vf2
        const int o = idx - OVF2, f = o >> 9, l = (o >> 3) & 63, e = o & 7;
        const int col = (f >> 3) * 16 + (l & 15);
        const int k = (f & 7) * 32 + ((l >> 4) << 3) + e;
        v = f2b(vfw2[(size_t)k * 256 + col]);
    }
    wb[idx] = v;
}

// ---------------------------------------------------------------- k_vnb
__global__ __launch_bounds__(256) void k_vnb(
    const float* __restrict__ vn_feat, ushort* __restrict__ vnb, int total4)
{
    const int i = blockIdx.x * 256 + threadIdx.x;
    if (i >= total4) return;
    const float4 v = *(const float4*)&vn_feat[(size_t)i * 4];
    ushort4 o;
    o.x = f2b(v.x); o.y = f2b(v.y); o.z = f2b(v.z); o.w = f2b(v.w);
    *(ushort4*)&vnb[(size_t)i * 4] = o;
}

// ---------------------------------------------------------------- k_nfs
__global__ __launch_bounds__(256) void k_nfs(
    const float* __restrict__ node_feat, const float* __restrict__ w_scalar,
    ushort* __restrict__ nfsb)
{
    __shared__ float At[32][20];
    __shared__ float Wt[16][128];
    const int t  = threadIdx.x;
    const int m0 = blockIdx.x * 32;
    const int c4 = (t & 31) * 4;
    const int rg = t >> 5;
    float acc[4][4] = {};
    for (int k0 = 0; k0 < 128; k0 += 16) {
        if (t < 128) {
            const int r = t >> 2, kk = (t & 3) * 4;
            *(float4*)&At[r][kk] =
                *(const float4*)&node_feat[(size_t)(m0 + r) * FEAT + k0 + kk];
        }
        #pragma unroll
        for (int i = 0; i < 2; ++i) {
            const int p  = t + i * 256;
            const int wr = p >> 5, wc = (p & 31) * 4;
            *(float4*)&Wt[wr][wc] =
                *(const float4*)&w_scalar[(size_t)(k0 + wr) * SDIM + wc];
        }
        __syncthreads();
        #pragma unroll
        for (int kk = 0; kk < 16; ++kk) {
            const float4 w = *(const float4*)&Wt[kk][c4];
            #pragma unroll
            for (int j = 0; j < 4; ++j) {
                const float a = At[rg * 4 + j][kk];
                acc[j][0] = fmaf(a, w.x, acc[j][0]);
                acc[j][1] = fmaf(a, w.y, acc[j][1]);
                acc[j][2] = fmaf(a, w.z, acc[j][2]);
                acc[j][3] = fmaf(a, w.w, acc[j][3]);
            }
        }
        __syncthreads();
    }
    const float s = 0.08838834764831845f;
    #pragma unroll
    for (int j = 0; j < 4; ++j) {
        ushort4 o;
        o.x = f2b(acc[j][0] * s); o.y = f2b(acc[j][1] * s);
        o.z = f2b(acc[j][2] * s); o.w = f2b(acc[j][3] * s);
        *(ushort4*)&nfsb[(size_t)(m0 + rg * 4 + j) * SDIM + c4] = o;
    }
}

// ---------------------------------------------------------------- k_edge
// 32 row-sorted edges/block, 256 threads = 4 waves. LDS 39.4KB -> 4 blk/CU.
__global__ __launch_bounds__(256, 4) void k_edge(
    const ushort* __restrict__ nfsb, const ushort* __restrict__ vnb,
    const float* __restrict__ node_pos, const float* __restrict__ vn_pos,
    const int* __restrict__ eidx, const int* __restrict__ elist,
    const ushort* __restrict__ wb,
    const float* __restrict__ b1, const float* __restrict__ b2,
    const float* __restrict__ vrb1, const float* __restrict__ vrb2,
    const float* __restrict__ rvb1, const float* __restrict__ rvb2,
    float* __restrict__ agg_feat, float* __restrict__ agg_vr,
    float* __restrict__ agg_rv, int E)
{
    __shared__ ushort Mg[32 * MSTR];
    __shared__ ushort Hd[32 * MSTR];
    __shared__ ushort ipB[32 * 16];
    __shared__ float dnS[32][12];
    __shared__ float wvrS[32][4];
    __shared__ float wrvS[32][16];
    __shared__ int rowi[32], coli[32];

    const int t  = threadIdx.x;
    const int e0 = blockIdx.x * 32;
    const int wv = t >> 6;
    const int lane = t & 63;
    const int lr = lane & 15;
    const int lk = lane >> 4;
    const int colBase = wv * 64;

    // ---- geometry (t<32), row-sorted edges ----
    if (t < 32) {
        const int e = elist[e0 + t];
        const int r = eidx[e];
        const int c = eidx[E + e];
        rowi[t] = r; coli[t] = c;
        const float px = node_pos[r * 3 + 0];
        const float py = node_pos[r * 3 + 1];
        const float pz = node_pos[r * 3 + 2];
        float d[4][3];
        #pragma unroll
        for (int ch = 0; ch < 4; ++ch) {
            d[ch][0] = px - vn_pos[(size_t)c * 12 + ch * 3 + 0];
            d[ch][1] = py - vn_pos[(size_t)c * 12 + ch * 3 + 1];
            d[ch][2] = pz - vn_pos[(size_t)c * 12 + ch * 3 + 2];
        }
        float ss = 0.f, ipv[16];
        #pragma unroll
        for (int ci = 0; ci < 4; ++ci)
            #pragma unroll
            for (int ck = 0; ck < 4; ++ck) {
                const float v = d[ci][0]*d[ck][0] + d[ci][1]*d[ck][1] + d[ci][2]*d[ck][2];
                ipv[ci * 4 + ck] = v; ss += v * v;
            }
        const float inrm = 1.0f / fmaxf(sqrtf(ss), 1e-8f);
        #pragma unroll
        for (int i = 0; i < 16; ++i) ipB[t * 16 + i] = f2b(ipv[i] * inrm);
        #pragma unroll
        for (int ch = 0; ch < 4; ++ch) {
            const float nn = sqrtf(d[ch][0]*d[ch][0] + d[ch][1]*d[ch][1] + d[ch][2]*d[ch][2]);
            const float s = 1.0f / fmaxf(nn, 1e-8f);
            dnS[t][ch * 3 + 0] = d[ch][0] * s;
            dnS[t][ch * 3 + 1] = d[ch][1] * s;
            dnS[t][ch * 3 + 2] = d[ch][2] * s;
        }
    }
    __syncthreads();

    const ushort* nA0 = nfsb + (size_t)rowi[lr]      * SDIM + lk * 8;
    const ushort* nA1 = nfsb + (size_t)rowi[lr + 16] * SDIM + lk * 8;
    const ushort* vA0 = vnb  + (size_t)coli[lr]      * HDIM + lk * 8;
    const ushort* vA1 = vnb  + (size_t)coli[lr + 16] * HDIM + lk * 8;
    const ushort* w1t = wb + OW1;

    f32x4 acc[2][4];

    // ===== cm layer 1 (K=416: 128 nfs | 256 vn | 16 ip | 16 zero) =====
    #pragma unroll
    for (int mt = 0; mt < 2; ++mt)
        #pragma unroll
        for (int nt = 0; nt < 4; ++nt) acc[mt][nt] = (f32x4)0.f;
    #pragma unroll
    for (int ks = 0; ks < 13; ++ks) {
        bf16x8 a0, a1;
        if (ks < 4) {
            a0 = *(const bf16x8*)(nA0 + ks * 32);
            a1 = *(const bf16x8*)(nA1 + ks * 32);
        } else if (ks < 12) {
            a0 = *(const bf16x8*)(vA0 + ks * 32 - 128);
            a1 = *(const bf16x8*)(vA1 + ks * 32 - 128);
        } else if (lk < 2) {
            a0 = *(const bf16x8*)&ipB[lr * 16 + lk * 8];
            a1 = *(const bf16x8*)&ipB[(lr + 16) * 16 + lk * 8];
        } else {
            a0 = (bf16x8)(short)0;
            a1 = (bf16x8)(short)0;
        }
        #pragma unroll
        for (int nt = 0; nt < 4; ++nt) {
            const bf16x8 b = *(const bf16x8*)&w1t[(size_t)(((wv * 4 + nt) * 13 + ks) * 512) + lane * 8];
            acc[0][nt] = __builtin_amdgcn_mfma_f32_16x16x32_bf16(a0, b, acc[0][nt], 0, 0, 0);
            acc[1][nt] = __builtin_amdgcn_mfma_f32_16x16x32_bf16(a1, b, acc[1][nt], 0, 0, 0);
        }
    }
    EPI_SILU(Hd, b1);
    __syncthreads();

    // ===== cm layer 2 -> msg =====
    KLOOP_FR(Hd, wb + OW2);
    #pragma unroll
    for (int nt = 0; nt < 4; ++nt) {
        const int col = colBase + nt * 16 + lr;
        const float bb = b2[col];
        #pragma unroll
        for (int mt = 0; mt < 2; ++mt)
            #pragma unroll
            for (int r = 0; r < 4; ++r) {
                const int row = mt * 16 + lk * 4 + r;
                Mg[row * MSTR + col] = f2b(acc[mt][nt][r] + bb);
            }
    }
    __syncthreads();

    // ===== segmented reduction msg -> agg_feat (thread t = column t) =====
    {
        float s = 0.f;
        int prev = rowi[0];
        for (int r = 0; r < 32; ++r) {
            const int rr = rowi[r];
            if (rr != prev) {
                atomicAdd(&agg_feat[(size_t)prev * HDIM + t], s);
                s = 0.f; prev = rr;
            }
            s += b2f(Mg[r * MSTR + t]);
        }
        atomicAdd(&agg_feat[(size_t)prev * HDIM + t], s);
    }

    // ===== vr layer 1 =====
    KLOOP_FR(Mg, wb + OVR1);
    EPI_SILU(Hd, vrb1);
    __syncthreads();

    // ===== vr layer 2 (wave 0, N=4 padded to 16) =====
    if (wv == 0) {
        const ushort* vrw2t = wb + OVR2;
        f32x4 a2[2]; a2[0] = (f32x4)0.f; a2[1] = (f32x4)0.f;
        #pragma unroll
        for (int ks = 0; ks < 8; ++ks) {
            const bf16x8 a0 = *(const bf16x8*)&Hd[lr * MSTR + ks * 32 + lk * 8];
            const bf16x8 a1 = *(const bf16x8*)&Hd[(lr + 16) * MSTR + ks * 32 + lk * 8];
            const bf16x8 b  = *(const bf16x8*)&vrw2t[(size_t)(ks * 512) + lane * 8];
            a2[0] = __builtin_amdgcn_mfma_f32_16x16x32_bf16(a0, b, a2[0], 0, 0, 0);
            a2[1] = __builtin_amdgcn_mfma_f32_16x16x32_bf16(a1, b, a2[1], 0, 0, 0);
        }
        if (lr < 4) {
            const float bb = vrb2[lr];
            #pragma unroll
            for (int mt = 0; mt < 2; ++mt)
                #pragma unroll
                for (int r = 0; r < 4; ++r)
                    wvrS[mt * 16 + lk * 4 + r][lr] = a2[mt][r] + bb;
        }
    }
    __syncthreads();

    // ===== rv layer 1 =====
    KLOOP_FR(Mg, wb + ORV1);
    EPI_SILU(Hd, rvb1);
    __syncthreads();

    // ===== rv layer 2 (wave 0, N=16) =====
    if (wv == 0) {
        const ushort* rvw2t = wb + ORV2;
        f32x4 a2[2]; a2[0] = (f32x4)0.f; a2[1] = (f32x4)0.f;
        #pragma unroll
        for (int ks = 0; ks < 8; ++ks) {
            const bf16x8 a0 = *(const bf16x8*)&Hd[lr * MSTR + ks * 32 + lk * 8];
            const bf16x8 a1 = *(const bf16x8*)&Hd[(lr + 16) * MSTR + ks * 32 + lk * 8];
            const bf16x8 b  = *(const bf16x8*)&rvw2t[(size_t)(ks * 512) + lane * 8];
            a2[0] = __builtin_amdgcn_mfma_f32_16x16x32_bf16(a0, b, a2[0], 0, 0, 0);
            a2[1] = __builtin_amdgcn_mfma_f32_16x16x32_bf16(a1, b, a2[1], 0, 0, 0);
        }
        const float bb = rvb2[lr];
        #pragma unroll
        for (int mt = 0; mt < 2; ++mt)
            #pragma unroll
            for (int r = 0; r < 4; ++r)
                wrvS[mt * 16 + lk * 4 + r][lr] = a2[mt][r] + bb;
    }
    __syncthreads();

    // ===== per-edge geometric update (t<32) =====
    if (t < 32) {
        float wvv[4], wrr[16], dn[12], ev[15];
        #pragma unroll
        for (int c = 0; c < 4; ++c)  wvv[c] = wvrS[t][c];
        #pragma unroll
        for (int i = 0; i < 16; ++i) wrr[i] = wrvS[t][i];
        #pragma unroll
        for (int i = 0; i < 12; ++i) dn[i]  = dnS[t][i];
        #pragma unroll
        for (int j = 0; j < 3; ++j) {
            float v = 0.f;
            #pragma unroll
            for (int c = 0; c < 4; ++c) v = fmaf(wvv[c], dn[c * 3 + j], v);
            ev[j] = 0.5f * v;
        }
        #pragma unroll
        for (int u = 0; u < 4; ++u)
            #pragma unroll
            for (int j = 0; j < 3; ++j) {
                float v = 0.f;
                #pragma unroll
                for (int c = 0; c < 4; ++c) v = fmaf(wrr[c * 4 + u], dn[c * 3 + j], v);
                ev[3 + u * 3 + j] = -0.5f * v;
            }
        #pragma unroll
        for (int i = 0; i < 15; ++i) wrvS[t][i] = ev[i];
    }
    __syncthreads();

    // ===== segmented reduction vr/rv (t<15) =====
    if (t < 15) {
        float s = 0.f;
        int prev = rowi[0];
        for (int r = 0; r < 32; ++r) {
            const int rr = rowi[r];
            if (rr != prev) {
                if (t < 3) atomicAdd(&agg_vr[(size_t)prev * 3 + t], s);
                else       atomicAdd(&agg_rv[(size_t)prev * 12 + (t - 3)], s);
                s = 0.f; prev = rr;
            }
            s += wrvS[r][t];
        }
        if (t < 3) atomicAdd(&agg_vr[(size_t)prev * 3 + t], s);
        else       atomicAdd(&agg_rv[(size_t)prev * 12 + (t - 3)], s);
    }
}

// ---------------------------------------------------------------- k_node
// 32 nodes/block (625 blocks), 256 threads = 4 waves, frag-packed weights.
__global__ __launch_bounds__(256, 4) void k_node(
    const float* __restrict__ node_feat, const float* __restrict__ node_pos,
    const float* __restrict__ vn_feat, const float* __restrict__ vn_pos,
    const float* __restrict__ agg_feat, const float* __restrict__ agg_vr,
    const float* __restrict__ agg_rv, const float* __restrict__ cntf,
    const ushort* __restrict__ wb,
    const float* __restrict__ ftb1, const float* __restrict__ ftb2,
    const float* __restrict__ f2tb1, const float* __restrict__ f2tb2,
    const float* __restrict__ vfb1, const float* __restrict__ vfb2,
    float* __restrict__ out, int Nn)
{
    __shared__ ushort Ab[32 * MSTR];
    __shared__ ushort Hd[32 * MSTR];
    __shared__ float rc[32];
    const int t  = threadIdx.x;
    const int n0 = blockIdx.x * 32;
    const int wv = t >> 6;
    const int lane = t & 63;
    const int lr = lane & 15;
    const int lk = lane >> 4;
    const int colBase = wv * 64;

    float* nf_out = out;
    float* np_out = out + (size_t)Nn * FEAT;
    float* vf_out = np_out + (size_t)Nn * 3;
    float* vp_out = vf_out + (size_t)Nn * HDIM;

    if (t < 32) rc[t] = 1.0f / fmaxf(cntf[n0 + t], 1.0f);
    __syncthreads();
    #pragma unroll
    for (int i = 0; i < 8; ++i) {
        const int p = t + i * 256;
        const int r = p >> 6, cc = (p & 63) * 4;
        float4 v = *(const float4*)&agg_feat[(size_t)(n0 + r) * HDIM + cc];
        const float s = rc[r];
        ushort4 o;
        o.x = f2b(v.x * s); o.y = f2b(v.y * s);
        o.z = f2b(v.z * s); o.w = f2b(v.w * s);
        *(ushort4*)&Ab[r * MSTR + cc] = o;
    }
    __syncthreads();

    f32x4 acc[2][4];

    // ---- vf MLP ----
    KLOOP_FR(Ab, wb + OVF1);
    EPI_SILU(Hd, vfb1);
    __syncthreads();
    KLOOP_FR(Hd, wb + OVF2);
    #pragma unroll
    for (int nt = 0; nt < 4; ++nt) {
        const int col = colBase + nt * 16 + lr;
        const float bb = vfb2[col];
        #pragma unroll
        for (int mt = 0; mt < 2; ++mt)
            #pragma unroll
            for (int r = 0; r < 4; ++r) {
                const int row = mt * 16 + lk * 4 + r;
                const size_t o = (size_t)(n0 + row) * HDIM + col;
                vf_out[o] = vn_feat[o] + acc[mt][nt][r] + bb;
            }
    }
    __syncthreads();

    // ---- ft MLP ----
    KLOOP_FR(Ab, wb + OFT1);
    EPI_SILU(Hd, ftb1);
    __syncthreads();
    KLOOP_FR(Hd, wb + OFT2);
    #pragma unroll
    for (int nt = 0; nt < 4; ++nt) {               // x2 -> Ab (bf16)
        const int col = colBase + nt * 16 + lr;
        const float bb = ftb2[col];
        #pragma unroll
        for (int mt = 0; mt < 2; ++mt)
            #pragma unroll
            for (int r = 0; r < 4; ++r) {
                const int row = mt * 16 + lk * 4 + r;
                Ab[row * MSTR + col] = f2b(acc[mt][nt][r] + bb);
            }
    }
    __syncthreads();

    // ---- f2t MLP ----
    KLOOP_FR(Ab, wb + OF2T1);
    EPI_SILU(Hd, f2tb1);
    __syncthreads();
    {   // layer 2, N=128: 4 waves x 32 cols, frag-packed (8 nt total)
        const ushort* w2p = wb + OF2T2;
        f32x4 a2[2][2];
        #pragma unroll
        for (int mt = 0; mt < 2; ++mt)
            #pragma unroll
            for (int nt = 0; nt < 2; ++nt) a2[mt][nt] = (f32x4)0.f;
        #pragma unroll
        for (int ks = 0; ks < 8; ++ks) {
            const int k0 = ks * 32 + lk * 8;
            const bf16x8 a0 = *(const bf16x8*)&Hd[lr * MSTR + k0];
            const bf16x8 a1 = *(const bf16x8*)&Hd[(lr + 16) * MSTR + k0];
            const bf16x8 w0 = *(const bf16x8*)&w2p[(size_t)(((wv * 2 + 0) * 8 + ks) * 512) + lane * 8];
            const bf16x8 w1v = *(const bf16x8*)&w2p[(size_t)(((wv * 2 + 1) * 8 + ks) * 512) + lane * 8];
            a2[0][0] = __builtin_amdgcn_mfma_f32_16x16x32_bf16(a0, w0, a2[0][0], 0, 0, 0);
            a2[1][0] = __builtin_amdgcn_mfma_f32_16x16x32_bf16(a1, w0, a2[1][0], 0, 0, 0);
            a2[0][1] = __builtin_amdgcn_mfma_f32_16x16x32_bf16(a0, w1v, a2[0][1], 0, 0, 0);
            a2[1][1] = __builtin_amdgcn_mfma_f32_16x16x32_bf16(a1, w1v, a2[1][1], 0, 0, 0);
        }
        #pragma unroll
        for (int nt = 0; nt < 2; ++nt) {
            const int col = wv * 32 + nt * 16 + lr;
            const float bb = f2tb2[col];
            #pragma unroll
            for (int mt = 0; mt < 2; ++mt)
                #pragma unroll
                for (int r = 0; r < 4; ++r) {
                    const int row = mt * 16 + lk * 4 + r;
                    const size_t o = (size_t)(n0 + row) * FEAT + col;
                    nf_out[o] = node_feat[o] + a2[mt][nt][r] + bb;
                }
        }
    }

    // passthrough cols 128..479
    for (int p = t; p < 32 * 88; p += 256) {
        const int r = p / 88;
        const int cc = 128 + (p % 88) * 4;
        const size_t o = (size_t)(n0 + r) * FEAT + cc;
        *(float4*)&nf_out[o] = *(const float4*)&node_feat[o];
    }
    if (t < 32) {
        const int n = n0 + t;
        const float s = rc[t];
        #pragma unroll
        for (int j = 0; j < 3; ++j)
            np_out[(size_t)n * 3 + j] = node_pos[(size_t)n * 3 + j] + agg_vr[(size_t)n * 3 + j] * s;
        #pragma unroll
        for (int j = 0; j < 12; ++j)
            vp_out[(size_t)n * 12 + j] = vn_pos[(size_t)n * 12 + j] + agg_rv[(size_t)n * 12 + j] * s;
    }
}

// ---------------------------------------------------------------- launch
extern "C" void kernel_launch(void* const* d_in, const int* in_sizes, int n_in,
                              void* d_out, int out_size, void* d_ws, size_t ws_size,
                              hipStream_t stream)
{
    (void)n_in; (void)out_size; (void)ws_size;
    const float* node_feat = (const float*)d_in[0];
    const float* node_pos  = (const float*)d_in[1];
    const float* vn_feat   = (const float*)d_in[2];
    const float* vn_pos    = (const float*)d_in[3];
    const int*   eidx      = (const int*)d_in[4];
    const float* w_scalar  = (const float*)d_in[5];
    const float* cm_w1  = (const float*)d_in[6];
    const float* cm_b1  = (const float*)d_in[7];
    const float* cm_w2  = (const float*)d_in[8];
    const float* cm_b2  = (const float*)d_in[9];
    const float* vr_w1  = (const float*)d_in[10];
    const float* vr_b1  = (const float*)d_in[11];
    const float* vr_w2  = (const float*)d_in[12];
    const float* vr_b2  = (const float*)d_in[13];
    const float* rv_w1  = (const float*)d_in[14];
    const float* rv_b1  = (const float*)d_in[15];
    const float* rv_w2  = (const float*)d_in[16];
    const float* rv_b2  = (const float*)d_in[17];
    const float* ft_w1  = (const float*)d_in[18];
    const float* ft_b1  = (const float*)d_in[19];
    const float* ft_w2  = (const float*)d_in[20];
    const float* ft_b2  = (const float*)d_in[21];
    const float* f2t_w1 = (const float*)d_in[22];
    const float* f2t_b1 = (const float*)d_in[23];
    const float* f2t_w2 = (const float*)d_in[24];
    const float* f2t_b2 = (const float*)d_in[25];
    const float* vf_w1  = (const float*)d_in[26];
    const float* vf_b1  = (const float*)d_in[27];
    const float* vf_w2  = (const float*)d_in[28];
    const float* vf_b2  = (const float*)d_in[29];

    const int Nn = in_sizes[0] / FEAT;        // 20000
    const int E  = in_sizes[4] / 2;           // 240000

    // workspace layout
    float* ws       = (float*)d_ws;
    float* agg_feat = ws;                                // Nn*256 (zeroed)
    float* agg_vr   = agg_feat + (size_t)Nn * HDIM;      // Nn*3   (zeroed)
    float* agg_rv   = agg_vr   + (size_t)Nn * 3;         // Nn*12  (zeroed)
    float* cntf     = agg_rv   + (size_t)Nn * 12;        // Nn     (zeroed)
    int*   cnt_i    = (int*)(cntf + Nn);                 // Nn     (zeroed)
    int*   cursor   = cnt_i + Nn;                        // Nn     (zeroed)
    int*   rowstart = cursor + Nn;                       // Nn+16
    int*   elist    = rowstart + Nn + 16;                // E
    ushort* nfsb = (ushort*)(elist + E);                 // Nn*128
    ushort* vnb  = nfsb + (size_t)Nn * SDIM;             // Nn*256
    ushort* wb   = vnb  + (size_t)Nn * HDIM;             // OWTOT

    const size_t zero_bytes = (size_t)Nn * (HDIM + 3 + 12 + 1 + 2) * sizeof(float);
    hipMemsetAsync(agg_feat, 0, zero_bytes, stream);

    const int eg = (E + 255) / 256;
    k_count<<<eg, 256, 0, stream>>>(eidx, cnt_i, E);
    k_scan<<<1, 1024, 0, stream>>>(cnt_i, rowstart, cntf, Nn);
    k_place<<<eg, 256, 0, stream>>>(eidx, rowstart, cursor, elist, E);
    k_wprep<<<(OWTOT + 255) / 256, 256, 0, stream>>>(
        cm_w1, cm_w2, vr_w1, rv_w1, vr_w2, rv_w2,
        ft_w1, ft_w2, f2t_w1, f2t_w2, vf_w1, vf_w2, wb);
    k_vnb<<<(Nn * 64 + 255) / 256, 256, 0, stream>>>(vn_feat, vnb, Nn * 64);
    k_nfs<<<Nn / 32, 256, 0, stream>>>(node_feat, w_scalar, nfsb);
    k_edge<<<E / 32, 256, 0, stream>>>(nfsb, vnb, node_pos, vn_pos, eidx, elist,
                                       wb, cm_b1, cm_b2, vr_b1, vr_b2, rv_b1, rv_b2,
                                       agg_feat, agg_vr, agg_rv, E);
    k_node<<<Nn / 32, 256, 0, stream>>>(node_feat, node_pos, vn_feat, vn_pos,
                                        agg_feat, agg_vr, agg_rv, cntf, wb,
                                        ft_b1, ft_b2, f2t_b1, f2t_b2, vf_b1, vf_b2,
                                        (float*)d_out, Nn);
}

// Round 9
// 489.174 us; speedup vs baseline: 2.8827x; 1.0543x over previous
//
#include <hip/hip_runtime.h>
#include <hip/hip_bf16.h>
#include <math.h>

// VNLayer: N=20000 nodes, E=240000 edges, H=256, SD=128, C=4, FEAT=480
// Round 9: 64-edge blocks, 512 threads, tall-skinny wave tiles.
// Each of 8 waves: 4 m-tiles x 2 n-tiles -> per ks-group 2 global B-loads
// feed 16 MFMAs (global:MFMA ratio halved vs round 8), weight L2 traffic
// per edge halved, per-edge phase overhead halved. TLP unchanged
// (2 blk/CU x 8 waves = 16 waves/CU). Frag-packed weights from round 8.

#define FEAT 480
#define HDIM 256
#define SDIM 128
#define MSTR 264    // LDS A row stride (ushorts)

// bf16 weight arena offsets (ushort elements) -- frag-packed regions
#define OW1   0          // cm1 : 16 nt x 13 ks x 512
#define OW2   106496     // cm2 : 16 x 8 x 512
#define OVR1  172032
#define ORV1  237568
#define OVR2  303104     // vr2 : 1 x 8 x 512 (cols>=4 zero)
#define ORV2  307200     // rv2 : 1 x 8 x 512
#define OFT1  311296
#define OFT2  376832
#define OF2T1 442368
#define OF2T2 507904     // f2t2: 8 nt x 8 ks x 512
#define OVF1  540672
#define OVF2  606208
#define OWTOT 671744

typedef __attribute__((ext_vector_type(8))) short bf16x8;
typedef __attribute__((ext_vector_type(4))) float f32x4;

__device__ __forceinline__ float silu_f(float x) {
    return x / (1.0f + __expf(-x));
}
__device__ __forceinline__ ushort f2b(float v) {
    __hip_bfloat16 h = __float2bfloat16(v);
    return *(ushort*)&h;
}
__device__ __forceinline__ float b2f(ushort u) {
    union { unsigned int i; float f; } c;
    c.i = ((unsigned int)u) << 16;
    return c.f;
}

// k_edge K=256 GEMM: 4 m-tiles x 2 n-tiles per wave. A from LDS, B frag-packed.
// Uses names: lane, lr, lk, wv, acc (f32x4 acc[4][2]).
#define KLOOP2(SRC, WP)                                                        \
    {                                                                          \
        _Pragma("unroll")                                                      \
        for (int mt = 0; mt < 4; ++mt)                                         \
            _Pragma("unroll")                                                  \
            for (int nt = 0; nt < 2; ++nt) acc[mt][nt] = (f32x4)0.f;           \
        _Pragma("unroll")                                                      \
        for (int ks = 0; ks < 8; ++ks) {                                       \
            bf16x8 a_[4];                                                      \
            _Pragma("unroll")                                                  \
            for (int mt = 0; mt < 4; ++mt)                                     \
                a_[mt] = *(const bf16x8*)&(SRC)[(mt * 16 + lr) * MSTR + ks * 32 + lk * 8]; \
            _Pragma("unroll")                                                  \
            for (int nt = 0; nt < 2; ++nt) {                                   \
                const bf16x8 b = *(const bf16x8*)&(WP)[(size_t)(((wv * 2 + nt) * 8 + ks) * 512) + lane * 8]; \
                _Pragma("unroll")                                              \
                for (int mt = 0; mt < 4; ++mt)                                 \
                    acc[mt][nt] = __builtin_amdgcn_mfma_f32_16x16x32_bf16(a_[mt], b, acc[mt][nt], 0, 0, 0); \
            }                                                                  \
        }                                                                      \
    }

// silu epilogue into an LDS bf16 matrix (64 rows, wave covers 2 n-tiles)
#define EPI_SILU2(DST, BIAS)                                                   \
    _Pragma("unroll")                                                          \
    for (int nt = 0; nt < 2; ++nt) {                                           \
        const int col = colBase + nt * 16 + lr;                                \
        const float bb = (BIAS)[col];                                          \
        _Pragma("unroll")                                                      \
        for (int mt = 0; mt < 4; ++mt)                                         \
            _Pragma("unroll")                                                  \
            for (int r = 0; r < 4; ++r) {                                      \
                const int row = mt * 16 + lk * 4 + r;                          \
                (DST)[row * MSTR + col] = f2b(silu_f(acc[mt][nt][r] + bb));    \
            }                                                                  \
    }

// k_node K=256 GEMM (round-8 form): 2 m-tiles x 4 n-tiles per wave.
#define KLOOP_FR(SRC, WP)                                                      \
    {                                                                          \
        _Pragma("unroll")                                                      \
        for (int mt = 0; mt < 2; ++mt)                                         \
            _Pragma("unroll")                                                  \
            for (int nt = 0; nt < 4; ++nt) accn[mt][nt] = (f32x4)0.f;          \
        _Pragma("unroll")                                                      \
        for (int ks = 0; ks < 8; ++ks) {                                       \
            const bf16x8 a0 = *(const bf16x8*)&(SRC)[lr * MSTR + ks * 32 + lk * 8];        \
            const bf16x8 a1 = *(const bf16x8*)&(SRC)[(lr + 16) * MSTR + ks * 32 + lk * 8]; \
            _Pragma("unroll")                                                  \
            for (int nt = 0; nt < 4; ++nt) {                                   \
                const bf16x8 b = *(const bf16x8*)&(WP)[(size_t)(((wv * 4 + nt) * 8 + ks) * 512) + lane * 8]; \
                accn[0][nt] = __builtin_amdgcn_mfma_f32_16x16x32_bf16(a0, b, accn[0][nt], 0, 0, 0); \
                accn[1][nt] = __builtin_amdgcn_mfma_f32_16x16x32_bf16(a1, b, accn[1][nt], 0, 0, 0); \
            }                                                                  \
        }                                                                      \
    }

#define EPI_SILUN(DST, BIAS)                                                   \
    _Pragma("unroll")                                                          \
    for (int nt = 0; nt < 4; ++nt) {                                           \
        const int col = colBase + nt * 16 + lr;                                \
        const float bb = (BIAS)[col];                                          \
        _Pragma("unroll")                                                      \
        for (int mt = 0; mt < 2; ++mt)                                         \
            _Pragma("unroll")                                                  \
            for (int r = 0; r < 4; ++r) {                                      \
                const int row = mt * 16 + lk * 4 + r;                          \
                (DST)[row * MSTR + col] = f2b(silu_f(accn[mt][nt][r] + bb));   \
            }                                                                  \
    }

// ---------------------------------------------------------------- CSR build
__global__ __launch_bounds__(256) void k_count(
    const int* __restrict__ eidx, int* __restrict__ cnt_i, int E)
{
    const int e = blockIdx.x * 256 + threadIdx.x;
    if (e < E) atomicAdd(&cnt_i[eidx[e]], 1);
}

__global__ __launch_bounds__(1024) void k_scan(
    const int* __restrict__ cnt_i, int* __restrict__ rowstart,
    float* __restrict__ cntf, int Nn)
{
    __shared__ int sh[1024];
    __shared__ int carry_s;
    const int t = threadIdx.x;
    if (t == 0) carry_s = 0;
    __syncthreads();
    const int nch = (Nn + 1023) / 1024;
    for (int ch = 0; ch < nch; ++ch) {
        const int i = ch * 1024 + t;
        const int v = (i < Nn) ? cnt_i[i] : 0;
        sh[t] = v;
        __syncthreads();
        for (int off = 1; off < 1024; off <<= 1) {
            const int add = (t >= off) ? sh[t - off] : 0;
            __syncthreads();
            sh[t] += add;
            __syncthreads();
        }
        const int incl = sh[t];
        const int carry = carry_s;
        if (i < Nn) {
            rowstart[i + 1] = carry + incl;
            cntf[i] = fmaxf((float)v, 1.0f);
        }
        __syncthreads();
        if (t == 1023) carry_s = carry + incl;
        __syncthreads();
    }
    if (t == 0) rowstart[0] = 0;
}

__global__ __launch_bounds__(256) void k_place(
    const int* __restrict__ eidx, const int* __restrict__ rowstart,
    int* __restrict__ cursor, int* __restrict__ elist, int E)
{
    const int e = blockIdx.x * 256 + threadIdx.x;
    if (e < E) {
        const int r = eidx[e];
        const int p = atomicAdd(&cursor[r], 1);
        elist[rowstart[r] + p] = e;
    }
}

// ---------------------------------------------------------------- k_wprep
// Frag-packed bf16 weights (identical to round 8).
__global__ __launch_bounds__(256) void k_wprep(
    const float* __restrict__ w1, const float* __restrict__ w2,
    const float* __restrict__ vrw1, const float* __restrict__ rvw1,
    const float* __restrict__ vrw2, const float* __restrict__ rvw2,
    const float* __restrict__ ftw1, const float* __restrict__ ftw2,
    const float* __restrict__ f2tw1, const float* __restrict__ f2tw2,
    const float* __restrict__ vfw1, const float* __restrict__ vfw2,
    ushort* __restrict__ wb)
{
    const int idx = blockIdx.x * 256 + threadIdx.x;
    if (idx >= OWTOT) return;
    ushort v;
    if (idx < OW2) {
        const int o = idx, f = o >> 9, l = (o >> 3) & 63, e = o & 7;
        const int nt = f / 13, ks = f % 13;
        const int col = nt * 16 + (l & 15);
        const int k = ks * 32 + ((l >> 4) << 3) + e;
        v = (k < 400) ? f2b(w1[(size_t)k * 256 + col]) : (ushort)0;
    } else if (idx < OVR1) {
        const int o = idx - OW2, f = o >> 9, l = (o >> 3) & 63, e = o & 7;
        const int col = (f >> 3) * 16 + (l & 15);
        const int k = (f & 7) * 32 + ((l >> 4) << 3) + e;
        v = f2b(w2[(size_t)k * 256 + col]);
    } else if (idx < ORV1) {
        const int o = idx - OVR1, f = o >> 9, l = (o >> 3) & 63, e = o & 7;
        const int col = (f >> 3) * 16 + (l & 15);
        const int k = (f & 7) * 32 + ((l >> 4) << 3) + e;
        v = f2b(vrw1[(size_t)k * 256 + col]);
    } else if (idx < OVR2) {
        const int o = idx - ORV1, f = o >> 9, l = (o >> 3) & 63, e = o & 7;
        const int col = (f >> 3) * 16 + (l & 15);
        const int k = (f & 7) * 32 + ((l >> 4) << 3) + e;
        v = f2b(rvw1[(size_t)k * 256 + col]);
    } else if (idx < ORV2) {
        const int o = idx - OVR2, f = o >> 9, l = (o >> 3) & 63, e = o & 7;
        const int col = l & 15;
        const int k = f * 32 + ((l >> 4) << 3) + e;
        v = (col < 4) ? f2b(vrw2[(size_t)k * 4 + col]) : (ushort)0;
    } else if (idx < OFT1) {
        const int o = idx - ORV2, f = o >> 9, l = (o >> 3) & 63, e = o & 7;
        const int col = l & 15;
        const int k = f * 32 + ((l >> 4) << 3) + e;
        v = f2b(rvw2[(size_t)k * 16 + col]);
    } else if (idx < OFT2) {
        const int o = idx - OFT1, f = o >> 9, l = (o >> 3) & 63, e = o & 7;
        const int col = (f >> 3) * 16 + (l & 15);
        const int k = (f & 7) * 32 + ((l >> 4) << 3) + e;
        v = f2b(ftw1[(size_t)k * 256 + col]);
    } else if (idx < OF2T1) {
        const int o = idx - OFT2, f = o >> 9, l = (o >> 3) & 63, e = o & 7;
        const int col = (f >> 3) * 16 + (l & 15);
        const int k = (f & 7) * 32 + ((l >> 4) << 3) + e;
        v = f2b(ftw2[(size_t)k * 256 + col]);
    } else if (idx < OF2T2) {
        const int o = idx - OF2T1, f = o >> 9, l = (o >> 3) & 63, e = o & 7;
        const int col = (f >> 3) * 16 + (l & 15);
        const int k = (f & 7) * 32 + ((l >> 4) << 3) + e;
        v = f2b(f2tw1[(size_t)k * 256 + col]);
    } else if (idx < OVF1) {
        const int o = idx - OF2T2, f = o >> 9, l = (o >> 3) & 63, e = o & 7;
        const int col = (f >> 3) * 16 + (l & 15);
        const int k = (f & 7) * 32 + ((l >> 4) << 3) + e;
        v = f2b(f2tw2[(size_t)k * 128 + col]);
    } else if (idx < OVF2) {
        const int o = idx - OVF1, f = o >> 9, l = (o >> 3) & 63, e = o & 7;
        const int col = (f >> 3) * 16 + (l & 15);
        const int k = (f & 7) * 32 + ((l >> 4) << 3) + e;
        v = f2b(vfw1[(size_t)k * 256 + col]);
    } else {
        const int o = idx - OVF2, f = o >> 9, l = (o >> 3) & 63, e = o & 7;
        const int col = (f >> 3) * 16 + (l & 15);
        const int k = (f & 7) * 32 + ((l >> 4) << 3) + e;
        v = f2b(vfw2[(size_t)k * 256 + col]);
    }
    wb[idx] = v;
}

// ---------------------------------------------------------------- k_vnb
__global__ __launch_bounds__(256) void k_vnb(
    const float* __restrict__ vn_feat, ushort* __restrict__ vnb, int total4)
{
    const int i = blockIdx.x * 256 + threadIdx.x;
    if (i >= total4) return;
    const float4 v = *(const float4*)&vn_feat[(size_t)i * 4];
    ushort4 o;
    o.x = f2b(v.x); o.y = f2b(v.y); o.z = f2b(v.z); o.w = f2b(v.w);
    *(ushort4*)&vnb[(size_t)i * 4] = o;
}

// ---------------------------------------------------------------- k_nfs
__global__ __launch_bounds__(256) void k_nfs(
    const float* __restrict__ node_feat, const float* __restrict__ w_scalar,
    ushort* __restrict__ nfsb)
{
    __shared__ float At[32][20];
    __shared__ float Wt[16][128];
    const int t  = threadIdx.x;
    const int m0 = blockIdx.x * 32;
    const int c4 = (t & 31) * 4;
    const int rg = t >> 5;
    float acc[4][4] = {};
    for (int k0 = 0; k0 < 128; k0 += 16) {
        if (t < 128) {
            const int r = t >> 2, kk = (t & 3) * 4;
            *(float4*)&At[r][kk] =
                *(const float4*)&node_feat[(size_t)(m0 + r) * FEAT + k0 + kk];
        }
        #pragma unroll
        for (int i = 0; i < 2; ++i) {
            const int p  = t + i * 256;
            const int wr = p >> 5, wc = (p & 31) * 4;
            *(float4*)&Wt[wr][wc] =
                *(const float4*)&w_scalar[(size_t)(k0 + wr) * SDIM + wc];
        }
        __syncthreads();
        #pragma unroll
        for (int kk = 0; kk < 16; ++kk) {
            const float4 w = *(const float4*)&Wt[kk][c4];
            #pragma unroll
            for (int j = 0; j < 4; ++j) {
                const float a = At[rg * 4 + j][kk];
                acc[j][0] = fmaf(a, w.x, acc[j][0]);
                acc[j][1] = fmaf(a, w.y, acc[j][1]);
                acc[j][2] = fmaf(a, w.z, acc[j][2]);
                acc[j][3] = fmaf(a, w.w, acc[j][3]);
            }
        }
        __syncthreads();
    }
    const float s = 0.08838834764831845f;
    #pragma unroll
    for (int j = 0; j < 4; ++j) {
        ushort4 o;
        o.x = f2b(acc[j][0] * s); o.y = f2b(acc[j][1] * s);
        o.z = f2b(acc[j][2] * s); o.w = f2b(acc[j][3] * s);
        *(ushort4*)&nfsb[(size_t)(m0 + rg * 4 + j) * SDIM + c4] = o;
    }
}

// ---------------------------------------------------------------- k_edge
// 64 row-sorted edges/block, 512 threads = 8 waves. LDS 78.3KB -> 2 blk/CU.
__global__ __launch_bounds__(512, 4) void k_edge(
    const ushort* __restrict__ nfsb, const ushort* __restrict__ vnb,
    const float* __restrict__ node_pos, const float* __restrict__ vn_pos,
    const int* __restrict__ eidx, const int* __restrict__ elist,
    const ushort* __restrict__ wb,
    const float* __restrict__ b1, const float* __restrict__ b2,
    const float* __restrict__ vrb1, const float* __restrict__ vrb2,
    const float* __restrict__ rvb1, const float* __restrict__ rvb2,
    float* __restrict__ agg_feat, float* __restrict__ agg_vr,
    float* __restrict__ agg_rv, int E)
{
    __shared__ ushort Mg[64 * MSTR];   // 33.8 KB msg
    __shared__ ushort Hd[64 * MSTR];   // 33.8 KB hidden
    __shared__ ushort ipB[64 * 16];    // 2 KB
    __shared__ float dnS[64][12];
    __shared__ float wvrS[64][4];
    __shared__ float wrvS[64][16];
    __shared__ int rowi[64], coli[64];

    const int t  = threadIdx.x;
    const int e0 = blockIdx.x * 64;
    const int wv = t >> 6;             // 0..7
    const int lane = t & 63;
    const int lr = lane & 15;
    const int lk = lane >> 4;
    const int colBase = wv * 32;       // 2 n-tiles per wave

    // ---- geometry (t<64), row-sorted edges ----
    if (t < 64) {
        const int e = elist[e0 + t];
        const int r = eidx[e];
        const int c = eidx[E + e];
        rowi[t] = r; coli[t] = c;
        const float px = node_pos[r * 3 + 0];
        const float py = node_pos[r * 3 + 1];
        const float pz = node_pos[r * 3 + 2];
        float d[4][3];
        #pragma unroll
        for (int ch = 0; ch < 4; ++ch) {
            d[ch][0] = px - vn_pos[(size_t)c * 12 + ch * 3 + 0];
            d[ch][1] = py - vn_pos[(size_t)c * 12 + ch * 3 + 1];
            d[ch][2] = pz - vn_pos[(size_t)c * 12 + ch * 3 + 2];
        }
        float ss = 0.f, ipv[16];
        #pragma unroll
        for (int ci = 0; ci < 4; ++ci)
            #pragma unroll
            for (int ck = 0; ck < 4; ++ck) {
                const float v = d[ci][0]*d[ck][0] + d[ci][1]*d[ck][1] + d[ci][2]*d[ck][2];
                ipv[ci * 4 + ck] = v; ss += v * v;
            }
        const float inrm = 1.0f / fmaxf(sqrtf(ss), 1e-8f);
        #pragma unroll
        for (int i = 0; i < 16; ++i) ipB[t * 16 + i] = f2b(ipv[i] * inrm);
        #pragma unroll
        for (int ch = 0; ch < 4; ++ch) {
            const float nn = sqrtf(d[ch][0]*d[ch][0] + d[ch][1]*d[ch][1] + d[ch][2]*d[ch][2]);
            const float s = 1.0f / fmaxf(nn, 1e-8f);
            dnS[t][ch * 3 + 0] = d[ch][0] * s;
            dnS[t][ch * 3 + 1] = d[ch][1] * s;
            dnS[t][ch * 3 + 2] = d[ch][2] * s;
        }
    }
    __syncthreads();

    // per-lane A row pointers for cm1 (4 m-tiles)
    const ushort* nA[4]; const ushort* vA[4];
    #pragma unroll
    for (int mt = 0; mt < 4; ++mt) {
        nA[mt] = nfsb + (size_t)rowi[mt * 16 + lr] * SDIM + lk * 8;
        vA[mt] = vnb  + (size_t)coli[mt * 16 + lr] * HDIM + lk * 8;
    }
    const ushort* w1t = wb + OW1;

    f32x4 acc[4][2];

    // ===== cm layer 1 (K=416: 128 nfs | 256 vn | 16 ip | 16 zero) =====
    #pragma unroll
    for (int mt = 0; mt < 4; ++mt)
        #pragma unroll
        for (int nt = 0; nt < 2; ++nt) acc[mt][nt] = (f32x4)0.f;
    #pragma unroll
    for (int ks = 0; ks < 13; ++ks) {
        bf16x8 a_[4];
        #pragma unroll
        for (int mt = 0; mt < 4; ++mt) {
            if (ks < 4)       a_[mt] = *(const bf16x8*)(nA[mt] + ks * 32);
            else if (ks < 12) a_[mt] = *(const bf16x8*)(vA[mt] + ks * 32 - 128);
            else if (lk < 2)  a_[mt] = *(const bf16x8*)&ipB[(mt * 16 + lr) * 16 + lk * 8];
            else              a_[mt] = (bf16x8)(short)0;
        }
        #pragma unroll
        for (int nt = 0; nt < 2; ++nt) {
            const bf16x8 b = *(const bf16x8*)&w1t[(size_t)(((wv * 2 + nt) * 13 + ks) * 512) + lane * 8];
            #pragma unroll
            for (int mt = 0; mt < 4; ++mt)
                acc[mt][nt] = __builtin_amdgcn_mfma_f32_16x16x32_bf16(a_[mt], b, acc[mt][nt], 0, 0, 0);
        }
    }
    EPI_SILU2(Hd, b1);
    __syncthreads();

    // ===== cm layer 2 -> msg =====
    KLOOP2(Hd, wb + OW2);
    #pragma unroll
    for (int nt = 0; nt < 2; ++nt) {
        const int col = colBase + nt * 16 + lr;
        const float bb = b2[col];
        #pragma unroll
        for (int mt = 0; mt < 4; ++mt)
            #pragma unroll
            for (int r = 0; r < 4; ++r) {
                const int row = mt * 16 + lk * 4 + r;
                Mg[row * MSTR + col] = f2b(acc[mt][nt][r] + bb);
            }
    }
    __syncthreads();

    // ===== segmented reduction msg -> agg_feat (two 32-row halves) =====
    {
        const int col = t & 255;
        const int r0 = (t >> 8) * 32;
        float s = 0.f;
        int prev = rowi[r0];
        for (int r = r0; r < r0 + 32; ++r) {
            const int rr = rowi[r];
            if (rr != prev) {
                atomicAdd(&agg_feat[(size_t)prev * HDIM + col], s);
                s = 0.f; prev = rr;
            }
            s += b2f(Mg[r * MSTR + col]);
        }
        atomicAdd(&agg_feat[(size_t)prev * HDIM + col], s);
    }

    // ===== vr layer 1 =====
    KLOOP2(Mg, wb + OVR1);
    EPI_SILU2(Hd, vrb1);
    __syncthreads();

    // ===== vr layer 2 (waves 0 and 4, each a 32-row half) =====
    if ((wv & 3) == 0) {
        const int rb = (wv >> 2) * 32;
        const ushort* vrw2t = wb + OVR2;
        f32x4 a2[2]; a2[0] = (f32x4)0.f; a2[1] = (f32x4)0.f;
        #pragma unroll
        for (int ks = 0; ks < 8; ++ks) {
            const bf16x8 a0 = *(const bf16x8*)&Hd[(rb + lr) * MSTR + ks * 32 + lk * 8];
            const bf16x8 a1 = *(const bf16x8*)&Hd[(rb + 16 + lr) * MSTR + ks * 32 + lk * 8];
            const bf16x8 b  = *(const bf16x8*)&vrw2t[(size_t)(ks * 512) + lane * 8];
            a2[0] = __builtin_amdgcn_mfma_f32_16x16x32_bf16(a0, b, a2[0], 0, 0, 0);
            a2[1] = __builtin_amdgcn_mfma_f32_16x16x32_bf16(a1, b, a2[1], 0, 0, 0);
        }
        if (lr < 4) {
            const float bb = vrb2[lr];
            #pragma unroll
            for (int mt = 0; mt < 2; ++mt)
                #pragma unroll
                for (int r = 0; r < 4; ++r)
                    wvrS[rb + mt * 16 + lk * 4 + r][lr] = a2[mt][r] + bb;
        }
    }
    __syncthreads();

    // ===== rv layer 1 =====
    KLOOP2(Mg, wb + ORV1);
    EPI_SILU2(Hd, rvb1);
    __syncthreads();

    // ===== rv layer 2 (waves 0 and 4) =====
    if ((wv & 3) == 0) {
        const int rb = (wv >> 2) * 32;
        const ushort* rvw2t = wb + ORV2;
        f32x4 a2[2]; a2[0] = (f32x4)0.f; a2[1] = (f32x4)0.f;
        #pragma unroll
        for (int ks = 0; ks < 8; ++ks) {
            const bf16x8 a0 = *(const bf16x8*)&Hd[(rb + lr) * MSTR + ks * 32 + lk * 8];
            const bf16x8 a1 = *(const bf16x8*)&Hd[(rb + 16 + lr) * MSTR + ks * 32 + lk * 8];
            const bf16x8 b  = *(const bf16x8*)&rvw2t[(size_t)(ks * 512) + lane * 8];
            a2[0] = __builtin_amdgcn_mfma_f32_16x16x32_bf16(a0, b, a2[0], 0, 0, 0);
            a2[1] = __builtin_amdgcn_mfma_f32_16x16x32_bf16(a1, b, a2[1], 0, 0, 0);
        }
        const float bb = rvb2[lr];
        #pragma unroll
        for (int mt = 0; mt < 2; ++mt)
            #pragma unroll
            for (int r = 0; r < 4; ++r)
                wrvS[rb + mt * 16 + lk * 4 + r][lr] = a2[mt][r] + bb;
    }
    __syncthreads();

    // ===== per-edge geometric update (t<64) =====
    if (t < 64) {
        float wvv[4], wrr[16], dn[12], ev[15];
        #pragma unroll
        for (int c = 0; c < 4; ++c)  wvv[c] = wvrS[t][c];
        #pragma unroll
        for (int i = 0; i < 16; ++i) wrr[i] = wrvS[t][i];
        #pragma unroll
        for (int i = 0; i < 12; ++i) dn[i]  = dnS[t][i];
        #pragma unroll
        for (int j = 0; j < 3; ++j) {
            float v = 0.f;
            #pragma unroll
            for (int c = 0; c < 4; ++c) v = fmaf(wvv[c], dn[c * 3 + j], v);
            ev[j] = 0.5f * v;
        }
        #pragma unroll
        for (int u = 0; u < 4; ++u)
            #pragma unroll
            for (int j = 0; j < 3; ++j) {
                float v = 0.f;
                #pragma unroll
                for (int c = 0; c < 4; ++c) v = fmaf(wrr[c * 4 + u], dn[c * 3 + j], v);
                ev[3 + u * 3 + j] = -0.5f * v;
            }
        #pragma unroll
        for (int i = 0; i < 15; ++i) wrvS[t][i] = ev[i];
    }
    __syncthreads();

    // ===== segmented reduction vr/rv (two halves: t<15, 256<=t<271) =====
    if ((t & 255) < 15 && t < 512) {
        const int comp = t & 255;
        if (t < 256 || t >= 256) {
            const int r0 = (t >> 8) * 32;
            float s = 0.f;
            int prev = rowi[r0];
            for (int r = r0; r < r0 + 32; ++r) {
                const int rr = rowi[r];
                if (rr != prev) {
                    if (comp < 3) atomicAdd(&agg_vr[(size_t)prev * 3 + comp], s);
                    else          atomicAdd(&agg_rv[(size_t)prev * 12 + (comp - 3)], s);
                    s = 0.f; prev = rr;
                }
                s += wrvS[r][comp];
            }
            if (comp < 3) atomicAdd(&agg_vr[(size_t)prev * 3 + comp], s);
            else          atomicAdd(&agg_rv[(size_t)prev * 12 + (comp - 3)], s);
        }
    }
}

// ---------------------------------------------------------------- k_node
// 32 nodes/block (625 blocks), 256 threads = 4 waves (round-8 form).
__global__ __launch_bounds__(256, 4) void k_node(
    const float* __restrict__ node_feat, const float* __restrict__ node_pos,
    const float* __restrict__ vn_feat, const float* __restrict__ vn_pos,
    const float* __restrict__ agg_feat, const float* __restrict__ agg_vr,
    const float* __restrict__ agg_rv, const float* __restrict__ cntf,
    const ushort* __restrict__ wb,
    const float* __restrict__ ftb1, const float* __restrict__ ftb2,
    const float* __restrict__ f2tb1, const float* __restrict__ f2tb2,
    const float* __restrict__ vfb1, const float* __restrict__ vfb2,
    float* __restrict__ out, int Nn)
{
    __shared__ ushort Ab[32 * MSTR];
    __shared__ ushort Hd[32 * MSTR];
    __shared__ float rc[32];
    const int t  = threadIdx.x;
    const int n0 = blockIdx.x * 32;
    const int wv = t >> 6;
    const int lane = t & 63;
    const int lr = lane & 15;
    const int lk = lane >> 4;
    const int colBase = wv * 64;

    float* nf_out = out;
    float* np_out = out + (size_t)Nn * FEAT;
    float* vf_out = np_out + (size_t)Nn * 3;
    float* vp_out = vf_out + (size_t)Nn * HDIM;

    if (t < 32) rc[t] = 1.0f / fmaxf(cntf[n0 + t], 1.0f);
    __syncthreads();
    #pragma unroll
    for (int i = 0; i < 8; ++i) {
        const int p = t + i * 256;
        const int r = p >> 6, cc = (p & 63) * 4;
        float4 v = *(const float4*)&agg_feat[(size_t)(n0 + r) * HDIM + cc];
        const float s = rc[r];
        ushort4 o;
        o.x = f2b(v.x * s); o.y = f2b(v.y * s);
        o.z = f2b(v.z * s); o.w = f2b(v.w * s);
        *(ushort4*)&Ab[r * MSTR + cc] = o;
    }
    __syncthreads();

    f32x4 accn[2][4];

    // ---- vf MLP ----
    KLOOP_FR(Ab, wb + OVF1);
    EPI_SILUN(Hd, vfb1);
    __syncthreads();
    KLOOP_FR(Hd, wb + OVF2);
    #pragma unroll
    for (int nt = 0; nt < 4; ++nt) {
        const int col = colBase + nt * 16 + lr;
        const float bb = vfb2[col];
        #pragma unroll
        for (int mt = 0; mt < 2; ++mt)
            #pragma unroll
            for (int r = 0; r < 4; ++r) {
                const int row = mt * 16 + lk * 4 + r;
                const size_t o = (size_t)(n0 + row) * HDIM + col;
                vf_out[o] = vn_feat[o] + accn[mt][nt][r] + bb;
            }
    }
    __syncthreads();

    // ---- ft MLP ----
    KLOOP_FR(Ab, wb + OFT1);
    EPI_SILUN(Hd, ftb1);
    __syncthreads();
    KLOOP_FR(Hd, wb + OFT2);
    #pragma unroll
    for (int nt = 0; nt < 4; ++nt) {
        const int col = colBase + nt * 16 + lr;
        const float bb = ftb2[col];
        #pragma unroll
        for (int mt = 0; mt < 2; ++mt)
            #pragma unroll
            for (int r = 0; r < 4; ++r) {
                const int row = mt * 16 + lk * 4 + r;
                Ab[row * MSTR + col] = f2b(accn[mt][nt][r] + bb);
            }
    }
    __syncthreads();

    // ---- f2t MLP ----
    KLOOP_FR(Ab, wb + OF2T1);
    EPI_SILUN(Hd, f2tb1);
    __syncthreads();
    {
        const ushort* w2p = wb + OF2T2;
        f32x4 a2[2][2];
        #pragma unroll
        for (int mt = 0; mt < 2; ++mt)
            #pragma unroll
            for (int nt = 0; nt < 2; ++nt) a2[mt][nt] = (f32x4)0.f;
        #pragma unroll
        for (int ks = 0; ks < 8; ++ks) {
            const int k0 = ks * 32 + lk * 8;
            const bf16x8 a0 = *(const bf16x8*)&Hd[lr * MSTR + k0];
            const bf16x8 a1 = *(const bf16x8*)&Hd[(lr + 16) * MSTR + k0];
            const bf16x8 w0 = *(const bf16x8*)&w2p[(size_t)(((wv * 2 + 0) * 8 + ks) * 512) + lane * 8];
            const bf16x8 w1v = *(const bf16x8*)&w2p[(size_t)(((wv * 2 + 1) * 8 + ks) * 512) + lane * 8];
            a2[0][0] = __builtin_amdgcn_mfma_f32_16x16x32_bf16(a0, w0, a2[0][0], 0, 0, 0);
            a2[1][0] = __builtin_amdgcn_mfma_f32_16x16x32_bf16(a1, w0, a2[1][0], 0, 0, 0);
            a2[0][1] = __builtin_amdgcn_mfma_f32_16x16x32_bf16(a0, w1v, a2[0][1], 0, 0, 0);
            a2[1][1] = __builtin_amdgcn_mfma_f32_16x16x32_bf16(a1, w1v, a2[1][1], 0, 0, 0);
        }
        #pragma unroll
        for (int nt = 0; nt < 2; ++nt) {
            const int col = wv * 32 + nt * 16 + lr;
            const float bb = f2tb2[col];
            #pragma unroll
            for (int mt = 0; mt < 2; ++mt)
                #pragma unroll
                for (int r = 0; r < 4; ++r) {
                    const int row = mt * 16 + lk * 4 + r;
                    const size_t o = (size_t)(n0 + row) * FEAT + col;
                    nf_out[o] = node_feat[o] + a2[mt][nt][r] + bb;
                }
        }
    }

    // passthrough cols 128..479
    for (int p = t; p < 32 * 88; p += 256) {
        const int r = p / 88;
        const int cc = 128 + (p % 88) * 4;
        const size_t o = (size_t)(n0 + r) * FEAT + cc;
        *(float4*)&nf_out[o] = *(const float4*)&node_feat[o];
    }
    if (t < 32) {
        const int n = n0 + t;
        const float s = rc[t];
        #pragma unroll
        for (int j = 0; j < 3; ++j)
            np_out[(size_t)n * 3 + j] = node_pos[(size_t)n * 3 + j] + agg_vr[(size_t)n * 3 + j] * s;
        #pragma unroll
        for (int j = 0; j < 12; ++j)
            vp_out[(size_t)n * 12 + j] = vn_pos[(size_t)n * 12 + j] + agg_rv[(size_t)n * 12 + j] * s;
    }
}

// ---------------------------------------------------------------- launch
extern "C" void kernel_launch(void* const* d_in, const int* in_sizes, int n_in,
                              void* d_out, int out_size, void* d_ws, size_t ws_size,
                              hipStream_t stream)
{
    (void)n_in; (void)out_size; (void)ws_size;
    const float* node_feat = (const float*)d_in[0];
    const float* node_pos  = (const float*)d_in[1];
    const float* vn_feat   = (const float*)d_in[2];
    const float* vn_pos    = (const float*)d_in[3];
    const int*   eidx      = (const int*)d_in[4];
    const float* w_scalar  = (const float*)d_in[5];
    const float* cm_w1  = (const float*)d_in[6];
    const float* cm_b1  = (const float*)d_in[7];
    const float* cm_w2  = (const float*)d_in[8];
    const float* cm_b2  = (const float*)d_in[9];
    const float* vr_w1  = (const float*)d_in[10];
    const float* vr_b1  = (const float*)d_in[11];
    const float* vr_w2  = (const float*)d_in[12];
    const float* vr_b2  = (const float*)d_in[13];
    const float* rv_w1  = (const float*)d_in[14];
    const float* rv_b1  = (const float*)d_in[15];
    const float* rv_w2  = (const float*)d_in[16];
    const float* rv_b2  = (const float*)d_in[17];
    const float* ft_w1  = (const float*)d_in[18];
    const float* ft_b1  = (const float*)d_in[19];
    const float* ft_w2  = (const float*)d_in[20];
    const float* ft_b2  = (const float*)d_in[21];
    const float* f2t_w1 = (const float*)d_in[22];
    const float* f2t_b1 = (const float*)d_in[23];
    const float* f2t_w2 = (const float*)d_in[24];
    const float* f2t_b2 = (const float*)d_in[25];
    const float* vf_w1  = (const float*)d_in[26];
    const float* vf_b1  = (const float*)d_in[27];
    const float* vf_w2  = (const float*)d_in[28];
    const float* vf_b2  = (const float*)d_in[29];

    const int Nn = in_sizes[0] / FEAT;        // 20000
    const int E  = in_sizes[4] / 2;           // 240000

    // workspace layout
    float* ws       = (float*)d_ws;
    float* agg_feat = ws;                                // Nn*256 (zeroed)
    float* agg_vr   = agg_feat + (size_t)Nn * HDIM;      // Nn*3   (zeroed)
    float* agg_rv   = agg_vr   + (size_t)Nn * 3;         // Nn*12  (zeroed)
    float* cntf     = agg_rv   + (size_t)Nn * 12;        // Nn     (zeroed)
    int*   cnt_i    = (int*)(cntf + Nn);                 // Nn     (zeroed)
    int*   cursor   = cnt_i + Nn;                        // Nn     (zeroed)
    int*   rowstart = cursor + Nn;                       // Nn+16
    int*   elist    = rowstart + Nn + 16;                // E
    ushort* nfsb = (ushort*)(elist + E);                 // Nn*128
    ushort* vnb  = nfsb + (size_t)Nn * SDIM;             // Nn*256
    ushort* wb   = vnb  + (size_t)Nn * HDIM;             // OWTOT

    const size_t zero_bytes = (size_t)Nn * (HDIM + 3 + 12 + 1 + 2) * sizeof(float);
    hipMemsetAsync(agg_feat, 0, zero_bytes, stream);

    const int eg = (E + 255) / 256;
    k_count<<<eg, 256, 0, stream>>>(eidx, cnt_i, E);
    k_scan<<<1, 1024, 0, stream>>>(cnt_i, rowstart, cntf, Nn);
    k_place<<<eg, 256, 0, stream>>>(eidx, rowstart, cursor, elist, E);
    k_wprep<<<(OWTOT + 255) / 256, 256, 0, stream>>>(
        cm_w1, cm_w2, vr_w1, rv_w1, vr_w2, rv_w2,
        ft_w1, ft_w2, f2t_w1, f2t_w2, vf_w1, vf_w2, wb);
    k_vnb<<<(Nn * 64 + 255) / 256, 256, 0, stream>>>(vn_feat, vnb, Nn * 64);
    k_nfs<<<Nn / 32, 256, 0, stream>>>(node_feat, w_scalar, nfsb);
    k_edge<<<E / 64, 512, 0, stream>>>(nfsb, vnb, node_pos, vn_pos, eidx, elist,
                                       wb, cm_b1, cm_b2, vr_b1, vr_b2, rv_b1, rv_b2,
                                       agg_feat, agg_vr, agg_rv, E);
    k_node<<<Nn / 32, 256, 0, stream>>>(node_feat, node_pos, vn_feat, vn_pos,
                                        agg_feat, agg_vr, agg_rv, cntf, wb,
                                        ft_b1, ft_b2, f2t_b1, f2t_b2, vf_b1, vf_b2,
                                        (float*)d_out, Nn);
}

// Round 10
// 467.651 us; speedup vs baseline: 3.0154x; 1.0460x over previous
//
#include <hip/hip_runtime.h>
#include <hip/hip_bf16.h>
#include <math.h>

// VNLayer: N=20000 nodes, E=240000 edges, H=256, SD=128, C=4, FEAT=480
// Round 10: (1) k_edge: merge vr1+rv1 into one K-loop (shared A reads,
// accV/accR) and run vr2 (waves 0,4) CONCURRENTLY with rv2 (waves 1,5);
// rv-hidden overlays Mg. Removes one K-loop of LDS A-traffic + 2 phases.
// (2) parallel 3-kernel scan replaces the serial single-block k_scan.
// Frag-packed weights + 64-edge blocks from round 9 retained.

#define FEAT 480
#define HDIM 256
#define SDIM 128
#define MSTR 264    // LDS A row stride (ushorts)

// bf16 weight arena offsets (ushort elements) -- frag-packed regions
#define OW1   0          // cm1 : 16 nt x 13 ks x 512
#define OW2   106496     // cm2 : 16 x 8 x 512
#define OVR1  172032
#define ORV1  237568
#define OVR2  303104     // vr2 : 1 x 8 x 512 (cols>=4 zero)
#define ORV2  307200     // rv2 : 1 x 8 x 512
#define OFT1  311296
#define OFT2  376832
#define OF2T1 442368
#define OF2T2 507904     // f2t2: 8 nt x 8 ks x 512
#define OVF1  540672
#define OVF2  606208
#define OWTOT 671744

typedef __attribute__((ext_vector_type(8))) short bf16x8;
typedef __attribute__((ext_vector_type(4))) float f32x4;

__device__ __forceinline__ float silu_f(float x) {
    return x / (1.0f + __expf(-x));
}
__device__ __forceinline__ ushort f2b(float v) {
    __hip_bfloat16 h = __float2bfloat16(v);
    return *(ushort*)&h;
}
__device__ __forceinline__ float b2f(ushort u) {
    union { unsigned int i; float f; } c;
    c.i = ((unsigned int)u) << 16;
    return c.f;
}

// k_edge K=256 GEMM: 4 m-tiles x 2 n-tiles per wave. A from LDS, B frag-packed.
#define KLOOP2(SRC, WP)                                                        \
    {                                                                          \
        _Pragma("unroll")                                                      \
        for (int mt = 0; mt < 4; ++mt)                                         \
            _Pragma("unroll")                                                  \
            for (int nt = 0; nt < 2; ++nt) acc[mt][nt] = (f32x4)0.f;           \
        _Pragma("unroll")                                                      \
        for (int ks = 0; ks < 8; ++ks) {                                       \
            bf16x8 a_[4];                                                      \
            _Pragma("unroll")                                                  \
            for (int mt = 0; mt < 4; ++mt)                                     \
                a_[mt] = *(const bf16x8*)&(SRC)[(mt * 16 + lr) * MSTR + ks * 32 + lk * 8]; \
            _Pragma("unroll")                                                  \
            for (int nt = 0; nt < 2; ++nt) {                                   \
                const bf16x8 b = *(const bf16x8*)&(WP)[(size_t)(((wv * 2 + nt) * 8 + ks) * 512) + lane * 8]; \
                _Pragma("unroll")                                              \
                for (int mt = 0; mt < 4; ++mt)                                 \
                    acc[mt][nt] = __builtin_amdgcn_mfma_f32_16x16x32_bf16(a_[mt], b, acc[mt][nt], 0, 0, 0); \
            }                                                                  \
        }                                                                      \
    }

#define EPI_SILU2(DST, BIAS)                                                   \
    _Pragma("unroll")                                                          \
    for (int nt = 0; nt < 2; ++nt) {                                           \
        const int col = colBase + nt * 16 + lr;                                \
        const float bb = (BIAS)[col];                                          \
        _Pragma("unroll")                                                      \
        for (int mt = 0; mt < 4; ++mt)                                         \
            _Pragma("unroll")                                                  \
            for (int r = 0; r < 4; ++r) {                                      \
                const int row = mt * 16 + lk * 4 + r;                          \
                (DST)[row * MSTR + col] = f2b(silu_f(acc[mt][nt][r] + bb));    \
            }                                                                  \
    }

// k_node K=256 GEMM (round-8 form): 2 m-tiles x 4 n-tiles per wave.
#define KLOOP_FR(SRC, WP)                                                      \
    {                                                                          \
        _Pragma("unroll")                                                      \
        for (int mt = 0; mt < 2; ++mt)                                         \
            _Pragma("unroll")                                                  \
            for (int nt = 0; nt < 4; ++nt) accn[mt][nt] = (f32x4)0.f;          \
        _Pragma("unroll")                                                      \
        for (int ks = 0; ks < 8; ++ks) {                                       \
            const bf16x8 a0 = *(const bf16x8*)&(SRC)[lr * MSTR + ks * 32 + lk * 8];        \
            const bf16x8 a1 = *(const bf16x8*)&(SRC)[(lr + 16) * MSTR + ks * 32 + lk * 8]; \
            _Pragma("unroll")                                                  \
            for (int nt = 0; nt < 4; ++nt) {                                   \
                const bf16x8 b = *(const bf16x8*)&(WP)[(size_t)(((wv * 4 + nt) * 8 + ks) * 512) + lane * 8]; \
                accn[0][nt] = __builtin_amdgcn_mfma_f32_16x16x32_bf16(a0, b, accn[0][nt], 0, 0, 0); \
                accn[1][nt] = __builtin_amdgcn_mfma_f32_16x16x32_bf16(a1, b, accn[1][nt], 0, 0, 0); \
            }                                                                  \
        }                                                                      \
    }

#define EPI_SILUN(DST, BIAS)                                                   \
    _Pragma("unroll")                                                          \
    for (int nt = 0; nt < 4; ++nt) {                                           \
        const int col = colBase + nt * 16 + lr;                                \
        const float bb = (BIAS)[col];                                          \
        _Pragma("unroll")                                                      \
        for (int mt = 0; mt < 2; ++mt)                                         \
            _Pragma("unroll")                                                  \
            for (int r = 0; r < 4; ++r) {                                      \
                const int row = mt * 16 + lk * 4 + r;                          \
                (DST)[row * MSTR + col] = f2b(silu_f(accn[mt][nt][r] + bb));   \
            }                                                                  \
    }

// ---------------------------------------------------------------- CSR build
__global__ __launch_bounds__(256) void k_count(
    const int* __restrict__ eidx, int* __restrict__ cnt_i, int E)
{
    const int e = blockIdx.x * 256 + threadIdx.x;
    if (e < E) atomicAdd(&cnt_i[eidx[e]], 1);
}

// parallel scan: A (per-block inclusive scan + block sums), B (scan sums),
// C (add offsets). rowstart[i+1] = inclusive prefix; rowstart[0] = 0.
__global__ __launch_bounds__(1024) void k_scanA(
    const int* __restrict__ cnt_i, int* __restrict__ rowstart,
    float* __restrict__ cntf, int* __restrict__ bsum, int Nn)
{
    __shared__ int sh[1024];
    const int t = threadIdx.x;
    const int i = blockIdx.x * 1024 + t;
    const int v = (i < Nn) ? cnt_i[i] : 0;
    sh[t] = v;
    __syncthreads();
    for (int off = 1; off < 1024; off <<= 1) {
        const int add = (t >= off) ? sh[t - off] : 0;
        __syncthreads();
        sh[t] += add;
        __syncthreads();
    }
    if (i < Nn) {
        rowstart[i + 1] = sh[t];
        cntf[i] = fmaxf((float)v, 1.0f);
    }
    if (t == 1023) bsum[blockIdx.x] = sh[t];
}

__global__ __launch_bounds__(64) void k_scanB(int* __restrict__ bsum, int nb)
{
    if (threadIdx.x == 0) {
        int s = 0;
        for (int i = 0; i < nb; ++i) { const int v = bsum[i]; bsum[i] = s; s += v; }
    }
}

__global__ __launch_bounds__(1024) void k_scanC(
    int* __restrict__ rowstart, const int* __restrict__ bsum, int Nn)
{
    const int i = blockIdx.x * 1024 + threadIdx.x;
    if (i < Nn) rowstart[i + 1] += bsum[blockIdx.x];
    if (i == 0) rowstart[0] = 0;
}

__global__ __launch_bounds__(256) void k_place(
    const int* __restrict__ eidx, const int* __restrict__ rowstart,
    int* __restrict__ cursor, int* __restrict__ elist, int E)
{
    const int e = blockIdx.x * 256 + threadIdx.x;
    if (e < E) {
        const int r = eidx[e];
        const int p = atomicAdd(&cursor[r], 1);
        elist[rowstart[r] + p] = e;
    }
}

// ---------------------------------------------------------------- k_wprep
__global__ __launch_bounds__(256) void k_wprep(
    const float* __restrict__ w1, const float* __restrict__ w2,
    const float* __restrict__ vrw1, const float* __restrict__ rvw1,
    const float* __restrict__ vrw2, const float* __restrict__ rvw2,
    const float* __restrict__ ftw1, const float* __restrict__ ftw2,
    const float* __restrict__ f2tw1, const float* __restrict__ f2tw2,
    const float* __restrict__ vfw1, const float* __restrict__ vfw2,
    ushort* __restrict__ wb)
{
    const int idx = blockIdx.x * 256 + threadIdx.x;
    if (idx >= OWTOT) return;
    ushort v;
    if (idx < OW2) {
        const int o = idx, f = o >> 9, l = (o >> 3) & 63, e = o & 7;
        const int nt = f / 13, ks = f % 13;
        const int col = nt * 16 + (l & 15);
        const int k = ks * 32 + ((l >> 4) << 3) + e;
        v = (k < 400) ? f2b(w1[(size_t)k * 256 + col]) : (ushort)0;
    } else if (idx < OVR1) {
        const int o = idx - OW2, f = o >> 9, l = (o >> 3) & 63, e = o & 7;
        const int col = (f >> 3) * 16 + (l & 15);
        const int k = (f & 7) * 32 + ((l >> 4) << 3) + e;
        v = f2b(w2[(size_t)k * 256 + col]);
    } else if (idx < ORV1) {
        const int o = idx - OVR1, f = o >> 9, l = (o >> 3) & 63, e = o & 7;
        const int col = (f >> 3) * 16 + (l & 15);
        const int k = (f & 7) * 32 + ((l >> 4) << 3) + e;
        v = f2b(vrw1[(size_t)k * 256 + col]);
    } else if (idx < OVR2) {
        const int o = idx - ORV1, f = o >> 9, l = (o >> 3) & 63, e = o & 7;
        const int col = (f >> 3) * 16 + (l & 15);
        const int k = (f & 7) * 32 + ((l >> 4) << 3) + e;
        v = f2b(rvw1[(size_t)k * 256 + col]);
    } else if (idx < ORV2) {
        const int o = idx - OVR2, f = o >> 9, l = (o >> 3) & 63, e = o & 7;
        const int col = l & 15;
        const int k = f * 32 + ((l >> 4) << 3) + e;
        v = (col < 4) ? f2b(vrw2[(size_t)k * 4 + col]) : (ushort)0;
    } else if (idx < OFT1) {
        const int o = idx - ORV2, f = o >> 9, l = (o >> 3) & 63, e = o & 7;
        const int col = l & 15;
        const int k = f * 32 + ((l >> 4) << 3) + e;
        v = f2b(rvw2[(size_t)k * 16 + col]);
    } else if (idx < OFT2) {
        const int o = idx - OFT1, f = o >> 9, l = (o >> 3) & 63, e = o & 7;
        const int col = (f >> 3) * 16 + (l & 15);
        const int k = (f & 7) * 32 + ((l >> 4) << 3) + e;
        v = f2b(ftw1[(size_t)k * 256 + col]);
    } else if (idx < OF2T1) {
        const int o = idx - OFT2, f = o >> 9, l = (o >> 3) & 63, e = o & 7;
        const int col = (f >> 3) * 16 + (l & 15);
        const int k = (f & 7) * 32 + ((l >> 4) << 3) + e;
        v = f2b(ftw2[(size_t)k * 256 + col]);
    } else if (idx < OF2T2) {
        const int o = idx - OF2T1, f = o >> 9, l = (o >> 3) & 63, e = o & 7;
        const int col = (f >> 3) * 16 + (l & 15);
        const int k = (f & 7) * 32 + ((l >> 4) << 3) + e;
        v = f2b(f2tw1[(size_t)k * 256 + col]);
    } else if (idx < OVF1) {
        const int o = idx - OF2T2, f = o >> 9, l = (o >> 3) & 63, e = o & 7;
        const int col = (f >> 3) * 16 + (l & 15);
        const int k = (f & 7) * 32 + ((l >> 4) << 3) + e;
        v = f2b(f2tw2[(size_t)k * 128 + col]);
    } else if (idx < OVF2) {
        const int o = idx - OVF1, f = o >> 9, l = (o >> 3) & 63, e = o & 7;
        const int col = (f >> 3) * 16 + (l & 15);
        const int k = (f & 7) * 32 + ((l >> 4) << 3) + e;
        v = f2b(vfw1[(size_t)k * 256 + col]);
    } else {
        const int o = idx - OVF2, f = o >> 9, l = (o >> 3) & 63, e = o & 7;
        const int col = (f >> 3) * 16 + (l & 15);
        const int k = (f & 7) * 32 + ((l >> 4) << 3) + e;
        v = f2b(vfw2[(size_t)k * 256 + col]);
    }
    wb[idx] = v;
}

// ---------------------------------------------------------------- k_vnb
__global__ __launch_bounds__(256) void k_vnb(
    const float* __restrict__ vn_feat, ushort* __restrict__ vnb, int total4)
{
    const int i = blockIdx.x * 256 + threadIdx.x;
    if (i >= total4) return;
    const float4 v = *(const float4*)&vn_feat[(size_t)i * 4];
    ushort4 o;
    o.x = f2b(v.x); o.y = f2b(v.y); o.z = f2b(v.z); o.w = f2b(v.w);
    *(ushort4*)&vnb[(size_t)i * 4] = o;
}

// ---------------------------------------------------------------- k_nfs
__global__ __launch_bounds__(256) void k_nfs(
    const float* __restrict__ node_feat, const float* __restrict__ w_scalar,
    ushort* __restrict__ nfsb)
{
    __shared__ float At[32][20];
    __shared__ float Wt[16][128];
    const int t  = threadIdx.x;
    const int m0 = blockIdx.x * 32;
    const int c4 = (t & 31) * 4;
    const int rg = t >> 5;
    float acc[4][4] = {};
    for (int k0 = 0; k0 < 128; k0 += 16) {
        if (t < 128) {
            const int r = t >> 2, kk = (t & 3) * 4;
            *(float4*)&At[r][kk] =
                *(const float4*)&node_feat[(size_t)(m0 + r) * FEAT + k0 + kk];
        }
        #pragma unroll
        for (int i = 0; i < 2; ++i) {
            const int p  = t + i * 256;
            const int wr = p >> 5, wc = (p & 31) * 4;
            *(float4*)&Wt[wr][wc] =
                *(const float4*)&w_scalar[(size_t)(k0 + wr) * SDIM + wc];
        }
        __syncthreads();
        #pragma unroll
        for (int kk = 0; kk < 16; ++kk) {
            const float4 w = *(const float4*)&Wt[kk][c4];
            #pragma unroll
            for (int j = 0; j < 4; ++j) {
                const float a = At[rg * 4 + j][kk];
                acc[j][0] = fmaf(a, w.x, acc[j][0]);
                acc[j][1] = fmaf(a, w.y, acc[j][1]);
                acc[j][2] = fmaf(a, w.z, acc[j][2]);
                acc[j][3] = fmaf(a, w.w, acc[j][3]);
            }
        }
        __syncthreads();
    }
    const float s = 0.08838834764831845f;
    #pragma unroll
    for (int j = 0; j < 4; ++j) {
        ushort4 o;
        o.x = f2b(acc[j][0] * s); o.y = f2b(acc[j][1] * s);
        o.z = f2b(acc[j][2] * s); o.w = f2b(acc[j][3] * s);
        *(ushort4*)&nfsb[(size_t)(m0 + rg * 4 + j) * SDIM + c4] = o;
    }
}

// ---------------------------------------------------------------- k_edge
// 64 row-sorted edges/block, 512 threads = 8 waves. LDS 78.3KB -> 2 blk/CU.
__global__ __launch_bounds__(512, 4) void k_edge(
    const ushort* __restrict__ nfsb, const ushort* __restrict__ vnb,
    const float* __restrict__ node_pos, const float* __restrict__ vn_pos,
    const int* __restrict__ eidx, const int* __restrict__ elist,
    const ushort* __restrict__ wb,
    const float* __restrict__ b1, const float* __restrict__ b2,
    const float* __restrict__ vrb1, const float* __restrict__ vrb2,
    const float* __restrict__ rvb1, const float* __restrict__ rvb2,
    float* __restrict__ agg_feat, float* __restrict__ agg_vr,
    float* __restrict__ agg_rv, int E)
{
    __shared__ ushort Mg[64 * MSTR];   // msg; later rv-hidden overlay
    __shared__ ushort Hd[64 * MSTR];   // cm hidden, then vr hidden
    __shared__ ushort ipB[64 * 16];
    __shared__ float dnS[64][12];
    __shared__ float wvrS[64][4];
    __shared__ float wrvS[64][16];
    __shared__ int rowi[64], coli[64];

    const int t  = threadIdx.x;
    const int e0 = blockIdx.x * 64;
    const int wv = t >> 6;             // 0..7
    const int lane = t & 63;
    const int lr = lane & 15;
    const int lk = lane >> 4;
    const int colBase = wv * 32;       // 2 n-tiles per wave

    // ---- geometry (t<64), row-sorted edges ----
    if (t < 64) {
        const int e = elist[e0 + t];
        const int r = eidx[e];
        const int c = eidx[E + e];
        rowi[t] = r; coli[t] = c;
        const float px = node_pos[r * 3 + 0];
        const float py = node_pos[r * 3 + 1];
        const float pz = node_pos[r * 3 + 2];
        float d[4][3];
        #pragma unroll
        for (int ch = 0; ch < 4; ++ch) {
            d[ch][0] = px - vn_pos[(size_t)c * 12 + ch * 3 + 0];
            d[ch][1] = py - vn_pos[(size_t)c * 12 + ch * 3 + 1];
            d[ch][2] = pz - vn_pos[(size_t)c * 12 + ch * 3 + 2];
        }
        float ss = 0.f, ipv[16];
        #pragma unroll
        for (int ci = 0; ci < 4; ++ci)
            #pragma unroll
            for (int ck = 0; ck < 4; ++ck) {
                const float v = d[ci][0]*d[ck][0] + d[ci][1]*d[ck][1] + d[ci][2]*d[ck][2];
                ipv[ci * 4 + ck] = v; ss += v * v;
            }
        const float inrm = 1.0f / fmaxf(sqrtf(ss), 1e-8f);
        #pragma unroll
        for (int i = 0; i < 16; ++i) ipB[t * 16 + i] = f2b(ipv[i] * inrm);
        #pragma unroll
        for (int ch = 0; ch < 4; ++ch) {
            const float nn = sqrtf(d[ch][0]*d[ch][0] + d[ch][1]*d[ch][1] + d[ch][2]*d[ch][2]);
            const float s = 1.0f / fmaxf(nn, 1e-8f);
            dnS[t][ch * 3 + 0] = d[ch][0] * s;
            dnS[t][ch * 3 + 1] = d[ch][1] * s;
            dnS[t][ch * 3 + 2] = d[ch][2] * s;
        }
    }
    __syncthreads();

    // per-lane A row pointers for cm1 (4 m-tiles)
    const ushort* nA[4]; const ushort* vA[4];
    #pragma unroll
    for (int mt = 0; mt < 4; ++mt) {
        nA[mt] = nfsb + (size_t)rowi[mt * 16 + lr] * SDIM + lk * 8;
        vA[mt] = vnb  + (size_t)coli[mt * 16 + lr] * HDIM + lk * 8;
    }
    const ushort* w1t = wb + OW1;

    f32x4 acc[4][2];

    // ===== cm layer 1 (K=416: 128 nfs | 256 vn | 16 ip | 16 zero) =====
    #pragma unroll
    for (int mt = 0; mt < 4; ++mt)
        #pragma unroll
        for (int nt = 0; nt < 2; ++nt) acc[mt][nt] = (f32x4)0.f;
    #pragma unroll
    for (int ks = 0; ks < 13; ++ks) {
        bf16x8 a_[4];
        #pragma unroll
        for (int mt = 0; mt < 4; ++mt) {
            if (ks < 4)       a_[mt] = *(const bf16x8*)(nA[mt] + ks * 32);
            else if (ks < 12) a_[mt] = *(const bf16x8*)(vA[mt] + ks * 32 - 128);
            else if (lk < 2)  a_[mt] = *(const bf16x8*)&ipB[(mt * 16 + lr) * 16 + lk * 8];
            else              a_[mt] = (bf16x8)(short)0;
        }
        #pragma unroll
        for (int nt = 0; nt < 2; ++nt) {
            const bf16x8 b = *(const bf16x8*)&w1t[(size_t)(((wv * 2 + nt) * 13 + ks) * 512) + lane * 8];
            #pragma unroll
            for (int mt = 0; mt < 4; ++mt)
                acc[mt][nt] = __builtin_amdgcn_mfma_f32_16x16x32_bf16(a_[mt], b, acc[mt][nt], 0, 0, 0);
        }
    }
    EPI_SILU2(Hd, b1);
    __syncthreads();

    // ===== cm layer 2 -> msg =====
    KLOOP2(Hd, wb + OW2);
    #pragma unroll
    for (int nt = 0; nt < 2; ++nt) {
        const int col = colBase + nt * 16 + lr;
        const float bb = b2[col];
        #pragma unroll
        for (int mt = 0; mt < 4; ++mt)
            #pragma unroll
            for (int r = 0; r < 4; ++r) {
                const int row = mt * 16 + lk * 4 + r;
                Mg[row * MSTR + col] = f2b(acc[mt][nt][r] + bb);
            }
    }
    __syncthreads();

    // ===== segmented reduction msg -> agg_feat (two 32-row halves) =====
    {
        const int col = t & 255;
        const int r0 = (t >> 8) * 32;
        float s = 0.f;
        int prev = rowi[r0];
        for (int r = r0; r < r0 + 32; ++r) {
            const int rr = rowi[r];
            if (rr != prev) {
                atomicAdd(&agg_feat[(size_t)prev * HDIM + col], s);
                s = 0.f; prev = rr;
            }
            s += b2f(Mg[r * MSTR + col]);
        }
        atomicAdd(&agg_feat[(size_t)prev * HDIM + col], s);
    }

    // ===== vr + rv layer 1 (merged, shared A reads from Mg) =====
    {
        f32x4 accV[4][2], accR[4][2];
        #pragma unroll
        for (int mt = 0; mt < 4; ++mt)
            #pragma unroll
            for (int nt = 0; nt < 2; ++nt) { accV[mt][nt] = (f32x4)0.f; accR[mt][nt] = (f32x4)0.f; }
        #pragma unroll
        for (int ks = 0; ks < 8; ++ks) {
            bf16x8 a_[4];
            #pragma unroll
            for (int mt = 0; mt < 4; ++mt)
                a_[mt] = *(const bf16x8*)&Mg[(mt * 16 + lr) * MSTR + ks * 32 + lk * 8];
            #pragma unroll
            for (int nt = 0; nt < 2; ++nt) {
                const bf16x8 bv = *(const bf16x8*)&wb[OVR1 + (size_t)(((wv * 2 + nt) * 8 + ks) * 512) + lane * 8];
                #pragma unroll
                for (int mt = 0; mt < 4; ++mt)
                    accV[mt][nt] = __builtin_amdgcn_mfma_f32_16x16x32_bf16(a_[mt], bv, accV[mt][nt], 0, 0, 0);
                const bf16x8 br = *(const bf16x8*)&wb[ORV1 + (size_t)(((wv * 2 + nt) * 8 + ks) * 512) + lane * 8];
                #pragma unroll
                for (int mt = 0; mt < 4; ++mt)
                    accR[mt][nt] = __builtin_amdgcn_mfma_f32_16x16x32_bf16(a_[mt], br, accR[mt][nt], 0, 0, 0);
            }
        }
        __syncthreads();            // everyone done reading Mg
        #pragma unroll
        for (int nt = 0; nt < 2; ++nt) {
            const int col = colBase + nt * 16 + lr;
            const float bv = vrb1[col];
            const float br = rvb1[col];
            #pragma unroll
            for (int mt = 0; mt < 4; ++mt)
                #pragma unroll
                for (int r = 0; r < 4; ++r) {
                    const int row = mt * 16 + lk * 4 + r;
                    Hd[row * MSTR + col] = f2b(silu_f(accV[mt][nt][r] + bv));
                    Mg[row * MSTR + col] = f2b(silu_f(accR[mt][nt][r] + br));  // rv hidden
                }
        }
    }
    __syncthreads();

    // ===== vr2 (waves 0,4 from Hd) CONCURRENT with rv2 (waves 1,5 from Mg) =====
    if ((wv & 3) == 0) {
        const int rb = (wv >> 2) * 32;
        const ushort* vrw2t = wb + OVR2;
        f32x4 a2[2]; a2[0] = (f32x4)0.f; a2[1] = (f32x4)0.f;
        #pragma unroll
        for (int ks = 0; ks < 8; ++ks) {
            const bf16x8 a0 = *(const bf16x8*)&Hd[(rb + lr) * MSTR + ks * 32 + lk * 8];
            const bf16x8 a1 = *(const bf16x8*)&Hd[(rb + 16 + lr) * MSTR + ks * 32 + lk * 8];
            const bf16x8 b  = *(const bf16x8*)&vrw2t[(size_t)(ks * 512) + lane * 8];
            a2[0] = __builtin_amdgcn_mfma_f32_16x16x32_bf16(a0, b, a2[0], 0, 0, 0);
            a2[1] = __builtin_amdgcn_mfma_f32_16x16x32_bf16(a1, b, a2[1], 0, 0, 0);
        }
        if (lr < 4) {
            const float bb = vrb2[lr];
            #pragma unroll
            for (int mt = 0; mt < 2; ++mt)
                #pragma unroll
                for (int r = 0; r < 4; ++r)
                    wvrS[rb + mt * 16 + lk * 4 + r][lr] = a2[mt][r] + bb;
        }
    } else if ((wv & 3) == 1) {
        const int rb = (wv >> 2) * 32;
        const ushort* rvw2t = wb + ORV2;
        f32x4 a2[2]; a2[0] = (f32x4)0.f; a2[1] = (f32x4)0.f;
        #pragma unroll
        for (int ks = 0; ks < 8; ++ks) {
            const bf16x8 a0 = *(const bf16x8*)&Mg[(rb + lr) * MSTR + ks * 32 + lk * 8];
            const bf16x8 a1 = *(const bf16x8*)&Mg[(rb + 16 + lr) * MSTR + ks * 32 + lk * 8];
            const bf16x8 b  = *(const bf16x8*)&rvw2t[(size_t)(ks * 512) + lane * 8];
            a2[0] = __builtin_amdgcn_mfma_f32_16x16x32_bf16(a0, b, a2[0], 0, 0, 0);
            a2[1] = __builtin_amdgcn_mfma_f32_16x16x32_bf16(a1, b, a2[1], 0, 0, 0);
        }
        const float bb = rvb2[lr];
        #pragma unroll
        for (int mt = 0; mt < 2; ++mt)
            #pragma unroll
            for (int r = 0; r < 4; ++r)
                wrvS[rb + mt * 16 + lk * 4 + r][lr] = a2[mt][r] + bb;
    }
    __syncthreads();

    // ===== per-edge geometric update (t<64) =====
    if (t < 64) {
        float wvv[4], wrr[16], dn[12], ev[15];
        #pragma unroll
        for (int c = 0; c < 4; ++c)  wvv[c] = wvrS[t][c];
        #pragma unroll
        for (int i = 0; i < 16; ++i) wrr[i] = wrvS[t][i];
        #pragma unroll
        for (int i = 0; i < 12; ++i) dn[i]  = dnS[t][i];
        #pragma unroll
        for (int j = 0; j < 3; ++j) {
            float v = 0.f;
            #pragma unroll
            for (int c = 0; c < 4; ++c) v = fmaf(wvv[c], dn[c * 3 + j], v);
            ev[j] = 0.5f * v;
        }
        #pragma unroll
        for (int u = 0; u < 4; ++u)
            #pragma unroll
            for (int j = 0; j < 3; ++j) {
                float v = 0.f;
                #pragma unroll
                for (int c = 0; c < 4; ++c) v = fmaf(wrr[c * 4 + u], dn[c * 3 + j], v);
                ev[3 + u * 3 + j] = -0.5f * v;
            }
        #pragma unroll
        for (int i = 0; i < 15; ++i) wrvS[t][i] = ev[i];
    }
    __syncthreads();

    // ===== segmented reduction vr/rv (two halves) =====
    if ((t & 255) < 15) {
        const int comp = t & 255;
        const int r0 = (t >> 8) * 32;
        float s = 0.f;
        int prev = rowi[r0];
        for (int r = r0; r < r0 + 32; ++r) {
            const int rr = rowi[r];
            if (rr != prev) {
                if (comp < 3) atomicAdd(&agg_vr[(size_t)prev * 3 + comp], s);
                else          atomicAdd(&agg_rv[(size_t)prev * 12 + (comp - 3)], s);
                s = 0.f; prev = rr;
            }
            s += wrvS[r][comp];
        }
        if (comp < 3) atomicAdd(&agg_vr[(size_t)prev * 3 + comp], s);
        else          atomicAdd(&agg_rv[(size_t)prev * 12 + (comp - 3)], s);
    }
}

// ---------------------------------------------------------------- k_node
// 32 nodes/block (625 blocks), 256 threads = 4 waves (round-8 form).
__global__ __launch_bounds__(256, 4) void k_node(
    const float* __restrict__ node_feat, const float* __restrict__ node_pos,
    const float* __restrict__ vn_feat, const float* __restrict__ vn_pos,
    const float* __restrict__ agg_feat, const float* __restrict__ agg_vr,
    const float* __restrict__ agg_rv, const float* __restrict__ cntf,
    const ushort* __restrict__ wb,
    const float* __restrict__ ftb1, const float* __restrict__ ftb2,
    const float* __restrict__ f2tb1, const float* __restrict__ f2tb2,
    const float* __restrict__ vfb1, const float* __restrict__ vfb2,
    float* __restrict__ out, int Nn)
{
    __shared__ ushort Ab[32 * MSTR];
    __shared__ ushort Hd[32 * MSTR];
    __shared__ float rc[32];
    const int t  = threadIdx.x;
    const int n0 = blockIdx.x * 32;
    const int wv = t >> 6;
    const int lane = t & 63;
    const int lr = lane & 15;
    const int lk = lane >> 4;
    const int colBase = wv * 64;

    float* nf_out = out;
    float* np_out = out + (size_t)Nn * FEAT;
    float* vf_out = np_out + (size_t)Nn * 3;
    float* vp_out = vf_out + (size_t)Nn * HDIM;

    if (t < 32) rc[t] = 1.0f / fmaxf(cntf[n0 + t], 1.0f);
    __syncthreads();
    #pragma unroll
    for (int i = 0; i < 8; ++i) {
        const int p = t + i * 256;
        const int r = p >> 6, cc = (p & 63) * 4;
        float4 v = *(const float4*)&agg_feat[(size_t)(n0 + r) * HDIM + cc];
        const float s = rc[r];
        ushort4 o;
        o.x = f2b(v.x * s); o.y = f2b(v.y * s);
        o.z = f2b(v.z * s); o.w = f2b(v.w * s);
        *(ushort4*)&Ab[r * MSTR + cc] = o;
    }
    __syncthreads();

    f32x4 accn[2][4];

    // ---- vf MLP ----
    KLOOP_FR(Ab, wb + OVF1);
    EPI_SILUN(Hd, vfb1);
    __syncthreads();
    KLOOP_FR(Hd, wb + OVF2);
    #pragma unroll
    for (int nt = 0; nt < 4; ++nt) {
        const int col = colBase + nt * 16 + lr;
        const float bb = vfb2[col];
        #pragma unroll
        for (int mt = 0; mt < 2; ++mt)
            #pragma unroll
            for (int r = 0; r < 4; ++r) {
                const int row = mt * 16 + lk * 4 + r;
                const size_t o = (size_t)(n0 + row) * HDIM + col;
                vf_out[o] = vn_feat[o] + accn[mt][nt][r] + bb;
            }
    }
    __syncthreads();

    // ---- ft MLP ----
    KLOOP_FR(Ab, wb + OFT1);
    EPI_SILUN(Hd, ftb1);
    __syncthreads();
    KLOOP_FR(Hd, wb + OFT2);
    #pragma unroll
    for (int nt = 0; nt < 4; ++nt) {
        const int col = colBase + nt * 16 + lr;
        const float bb = ftb2[col];
        #pragma unroll
        for (int mt = 0; mt < 2; ++mt)
            #pragma unroll
            for (int r = 0; r < 4; ++r) {
                const int row = mt * 16 + lk * 4 + r;
                Ab[row * MSTR + col] = f2b(accn[mt][nt][r] + bb);
            }
    }
    __syncthreads();

    // ---- f2t MLP ----
    KLOOP_FR(Ab, wb + OF2T1);
    EPI_SILUN(Hd, f2tb1);
    __syncthreads();
    {
        const ushort* w2p = wb + OF2T2;
        f32x4 a2[2][2];
        #pragma unroll
        for (int mt = 0; mt < 2; ++mt)
            #pragma unroll
            for (int nt = 0; nt < 2; ++nt) a2[mt][nt] = (f32x4)0.f;
        #pragma unroll
        for (int ks = 0; ks < 8; ++ks) {
            const int k0 = ks * 32 + lk * 8;
            const bf16x8 a0 = *(const bf16x8*)&Hd[lr * MSTR + k0];
            const bf16x8 a1 = *(const bf16x8*)&Hd[(lr + 16) * MSTR + k0];
            const bf16x8 w0 = *(const bf16x8*)&w2p[(size_t)(((wv * 2 + 0) * 8 + ks) * 512) + lane * 8];
            const bf16x8 w1v = *(const bf16x8*)&w2p[(size_t)(((wv * 2 + 1) * 8 + ks) * 512) + lane * 8];
            a2[0][0] = __builtin_amdgcn_mfma_f32_16x16x32_bf16(a0, w0, a2[0][0], 0, 0, 0);
            a2[1][0] = __builtin_amdgcn_mfma_f32_16x16x32_bf16(a1, w0, a2[1][0], 0, 0, 0);
            a2[0][1] = __builtin_amdgcn_mfma_f32_16x16x32_bf16(a0, w1v, a2[0][1], 0, 0, 0);
            a2[1][1] = __builtin_amdgcn_mfma_f32_16x16x32_bf16(a1, w1v, a2[1][1], 0, 0, 0);
        }
        #pragma unroll
        for (int nt = 0; nt < 2; ++nt) {
            const int col = wv * 32 + nt * 16 + lr;
            const float bb = f2tb2[col];
            #pragma unroll
            for (int mt = 0; mt < 2; ++mt)
                #pragma unroll
                for (int r = 0; r < 4; ++r) {
                    const int row = mt * 16 + lk * 4 + r;
                    const size_t o = (size_t)(n0 + row) * FEAT + col;
                    nf_out[o] = node_feat[o] + a2[mt][nt][r] + bb;
                }
        }
    }

    // passthrough cols 128..479
    for (int p = t; p < 32 * 88; p += 256) {
        const int r = p / 88;
        const int cc = 128 + (p % 88) * 4;
        const size_t o = (size_t)(n0 + r) * FEAT + cc;
        *(float4*)&nf_out[o] = *(const float4*)&node_feat[o];
    }
    if (t < 32) {
        const int n = n0 + t;
        const float s = rc[t];
        #pragma unroll
        for (int j = 0; j < 3; ++j)
            np_out[(size_t)n * 3 + j] = node_pos[(size_t)n * 3 + j] + agg_vr[(size_t)n * 3 + j] * s;
        #pragma unroll
        for (int j = 0; j < 12; ++j)
            vp_out[(size_t)n * 12 + j] = vn_pos[(size_t)n * 12 + j] + agg_rv[(size_t)n * 12 + j] * s;
    }
}

// ---------------------------------------------------------------- launch
extern "C" void kernel_launch(void* const* d_in, const int* in_sizes, int n_in,
                              void* d_out, int out_size, void* d_ws, size_t ws_size,
                              hipStream_t stream)
{
    (void)n_in; (void)out_size; (void)ws_size;
    const float* node_feat = (const float*)d_in[0];
    const float* node_pos  = (const float*)d_in[1];
    const float* vn_feat   = (const float*)d_in[2];
    const float* vn_pos    = (const float*)d_in[3];
    const int*   eidx      = (const int*)d_in[4];
    const float* w_scalar  = (const float*)d_in[5];
    const float* cm_w1  = (const float*)d_in[6];
    const float* cm_b1  = (const float*)d_in[7];
    const float* cm_w2  = (const float*)d_in[8];
    const float* cm_b2  = (const float*)d_in[9];
    const float* vr_w1  = (const float*)d_in[10];
    const float* vr_b1  = (const float*)d_in[11];
    const float* vr_w2  = (const float*)d_in[12];
    const float* vr_b2  = (const float*)d_in[13];
    const float* rv_w1  = (const float*)d_in[14];
    const float* rv_b1  = (const float*)d_in[15];
    const float* rv_w2  = (const float*)d_in[16];
    const float* rv_b2  = (const float*)d_in[17];
    const float* ft_w1  = (const float*)d_in[18];
    const float* ft_b1  = (const float*)d_in[19];
    const float* ft_w2  = (const float*)d_in[20];
    const float* ft_b2  = (const float*)d_in[21];
    const float* f2t_w1 = (const float*)d_in[22];
    const float* f2t_b1 = (const float*)d_in[23];
    const float* f2t_w2 = (const float*)d_in[24];
    const float* f2t_b2 = (const float*)d_in[25];
    const float* vf_w1  = (const float*)d_in[26];
    const float* vf_b1  = (const float*)d_in[27];
    const float* vf_w2  = (const float*)d_in[28];
    const float* vf_b2  = (const float*)d_in[29];

    const int Nn = in_sizes[0] / FEAT;        // 20000
    const int E  = in_sizes[4] / 2;           // 240000

    // workspace layout
    float* ws       = (float*)d_ws;
    float* agg_feat = ws;                                // Nn*256 (zeroed)
    float* agg_vr   = agg_feat + (size_t)Nn * HDIM;      // Nn*3   (zeroed)
    float* agg_rv   = agg_vr   + (size_t)Nn * 3;         // Nn*12  (zeroed)
    float* cntf     = agg_rv   + (size_t)Nn * 12;        // Nn     (zeroed)
    int*   cnt_i    = (int*)(cntf + Nn);                 // Nn     (zeroed)
    int*   cursor   = cnt_i + Nn;                        // Nn     (zeroed)
    int*   rowstart = cursor + Nn;                       // Nn+8
    int*   bsum     = rowstart + Nn + 8;                 // 64
    int*   elist    = bsum + 64;                         // E
    ushort* nfsb = (ushort*)(elist + E);                 // Nn*128
    ushort* vnb  = nfsb + (size_t)Nn * SDIM;             // Nn*256
    ushort* wb   = vnb  + (size_t)Nn * HDIM;             // OWTOT

    const size_t zero_bytes = (size_t)Nn * (HDIM + 3 + 12 + 1 + 2) * sizeof(float);
    hipMemsetAsync(agg_feat, 0, zero_bytes, stream);

    const int eg = (E + 255) / 256;
    const int sb = (Nn + 1023) / 1024;        // 20 scan blocks
    k_count<<<eg, 256, 0, stream>>>(eidx, cnt_i, E);
    k_scanA<<<sb, 1024, 0, stream>>>(cnt_i, rowstart, cntf, bsum, Nn);
    k_scanB<<<1, 64, 0, stream>>>(bsum, sb);
    k_scanC<<<sb, 1024, 0, stream>>>(rowstart, bsum, Nn);
    k_place<<<eg, 256, 0, stream>>>(eidx, rowstart, cursor, elist, E);
    k_wprep<<<(OWTOT + 255) / 256, 256, 0, stream>>>(
        cm_w1, cm_w2, vr_w1, rv_w1, vr_w2, rv_w2,
        ft_w1, ft_w2, f2t_w1, f2t_w2, vf_w1, vf_w2, wb);
    k_vnb<<<(Nn * 64 + 255) / 256, 256, 0, stream>>>(vn_feat, vnb, Nn * 64);
    k_nfs<<<Nn / 32, 256, 0, stream>>>(node_feat, w_scalar, nfsb);
    k_edge<<<E / 64, 512, 0, stream>>>(nfsb, vnb, node_pos, vn_pos, eidx, elist,
                                       wb, cm_b1, cm_b2, vr_b1, vr_b2, rv_b1, rv_b2,
                                       agg_feat, agg_vr, agg_rv, E);
    k_node<<<Nn / 32, 256, 0, stream>>>(node_feat, node_pos, vn_feat, vn_pos,
                                        agg_feat, agg_vr, agg_rv, cntf, wb,
                                        ft_b1, ft_b2, f2t_b1, f2t_b2, vf_b1, vf_b2,
                                        (float*)d_out, Nn);
}

// Round 11
// 454.520 us; speedup vs baseline: 3.1025x; 1.0289x over previous
//
#include <hip/hip_runtime.h>
#include <hip/hip_bf16.h>
#include <math.h>

// VNLayer: N=20000 nodes, E=240000 edges, H=256, SD=128, C=4, FEAT=480
// Round 11: revert round-10's merged vr1+rv1 (it spilled: VGPR 52->64,
// WRITE_SIZE 29->95MB). Separate vr1/rv1 K-loops (single reused acc) but
// KEEP concurrent vr2||rv2 (rv-hidden goes to Mg: kloop-read -> barrier ->
// epi-overwrite). Parallel scan + frag-packed weights + 64-edge blocks kept.

#define FEAT 480
#define HDIM 256
#define SDIM 128
#define MSTR 264    // LDS A row stride (ushorts)

// bf16 weight arena offsets (ushort elements) -- frag-packed regions
#define OW1   0          // cm1 : 16 nt x 13 ks x 512
#define OW2   106496     // cm2 : 16 x 8 x 512
#define OVR1  172032
#define ORV1  237568
#define OVR2  303104     // vr2 : 1 x 8 x 512 (cols>=4 zero)
#define ORV2  307200     // rv2 : 1 x 8 x 512
#define OFT1  311296
#define OFT2  376832
#define OF2T1 442368
#define OF2T2 507904     // f2t2: 8 nt x 8 ks x 512
#define OVF1  540672
#define OVF2  606208
#define OWTOT 671744

typedef __attribute__((ext_vector_type(8))) short bf16x8;
typedef __attribute__((ext_vector_type(4))) float f32x4;

__device__ __forceinline__ float silu_f(float x) {
    return x / (1.0f + __expf(-x));
}
__device__ __forceinline__ ushort f2b(float v) {
    __hip_bfloat16 h = __float2bfloat16(v);
    return *(ushort*)&h;
}
__device__ __forceinline__ float b2f(ushort u) {
    union { unsigned int i; float f; } c;
    c.i = ((unsigned int)u) << 16;
    return c.f;
}

// k_edge K=256 GEMM: 4 m-tiles x 2 n-tiles per wave. A from LDS, B frag-packed.
#define KLOOP2(SRC, WP)                                                        \
    {                                                                          \
        _Pragma("unroll")                                                      \
        for (int mt = 0; mt < 4; ++mt)                                         \
            _Pragma("unroll")                                                  \
            for (int nt = 0; nt < 2; ++nt) acc[mt][nt] = (f32x4)0.f;           \
        _Pragma("unroll")                                                      \
        for (int ks = 0; ks < 8; ++ks) {                                       \
            bf16x8 a_[4];                                                      \
            _Pragma("unroll")                                                  \
            for (int mt = 0; mt < 4; ++mt)                                     \
                a_[mt] = *(const bf16x8*)&(SRC)[(mt * 16 + lr) * MSTR + ks * 32 + lk * 8]; \
            _Pragma("unroll")                                                  \
            for (int nt = 0; nt < 2; ++nt) {                                   \
                const bf16x8 b = *(const bf16x8*)&(WP)[(size_t)(((wv * 2 + nt) * 8 + ks) * 512) + lane * 8]; \
                _Pragma("unroll")                                              \
                for (int mt = 0; mt < 4; ++mt)                                 \
                    acc[mt][nt] = __builtin_amdgcn_mfma_f32_16x16x32_bf16(a_[mt], b, acc[mt][nt], 0, 0, 0); \
            }                                                                  \
        }                                                                      \
    }

#define EPI_SILU2(DST, BIAS)                                                   \
    _Pragma("unroll")                                                          \
    for (int nt = 0; nt < 2; ++nt) {                                           \
        const int col = colBase + nt * 16 + lr;                                \
        const float bb = (BIAS)[col];                                          \
        _Pragma("unroll")                                                      \
        for (int mt = 0; mt < 4; ++mt)                                         \
            _Pragma("unroll")                                                  \
            for (int r = 0; r < 4; ++r) {                                      \
                const int row = mt * 16 + lk * 4 + r;                          \
                (DST)[row * MSTR + col] = f2b(silu_f(acc[mt][nt][r] + bb));    \
            }                                                                  \
    }

// k_node K=256 GEMM (round-8 form): 2 m-tiles x 4 n-tiles per wave.
#define KLOOP_FR(SRC, WP)                                                      \
    {                                                                          \
        _Pragma("unroll")                                                      \
        for (int mt = 0; mt < 2; ++mt)                                         \
            _Pragma("unroll")                                                  \
            for (int nt = 0; nt < 4; ++nt) accn[mt][nt] = (f32x4)0.f;          \
        _Pragma("unroll")                                                      \
        for (int ks = 0; ks < 8; ++ks) {                                       \
            const bf16x8 a0 = *(const bf16x8*)&(SRC)[lr * MSTR + ks * 32 + lk * 8];        \
            const bf16x8 a1 = *(const bf16x8*)&(SRC)[(lr + 16) * MSTR + ks * 32 + lk * 8]; \
            _Pragma("unroll")                                                  \
            for (int nt = 0; nt < 4; ++nt) {                                   \
                const bf16x8 b = *(const bf16x8*)&(WP)[(size_t)(((wv * 4 + nt) * 8 + ks) * 512) + lane * 8]; \
                accn[0][nt] = __builtin_amdgcn_mfma_f32_16x16x32_bf16(a0, b, accn[0][nt], 0, 0, 0); \
                accn[1][nt] = __builtin_amdgcn_mfma_f32_16x16x32_bf16(a1, b, accn[1][nt], 0, 0, 0); \
            }                                                                  \
        }                                                                      \
    }

#define EPI_SILUN(DST, BIAS)                                                   \
    _Pragma("unroll")                                                          \
    for (int nt = 0; nt < 4; ++nt) {                                           \
        const int col = colBase + nt * 16 + lr;                                \
        const float bb = (BIAS)[col];                                          \
        _Pragma("unroll")                                                      \
        for (int mt = 0; mt < 2; ++mt)                                         \
            _Pragma("unroll")                                                  \
            for (int r = 0; r < 4; ++r) {                                      \
                const int row = mt * 16 + lk * 4 + r;                          \
                (DST)[row * MSTR + col] = f2b(silu_f(accn[mt][nt][r] + bb));   \
            }                                                                  \
    }

// ---------------------------------------------------------------- CSR build
__global__ __launch_bounds__(256) void k_count(
    const int* __restrict__ eidx, int* __restrict__ cnt_i, int E)
{
    const int e = blockIdx.x * 256 + threadIdx.x;
    if (e < E) atomicAdd(&cnt_i[eidx[e]], 1);
}

__global__ __launch_bounds__(1024) void k_scanA(
    const int* __restrict__ cnt_i, int* __restrict__ rowstart,
    float* __restrict__ cntf, int* __restrict__ bsum, int Nn)
{
    __shared__ int sh[1024];
    const int t = threadIdx.x;
    const int i = blockIdx.x * 1024 + t;
    const int v = (i < Nn) ? cnt_i[i] : 0;
    sh[t] = v;
    __syncthreads();
    for (int off = 1; off < 1024; off <<= 1) {
        const int add = (t >= off) ? sh[t - off] : 0;
        __syncthreads();
        sh[t] += add;
        __syncthreads();
    }
    if (i < Nn) {
        rowstart[i + 1] = sh[t];
        cntf[i] = fmaxf((float)v, 1.0f);
    }
    if (t == 1023) bsum[blockIdx.x] = sh[t];
}

__global__ __launch_bounds__(64) void k_scanB(int* __restrict__ bsum, int nb)
{
    if (threadIdx.x == 0) {
        int s = 0;
        for (int i = 0; i < nb; ++i) { const int v = bsum[i]; bsum[i] = s; s += v; }
    }
}

__global__ __launch_bounds__(1024) void k_scanC(
    int* __restrict__ rowstart, const int* __restrict__ bsum, int Nn)
{
    const int i = blockIdx.x * 1024 + threadIdx.x;
    if (i < Nn) rowstart[i + 1] += bsum[blockIdx.x];
    if (i == 0) rowstart[0] = 0;
}

__global__ __launch_bounds__(256) void k_place(
    const int* __restrict__ eidx, const int* __restrict__ rowstart,
    int* __restrict__ cursor, int* __restrict__ elist, int E)
{
    const int e = blockIdx.x * 256 + threadIdx.x;
    if (e < E) {
        const int r = eidx[e];
        const int p = atomicAdd(&cursor[r], 1);
        elist[rowstart[r] + p] = e;
    }
}

// ---------------------------------------------------------------- k_wprep
__global__ __launch_bounds__(256) void k_wprep(
    const float* __restrict__ w1, const float* __restrict__ w2,
    const float* __restrict__ vrw1, const float* __restrict__ rvw1,
    const float* __restrict__ vrw2, const float* __restrict__ rvw2,
    const float* __restrict__ ftw1, const float* __restrict__ ftw2,
    const float* __restrict__ f2tw1, const float* __restrict__ f2tw2,
    const float* __restrict__ vfw1, const float* __restrict__ vfw2,
    ushort* __restrict__ wb)
{
    const int idx = blockIdx.x * 256 + threadIdx.x;
    if (idx >= OWTOT) return;
    ushort v;
    if (idx < OW2) {
        const int o = idx, f = o >> 9, l = (o >> 3) & 63, e = o & 7;
        const int nt = f / 13, ks = f % 13;
        const int col = nt * 16 + (l & 15);
        const int k = ks * 32 + ((l >> 4) << 3) + e;
        v = (k < 400) ? f2b(w1[(size_t)k * 256 + col]) : (ushort)0;
    } else if (idx < OVR1) {
        const int o = idx - OW2, f = o >> 9, l = (o >> 3) & 63, e = o & 7;
        const int col = (f >> 3) * 16 + (l & 15);
        const int k = (f & 7) * 32 + ((l >> 4) << 3) + e;
        v = f2b(w2[(size_t)k * 256 + col]);
    } else if (idx < ORV1) {
        const int o = idx - OVR1, f = o >> 9, l = (o >> 3) & 63, e = o & 7;
        const int col = (f >> 3) * 16 + (l & 15);
        const int k = (f & 7) * 32 + ((l >> 4) << 3) + e;
        v = f2b(vrw1[(size_t)k * 256 + col]);
    } else if (idx < OVR2) {
        const int o = idx - ORV1, f = o >> 9, l = (o >> 3) & 63, e = o & 7;
        const int col = (f >> 3) * 16 + (l & 15);
        const int k = (f & 7) * 32 + ((l >> 4) << 3) + e;
        v = f2b(rvw1[(size_t)k * 256 + col]);
    } else if (idx < ORV2) {
        const int o = idx - OVR2, f = o >> 9, l = (o >> 3) & 63, e = o & 7;
        const int col = l & 15;
        const int k = f * 32 + ((l >> 4) << 3) + e;
        v = (col < 4) ? f2b(vrw2[(size_t)k * 4 + col]) : (ushort)0;
    } else if (idx < OFT1) {
        const int o = idx - ORV2, f = o >> 9, l = (o >> 3) & 63, e = o & 7;
        const int col = l & 15;
        const int k = f * 32 + ((l >> 4) << 3) + e;
        v = f2b(rvw2[(size_t)k * 16 + col]);
    } else if (idx < OFT2) {
        const int o = idx - OFT1, f = o >> 9, l = (o >> 3) & 63, e = o & 7;
        const int col = (f >> 3) * 16 + (l & 15);
        const int k = (f & 7) * 32 + ((l >> 4) << 3) + e;
        v = f2b(ftw1[(size_t)k * 256 + col]);
    } else if (idx < OF2T1) {
        const int o = idx - OFT2, f = o >> 9, l = (o >> 3) & 63, e = o & 7;
        const int col = (f >> 3) * 16 + (l & 15);
        const int k = (f & 7) * 32 + ((l >> 4) << 3) + e;
        v = f2b(ftw2[(size_t)k * 256 + col]);
    } else if (idx < OF2T2) {
        const int o = idx - OF2T1, f = o >> 9, l = (o >> 3) & 63, e = o & 7;
        const int col = (f >> 3) * 16 + (l & 15);
        const int k = (f & 7) * 32 + ((l >> 4) << 3) + e;
        v = f2b(f2tw1[(size_t)k * 256 + col]);
    } else if (idx < OVF1) {
        const int o = idx - OF2T2, f = o >> 9, l = (o >> 3) & 63, e = o & 7;
        const int col = (f >> 3) * 16 + (l & 15);
        const int k = (f & 7) * 32 + ((l >> 4) << 3) + e;
        v = f2b(f2tw2[(size_t)k * 128 + col]);
    } else if (idx < OVF2) {
        const int o = idx - OVF1, f = o >> 9, l = (o >> 3) & 63, e = o & 7;
        const int col = (f >> 3) * 16 + (l & 15);
        const int k = (f & 7) * 32 + ((l >> 4) << 3) + e;
        v = f2b(vfw1[(size_t)k * 256 + col]);
    } else {
        const int o = idx - OVF2, f = o >> 9, l = (o >> 3) & 63, e = o & 7;
        const int col = (f >> 3) * 16 + (l & 15);
        const int k = (f & 7) * 32 + ((l >> 4) << 3) + e;
        v = f2b(vfw2[(size_t)k * 256 + col]);
    }
    wb[idx] = v;
}

// ---------------------------------------------------------------- k_vnb
__global__ __launch_bounds__(256) void k_vnb(
    const float* __restrict__ vn_feat, ushort* __restrict__ vnb, int total4)
{
    const int i = blockIdx.x * 256 + threadIdx.x;
    if (i >= total4) return;
    const float4 v = *(const float4*)&vn_feat[(size_t)i * 4];
    ushort4 o;
    o.x = f2b(v.x); o.y = f2b(v.y); o.z = f2b(v.z); o.w = f2b(v.w);
    *(ushort4*)&vnb[(size_t)i * 4] = o;
}

// ---------------------------------------------------------------- k_nfs
__global__ __launch_bounds__(256) void k_nfs(
    const float* __restrict__ node_feat, const float* __restrict__ w_scalar,
    ushort* __restrict__ nfsb)
{
    __shared__ float At[32][20];
    __shared__ float Wt[16][128];
    const int t  = threadIdx.x;
    const int m0 = blockIdx.x * 32;
    const int c4 = (t & 31) * 4;
    const int rg = t >> 5;
    float acc[4][4] = {};
    for (int k0 = 0; k0 < 128; k0 += 16) {
        if (t < 128) {
            const int r = t >> 2, kk = (t & 3) * 4;
            *(float4*)&At[r][kk] =
                *(const float4*)&node_feat[(size_t)(m0 + r) * FEAT + k0 + kk];
        }
        #pragma unroll
        for (int i = 0; i < 2; ++i) {
            const int p  = t + i * 256;
            const int wr = p >> 5, wc = (p & 31) * 4;
            *(float4*)&Wt[wr][wc] =
                *(const float4*)&w_scalar[(size_t)(k0 + wr) * SDIM + wc];
        }
        __syncthreads();
        #pragma unroll
        for (int kk = 0; kk < 16; ++kk) {
            const float4 w = *(const float4*)&Wt[kk][c4];
            #pragma unroll
            for (int j = 0; j < 4; ++j) {
                const float a = At[rg * 4 + j][kk];
                acc[j][0] = fmaf(a, w.x, acc[j][0]);
                acc[j][1] = fmaf(a, w.y, acc[j][1]);
                acc[j][2] = fmaf(a, w.z, acc[j][2]);
                acc[j][3] = fmaf(a, w.w, acc[j][3]);
            }
        }
        __syncthreads();
    }
    const float s = 0.08838834764831845f;
    #pragma unroll
    for (int j = 0; j < 4; ++j) {
        ushort4 o;
        o.x = f2b(acc[j][0] * s); o.y = f2b(acc[j][1] * s);
        o.z = f2b(acc[j][2] * s); o.w = f2b(acc[j][3] * s);
        *(ushort4*)&nfsb[(size_t)(m0 + rg * 4 + j) * SDIM + c4] = o;
    }
}

// ---------------------------------------------------------------- k_edge
// 64 row-sorted edges/block, 512 threads = 8 waves. LDS 78.3KB -> 2 blk/CU.
__global__ __launch_bounds__(512, 4) void k_edge(
    const ushort* __restrict__ nfsb, const ushort* __restrict__ vnb,
    const float* __restrict__ node_pos, const float* __restrict__ vn_pos,
    const int* __restrict__ eidx, const int* __restrict__ elist,
    const ushort* __restrict__ wb,
    const float* __restrict__ b1, const float* __restrict__ b2,
    const float* __restrict__ vrb1, const float* __restrict__ vrb2,
    const float* __restrict__ rvb1, const float* __restrict__ rvb2,
    float* __restrict__ agg_feat, float* __restrict__ agg_vr,
    float* __restrict__ agg_rv, int E)
{
    __shared__ ushort Mg[64 * MSTR];   // msg; later rv-hidden overlay
    __shared__ ushort Hd[64 * MSTR];   // cm hidden, then vr hidden
    __shared__ ushort ipB[64 * 16];
    __shared__ float dnS[64][12];
    __shared__ float wvrS[64][4];
    __shared__ float wrvS[64][16];
    __shared__ int rowi[64], coli[64];

    const int t  = threadIdx.x;
    const int e0 = blockIdx.x * 64;
    const int wv = t >> 6;             // 0..7
    const int lane = t & 63;
    const int lr = lane & 15;
    const int lk = lane >> 4;
    const int colBase = wv * 32;       // 2 n-tiles per wave

    // ---- geometry (t<64), row-sorted edges ----
    if (t < 64) {
        const int e = elist[e0 + t];
        const int r = eidx[e];
        const int c = eidx[E + e];
        rowi[t] = r; coli[t] = c;
        const float px = node_pos[r * 3 + 0];
        const float py = node_pos[r * 3 + 1];
        const float pz = node_pos[r * 3 + 2];
        float d[4][3];
        #pragma unroll
        for (int ch = 0; ch < 4; ++ch) {
            d[ch][0] = px - vn_pos[(size_t)c * 12 + ch * 3 + 0];
            d[ch][1] = py - vn_pos[(size_t)c * 12 + ch * 3 + 1];
            d[ch][2] = pz - vn_pos[(size_t)c * 12 + ch * 3 + 2];
        }
        float ss = 0.f, ipv[16];
        #pragma unroll
        for (int ci = 0; ci < 4; ++ci)
            #pragma unroll
            for (int ck = 0; ck < 4; ++ck) {
                const float v = d[ci][0]*d[ck][0] + d[ci][1]*d[ck][1] + d[ci][2]*d[ck][2];
                ipv[ci * 4 + ck] = v; ss += v * v;
            }
        const float inrm = 1.0f / fmaxf(sqrtf(ss), 1e-8f);
        #pragma unroll
        for (int i = 0; i < 16; ++i) ipB[t * 16 + i] = f2b(ipv[i] * inrm);
        #pragma unroll
        for (int ch = 0; ch < 4; ++ch) {
            const float nn = sqrtf(d[ch][0]*d[ch][0] + d[ch][1]*d[ch][1] + d[ch][2]*d[ch][2]);
            const float s = 1.0f / fmaxf(nn, 1e-8f);
            dnS[t][ch * 3 + 0] = d[ch][0] * s;
            dnS[t][ch * 3 + 1] = d[ch][1] * s;
            dnS[t][ch * 3 + 2] = d[ch][2] * s;
        }
    }
    __syncthreads();

    // per-lane A row pointers for cm1 (4 m-tiles)
    const ushort* nA[4]; const ushort* vA[4];
    #pragma unroll
    for (int mt = 0; mt < 4; ++mt) {
        nA[mt] = nfsb + (size_t)rowi[mt * 16 + lr] * SDIM + lk * 8;
        vA[mt] = vnb  + (size_t)coli[mt * 16 + lr] * HDIM + lk * 8;
    }
    const ushort* w1t = wb + OW1;

    f32x4 acc[4][2];

    // ===== cm layer 1 (K=416: 128 nfs | 256 vn | 16 ip | 16 zero) =====
    #pragma unroll
    for (int mt = 0; mt < 4; ++mt)
        #pragma unroll
        for (int nt = 0; nt < 2; ++nt) acc[mt][nt] = (f32x4)0.f;
    #pragma unroll
    for (int ks = 0; ks < 13; ++ks) {
        bf16x8 a_[4];
        #pragma unroll
        for (int mt = 0; mt < 4; ++mt) {
            if (ks < 4)       a_[mt] = *(const bf16x8*)(nA[mt] + ks * 32);
            else if (ks < 12) a_[mt] = *(const bf16x8*)(vA[mt] + ks * 32 - 128);
            else if (lk < 2)  a_[mt] = *(const bf16x8*)&ipB[(mt * 16 + lr) * 16 + lk * 8];
            else              a_[mt] = (bf16x8)(short)0;
        }
        #pragma unroll
        for (int nt = 0; nt < 2; ++nt) {
            const bf16x8 b = *(const bf16x8*)&w1t[(size_t)(((wv * 2 + nt) * 13 + ks) * 512) + lane * 8];
            #pragma unroll
            for (int mt = 0; mt < 4; ++mt)
                acc[mt][nt] = __builtin_amdgcn_mfma_f32_16x16x32_bf16(a_[mt], b, acc[mt][nt], 0, 0, 0);
        }
    }
    EPI_SILU2(Hd, b1);
    __syncthreads();

    // ===== cm layer 2 -> msg =====
    KLOOP2(Hd, wb + OW2);
    #pragma unroll
    for (int nt = 0; nt < 2; ++nt) {
        const int col = colBase + nt * 16 + lr;
        const float bb = b2[col];
        #pragma unroll
        for (int mt = 0; mt < 4; ++mt)
            #pragma unroll
            for (int r = 0; r < 4; ++r) {
                const int row = mt * 16 + lk * 4 + r;
                Mg[row * MSTR + col] = f2b(acc[mt][nt][r] + bb);
            }
    }
    __syncthreads();

    // ===== segmented reduction msg -> agg_feat (two 32-row halves) =====
    {
        const int col = t & 255;
        const int r0 = (t >> 8) * 32;
        float s = 0.f;
        int prev = rowi[r0];
        for (int r = r0; r < r0 + 32; ++r) {
            const int rr = rowi[r];
            if (rr != prev) {
                atomicAdd(&agg_feat[(size_t)prev * HDIM + col], s);
                s = 0.f; prev = rr;
            }
            s += b2f(Mg[r * MSTR + col]);
        }
        atomicAdd(&agg_feat[(size_t)prev * HDIM + col], s);
    }

    // ===== vr layer 1 (reads Mg, writes Hd; no barrier needed after —
    //        rv1's internal barrier provides visibility before vr2) =====
    KLOOP2(Mg, wb + OVR1);
    EPI_SILU2(Hd, vrb1);

    // ===== rv layer 1 (reads Mg; barrier; epilogue overwrites Mg) =====
    KLOOP2(Mg, wb + ORV1);
    __syncthreads();                   // all Mg reads done + Hd writes visible
    #pragma unroll
    for (int nt = 0; nt < 2; ++nt) {
        const int col = colBase + nt * 16 + lr;
        const float br = rvb1[col];
        #pragma unroll
        for (int mt = 0; mt < 4; ++mt)
            #pragma unroll
            for (int r = 0; r < 4; ++r) {
                const int row = mt * 16 + lk * 4 + r;
                Mg[row * MSTR + col] = f2b(silu_f(acc[mt][nt][r] + br));  // rv hidden
            }
    }
    __syncthreads();

    // ===== vr2 (waves 0,4 from Hd) CONCURRENT with rv2 (waves 1,5 from Mg) =====
    if ((wv & 3) == 0) {
        const int rb = (wv >> 2) * 32;
        const ushort* vrw2t = wb + OVR2;
        f32x4 a2[2]; a2[0] = (f32x4)0.f; a2[1] = (f32x4)0.f;
        #pragma unroll
        for (int ks = 0; ks < 8; ++ks) {
            const bf16x8 a0 = *(const bf16x8*)&Hd[(rb + lr) * MSTR + ks * 32 + lk * 8];
            const bf16x8 a1 = *(const bf16x8*)&Hd[(rb + 16 + lr) * MSTR + ks * 32 + lk * 8];
            const bf16x8 b  = *(const bf16x8*)&vrw2t[(size_t)(ks * 512) + lane * 8];
            a2[0] = __builtin_amdgcn_mfma_f32_16x16x32_bf16(a0, b, a2[0], 0, 0, 0);
            a2[1] = __builtin_amdgcn_mfma_f32_16x16x32_bf16(a1, b, a2[1], 0, 0, 0);
        }
        if (lr < 4) {
            const float bb = vrb2[lr];
            #pragma unroll
            for (int mt = 0; mt < 2; ++mt)
                #pragma unroll
                for (int r = 0; r < 4; ++r)
                    wvrS[rb + mt * 16 + lk * 4 + r][lr] = a2[mt][r] + bb;
        }
    } else if ((wv & 3) == 1) {
        const int rb = (wv >> 2) * 32;
        const ushort* rvw2t = wb + ORV2;
        f32x4 a2[2]; a2[0] = (f32x4)0.f; a2[1] = (f32x4)0.f;
        #pragma unroll
        for (int ks = 0; ks < 8; ++ks) {
            const bf16x8 a0 = *(const bf16x8*)&Mg[(rb + lr) * MSTR + ks * 32 + lk * 8];
            const bf16x8 a1 = *(const bf16x8*)&Mg[(rb + 16 + lr) * MSTR + ks * 32 + lk * 8];
            const bf16x8 b  = *(const bf16x8*)&rvw2t[(size_t)(ks * 512) + lane * 8];
            a2[0] = __builtin_amdgcn_mfma_f32_16x16x32_bf16(a0, b, a2[0], 0, 0, 0);
            a2[1] = __builtin_amdgcn_mfma_f32_16x16x32_bf16(a1, b, a2[1], 0, 0, 0);
        }
        const float bb = rvb2[lr];
        #pragma unroll
        for (int mt = 0; mt < 2; ++mt)
            #pragma unroll
            for (int r = 0; r < 4; ++r)
                wrvS[rb + mt * 16 + lk * 4 + r][lr] = a2[mt][r] + bb;
    }
    __syncthreads();

    // ===== per-edge geometric update (t<64) =====
    if (t < 64) {
        float wvv[4], wrr[16], dn[12], ev[15];
        #pragma unroll
        for (int c = 0; c < 4; ++c)  wvv[c] = wvrS[t][c];
        #pragma unroll
        for (int i = 0; i < 16; ++i) wrr[i] = wrvS[t][i];
        #pragma unroll
        for (int i = 0; i < 12; ++i) dn[i]  = dnS[t][i];
        #pragma unroll
        for (int j = 0; j < 3; ++j) {
            float v = 0.f;
            #pragma unroll
            for (int c = 0; c < 4; ++c) v = fmaf(wvv[c], dn[c * 3 + j], v);
            ev[j] = 0.5f * v;
        }
        #pragma unroll
        for (int u = 0; u < 4; ++u)
            #pragma unroll
            for (int j = 0; j < 3; ++j) {
                float v = 0.f;
                #pragma unroll
                for (int c = 0; c < 4; ++c) v = fmaf(wrr[c * 4 + u], dn[c * 3 + j], v);
                ev[3 + u * 3 + j] = -0.5f * v;
            }
        #pragma unroll
        for (int i = 0; i < 15; ++i) wrvS[t][i] = ev[i];
    }
    __syncthreads();

    // ===== segmented reduction vr/rv (two halves) =====
    if ((t & 255) < 15) {
        const int comp = t & 255;
        const int r0 = (t >> 8) * 32;
        float s = 0.f;
        int prev = rowi[r0];
        for (int r = r0; r < r0 + 32; ++r) {
            const int rr = rowi[r];
            if (rr != prev) {
                if (comp < 3) atomicAdd(&agg_vr[(size_t)prev * 3 + comp], s);
                else          atomicAdd(&agg_rv[(size_t)prev * 12 + (comp - 3)], s);
                s = 0.f; prev = rr;
            }
            s += wrvS[r][comp];
        }
        if (comp < 3) atomicAdd(&agg_vr[(size_t)prev * 3 + comp], s);
        else          atomicAdd(&agg_rv[(size_t)prev * 12 + (comp - 3)], s);
    }
}

// ---------------------------------------------------------------- k_node
// 32 nodes/block (625 blocks), 256 threads = 4 waves (round-8 form).
__global__ __launch_bounds__(256, 4) void k_node(
    const float* __restrict__ node_feat, const float* __restrict__ node_pos,
    const float* __restrict__ vn_feat, const float* __restrict__ vn_pos,
    const float* __restrict__ agg_feat, const float* __restrict__ agg_vr,
    const float* __restrict__ agg_rv, const float* __restrict__ cntf,
    const ushort* __restrict__ wb,
    const float* __restrict__ ftb1, const float* __restrict__ ftb2,
    const float* __restrict__ f2tb1, const float* __restrict__ f2tb2,
    const float* __restrict__ vfb1, const float* __restrict__ vfb2,
    float* __restrict__ out, int Nn)
{
    __shared__ ushort Ab[32 * MSTR];
    __shared__ ushort Hd[32 * MSTR];
    __shared__ float rc[32];
    const int t  = threadIdx.x;
    const int n0 = blockIdx.x * 32;
    const int wv = t >> 6;
    const int lane = t & 63;
    const int lr = lane & 15;
    const int lk = lane >> 4;
    const int colBase = wv * 64;

    float* nf_out = out;
    float* np_out = out + (size_t)Nn * FEAT;
    float* vf_out = np_out + (size_t)Nn * 3;
    float* vp_out = vf_out + (size_t)Nn * HDIM;

    if (t < 32) rc[t] = 1.0f / fmaxf(cntf[n0 + t], 1.0f);
    __syncthreads();
    #pragma unroll
    for (int i = 0; i < 8; ++i) {
        const int p = t + i * 256;
        const int r = p >> 6, cc = (p & 63) * 4;
        float4 v = *(const float4*)&agg_feat[(size_t)(n0 + r) * HDIM + cc];
        const float s = rc[r];
        ushort4 o;
        o.x = f2b(v.x * s); o.y = f2b(v.y * s);
        o.z = f2b(v.z * s); o.w = f2b(v.w * s);
        *(ushort4*)&Ab[r * MSTR + cc] = o;
    }
    __syncthreads();

    f32x4 accn[2][4];

    // ---- vf MLP ----
    KLOOP_FR(Ab, wb + OVF1);
    EPI_SILUN(Hd, vfb1);
    __syncthreads();
    KLOOP_FR(Hd, wb + OVF2);
    #pragma unroll
    for (int nt = 0; nt < 4; ++nt) {
        const int col = colBase + nt * 16 + lr;
        const float bb = vfb2[col];
        #pragma unroll
        for (int mt = 0; mt < 2; ++mt)
            #pragma unroll
            for (int r = 0; r < 4; ++r) {
                const int row = mt * 16 + lk * 4 + r;
                const size_t o = (size_t)(n0 + row) * HDIM + col;
                vf_out[o] = vn_feat[o] + accn[mt][nt][r] + bb;
            }
    }
    __syncthreads();

    // ---- ft MLP ----
    KLOOP_FR(Ab, wb + OFT1);
    EPI_SILUN(Hd, ftb1);
    __syncthreads();
    KLOOP_FR(Hd, wb + OFT2);
    #pragma unroll
    for (int nt = 0; nt < 4; ++nt) {
        const int col = colBase + nt * 16 + lr;
        const float bb = ftb2[col];
        #pragma unroll
        for (int mt = 0; mt < 2; ++mt)
            #pragma unroll
            for (int r = 0; r < 4; ++r) {
                const int row = mt * 16 + lk * 4 + r;
                Ab[row * MSTR + col] = f2b(accn[mt][nt][r] + bb);
            }
    }
    __syncthreads();

    // ---- f2t MLP ----
    KLOOP_FR(Ab, wb + OF2T1);
    EPI_SILUN(Hd, f2tb1);
    __syncthreads();
    {
        const ushort* w2p = wb + OF2T2;
        f32x4 a2[2][2];
        #pragma unroll
        for (int mt = 0; mt < 2; ++mt)
            #pragma unroll
            for (int nt = 0; nt < 2; ++nt) a2[mt][nt] = (f32x4)0.f;
        #pragma unroll
        for (int ks = 0; ks < 8; ++ks) {
            const int k0 = ks * 32 + lk * 8;
            const bf16x8 a0 = *(const bf16x8*)&Hd[lr * MSTR + k0];
            const bf16x8 a1 = *(const bf16x8*)&Hd[(lr + 16) * MSTR + k0];
            const bf16x8 w0 = *(const bf16x8*)&w2p[(size_t)(((wv * 2 + 0) * 8 + ks) * 512) + lane * 8];
            const bf16x8 w1v = *(const bf16x8*)&w2p[(size_t)(((wv * 2 + 1) * 8 + ks) * 512) + lane * 8];
            a2[0][0] = __builtin_amdgcn_mfma_f32_16x16x32_bf16(a0, w0, a2[0][0], 0, 0, 0);
            a2[1][0] = __builtin_amdgcn_mfma_f32_16x16x32_bf16(a1, w0, a2[1][0], 0, 0, 0);
            a2[0][1] = __builtin_amdgcn_mfma_f32_16x16x32_bf16(a0, w1v, a2[0][1], 0, 0, 0);
            a2[1][1] = __builtin_amdgcn_mfma_f32_16x16x32_bf16(a1, w1v, a2[1][1], 0, 0, 0);
        }
        #pragma unroll
        for (int nt = 0; nt < 2; ++nt) {
            const int col = wv * 32 + nt * 16 + lr;
            const float bb = f2tb2[col];
            #pragma unroll
            for (int mt = 0; mt < 2; ++mt)
                #pragma unroll
                for (int r = 0; r < 4; ++r) {
                    const int row = mt * 16 + lk * 4 + r;
                    const size_t o = (size_t)(n0 + row) * FEAT + col;
                    nf_out[o] = node_feat[o] + a2[mt][nt][r] + bb;
                }
        }
    }

    // passthrough cols 128..479
    for (int p = t; p < 32 * 88; p += 256) {
        const int r = p / 88;
        const int cc = 128 + (p % 88) * 4;
        const size_t o = (size_t)(n0 + r) * FEAT + cc;
        *(float4*)&nf_out[o] = *(const float4*)&node_feat[o];
    }
    if (t < 32) {
        const int n = n0 + t;
        const float s = rc[t];
        #pragma unroll
        for (int j = 0; j < 3; ++j)
            np_out[(size_t)n * 3 + j] = node_pos[(size_t)n * 3 + j] + agg_vr[(size_t)n * 3 + j] * s;
        #pragma unroll
        for (int j = 0; j < 12; ++j)
            vp_out[(size_t)n * 12 + j] = vn_pos[(size_t)n * 12 + j] + agg_rv[(size_t)n * 12 + j] * s;
    }
}

// ---------------------------------------------------------------- launch
extern "C" void kernel_launch(void* const* d_in, const int* in_sizes, int n_in,
                              void* d_out, int out_size, void* d_ws, size_t ws_size,
                              hipStream_t stream)
{
    (void)n_in; (void)out_size; (void)ws_size;
    const float* node_feat = (const float*)d_in[0];
    const float* node_pos  = (const float*)d_in[1];
    const float* vn_feat   = (const float*)d_in[2];
    const float* vn_pos    = (const float*)d_in[3];
    const int*   eidx      = (const int*)d_in[4];
    const float* w_scalar  = (const float*)d_in[5];
    const float* cm_w1  = (const float*)d_in[6];
    const float* cm_b1  = (const float*)d_in[7];
    const float* cm_w2  = (const float*)d_in[8];
    const float* cm_b2  = (const float*)d_in[9];
    const float* vr_w1  = (const float*)d_in[10];
    const float* vr_b1  = (const float*)d_in[11];
    const float* vr_w2  = (const float*)d_in[12];
    const float* vr_b2  = (const float*)d_in[13];
    const float* rv_w1  = (const float*)d_in[14];
    const float* rv_b1  = (const float*)d_in[15];
    const float* rv_w2  = (const float*)d_in[16];
    const float* rv_b2  = (const float*)d_in[17];
    const float* ft_w1  = (const float*)d_in[18];
    const float* ft_b1  = (const float*)d_in[19];
    const float* ft_w2  = (const float*)d_in[20];
    const float* ft_b2  = (const float*)d_in[21];
    const float* f2t_w1 = (const float*)d_in[22];
    const float* f2t_b1 = (const float*)d_in[23];
    const float* f2t_w2 = (const float*)d_in[24];
    const float* f2t_b2 = (const float*)d_in[25];
    const float* vf_w1  = (const float*)d_in[26];
    const float* vf_b1  = (const float*)d_in[27];
    const float* vf_w2  = (const float*)d_in[28];
    const float* vf_b2  = (const float*)d_in[29];

    const int Nn = in_sizes[0] / FEAT;        // 20000
    const int E  = in_sizes[4] / 2;           // 240000

    // workspace layout
    float* ws       = (float*)d_ws;
    float* agg_feat = ws;                                // Nn*256 (zeroed)
    float* agg_vr   = agg_feat + (size_t)Nn * HDIM;      // Nn*3   (zeroed)
    float* agg_rv   = agg_vr   + (size_t)Nn * 3;         // Nn*12  (zeroed)
    float* cntf     = agg_rv   + (size_t)Nn * 12;        // Nn     (zeroed)
    int*   cnt_i    = (int*)(cntf + Nn);                 // Nn     (zeroed)
    int*   cursor   = cnt_i + Nn;                        // Nn     (zeroed)
    int*   rowstart = cursor + Nn;                       // Nn+8
    int*   bsum     = rowstart + Nn + 8;                 // 64
    int*   elist    = bsum + 64;                         // E
    ushort* nfsb = (ushort*)(elist + E);                 // Nn*128
    ushort* vnb  = nfsb + (size_t)Nn * SDIM;             // Nn*256
    ushort* wb   = vnb  + (size_t)Nn * HDIM;             // OWTOT

    const size_t zero_bytes = (size_t)Nn * (HDIM + 3 + 12 + 1 + 2) * sizeof(float);
    hipMemsetAsync(agg_feat, 0, zero_bytes, stream);

    const int eg = (E + 255) / 256;
    const int sb = (Nn + 1023) / 1024;        // 20 scan blocks
    k_count<<<eg, 256, 0, stream>>>(eidx, cnt_i, E);
    k_scanA<<<sb, 1024, 0, stream>>>(cnt_i, rowstart, cntf, bsum, Nn);
    k_scanB<<<1, 64, 0, stream>>>(bsum, sb);
    k_scanC<<<sb, 1024, 0, stream>>>(rowstart, bsum, Nn);
    k_place<<<eg, 256, 0, stream>>>(eidx, rowstart, cursor, elist, E);
    k_wprep<<<(OWTOT + 255) / 256, 256, 0, stream>>>(
        cm_w1, cm_w2, vr_w1, rv_w1, vr_w2, rv_w2,
        ft_w1, ft_w2, f2t_w1, f2t_w2, vf_w1, vf_w2, wb);
    k_vnb<<<(Nn * 64 + 255) / 256, 256, 0, stream>>>(vn_feat, vnb, Nn * 64);
    k_nfs<<<Nn / 32, 256, 0, stream>>>(node_feat, w_scalar, nfsb);
    k_edge<<<E / 64, 512, 0, stream>>>(nfsb, vnb, node_pos, vn_pos, eidx, elist,
                                       wb, cm_b1, cm_b2, vr_b1, vr_b2, rv_b1, rv_b2,
                                       agg_feat, agg_vr, agg_rv, E);
    k_node<<<Nn / 32, 256, 0, stream>>>(node_feat, node_pos, vn_feat, vn_pos,
                                        agg_feat, agg_vr, agg_rv, cntf, wb,
                                        ft_b1, ft_b2, f2t_b1, f2t_b2, vf_b1, vf_b2,
                                        (float*)d_out, Nn);
}

// Round 12
// 431.850 us; speedup vs baseline: 3.2653x; 1.0525x over previous
//
#include <hip/hip_runtime.h>
#include <hip/hip_bf16.h>
#include <math.h>

// VNLayer: N=20000 nodes, E=240000 edges, H=256, SD=128, C=4, FEAT=480
// Round 12: round-11 structure (best known, 454us) with one change:
// all f32 divisions replaced by single v_rcp_f32 (__builtin_amdgcn_rcpf).
// Without -ffast-math, `x/(1+exp(-x))` compiled to the 7-op IEEE div
// sequence; VALU was 2x the MFMA pipe (37.8% vs 18.4%). ~1ulp rcp is
// harmless (bf16 outputs, 7x threshold margin).

#define FEAT 480
#define HDIM 256
#define SDIM 128
#define MSTR 264    // LDS A row stride (ushorts)

// bf16 weight arena offsets (ushort elements) -- frag-packed regions
#define OW1   0          // cm1 : 16 nt x 13 ks x 512
#define OW2   106496     // cm2 : 16 x 8 x 512
#define OVR1  172032
#define ORV1  237568
#define OVR2  303104     // vr2 : 1 x 8 x 512 (cols>=4 zero)
#define ORV2  307200     // rv2 : 1 x 8 x 512
#define OFT1  311296
#define OFT2  376832
#define OF2T1 442368
#define OF2T2 507904     // f2t2: 8 nt x 8 ks x 512
#define OVF1  540672
#define OVF2  606208
#define OWTOT 671744

typedef __attribute__((ext_vector_type(8))) short bf16x8;
typedef __attribute__((ext_vector_type(4))) float f32x4;

__device__ __forceinline__ float rcp_f(float x) {
    return __builtin_amdgcn_rcpf(x);
}
__device__ __forceinline__ float silu_f(float x) {
    return x * rcp_f(1.0f + __expf(-x));
}
__device__ __forceinline__ ushort f2b(float v) {
    __hip_bfloat16 h = __float2bfloat16(v);
    return *(ushort*)&h;
}
__device__ __forceinline__ float b2f(ushort u) {
    union { unsigned int i; float f; } c;
    c.i = ((unsigned int)u) << 16;
    return c.f;
}

// k_edge K=256 GEMM: 4 m-tiles x 2 n-tiles per wave. A from LDS, B frag-packed.
#define KLOOP2(SRC, WP)                                                        \
    {                                                                          \
        _Pragma("unroll")                                                      \
        for (int mt = 0; mt < 4; ++mt)                                         \
            _Pragma("unroll")                                                  \
            for (int nt = 0; nt < 2; ++nt) acc[mt][nt] = (f32x4)0.f;           \
        _Pragma("unroll")                                                      \
        for (int ks = 0; ks < 8; ++ks) {                                       \
            bf16x8 a_[4];                                                      \
            _Pragma("unroll")                                                  \
            for (int mt = 0; mt < 4; ++mt)                                     \
                a_[mt] = *(const bf16x8*)&(SRC)[(mt * 16 + lr) * MSTR + ks * 32 + lk * 8]; \
            _Pragma("unroll")                                                  \
            for (int nt = 0; nt < 2; ++nt) {                                   \
                const bf16x8 b = *(const bf16x8*)&(WP)[(size_t)(((wv * 2 + nt) * 8 + ks) * 512) + lane * 8]; \
                _Pragma("unroll")                                              \
                for (int mt = 0; mt < 4; ++mt)                                 \
                    acc[mt][nt] = __builtin_amdgcn_mfma_f32_16x16x32_bf16(a_[mt], b, acc[mt][nt], 0, 0, 0); \
            }                                                                  \
        }                                                                      \
    }

#define EPI_SILU2(DST, BIAS)                                                   \
    _Pragma("unroll")                                                          \
    for (int nt = 0; nt < 2; ++nt) {                                           \
        const int col = colBase + nt * 16 + lr;                                \
        const float bb = (BIAS)[col];                                          \
        _Pragma("unroll")                                                      \
        for (int mt = 0; mt < 4; ++mt)                                         \
            _Pragma("unroll")                                                  \
            for (int r = 0; r < 4; ++r) {                                      \
                const int row = mt * 16 + lk * 4 + r;                          \
                (DST)[row * MSTR + col] = f2b(silu_f(acc[mt][nt][r] + bb));    \
            }                                                                  \
    }

// k_node K=256 GEMM (round-8 form): 2 m-tiles x 4 n-tiles per wave.
#define KLOOP_FR(SRC, WP)                                                      \
    {                                                                          \
        _Pragma("unroll")                                                      \
        for (int mt = 0; mt < 2; ++mt)                                         \
            _Pragma("unroll")                                                  \
            for (int nt = 0; nt < 4; ++nt) accn[mt][nt] = (f32x4)0.f;          \
        _Pragma("unroll")                                                      \
        for (int ks = 0; ks < 8; ++ks) {                                       \
            const bf16x8 a0 = *(const bf16x8*)&(SRC)[lr * MSTR + ks * 32 + lk * 8];        \
            const bf16x8 a1 = *(const bf16x8*)&(SRC)[(lr + 16) * MSTR + ks * 32 + lk * 8]; \
            _Pragma("unroll")                                                  \
            for (int nt = 0; nt < 4; ++nt) {                                   \
                const bf16x8 b = *(const bf16x8*)&(WP)[(size_t)(((wv * 4 + nt) * 8 + ks) * 512) + lane * 8]; \
                accn[0][nt] = __builtin_amdgcn_mfma_f32_16x16x32_bf16(a0, b, accn[0][nt], 0, 0, 0); \
                accn[1][nt] = __builtin_amdgcn_mfma_f32_16x16x32_bf16(a1, b, accn[1][nt], 0, 0, 0); \
            }                                                                  \
        }                                                                      \
    }

#define EPI_SILUN(DST, BIAS)                                                   \
    _Pragma("unroll")                                                          \
    for (int nt = 0; nt < 4; ++nt) {                                           \
        const int col = colBase + nt * 16 + lr;                                \
        const float bb = (BIAS)[col];                                          \
        _Pragma("unroll")                                                      \
        for (int mt = 0; mt < 2; ++mt)                                         \
            _Pragma("unroll")                                                  \
            for (int r = 0; r < 4; ++r) {                                      \
                const int row = mt * 16 + lk * 4 + r;                          \
                (DST)[row * MSTR + col] = f2b(silu_f(accn[mt][nt][r] + bb));   \
            }                                                                  \
    }

// ---------------------------------------------------------------- CSR build
__global__ __launch_bounds__(256) void k_count(
    const int* __restrict__ eidx, int* __restrict__ cnt_i, int E)
{
    const int e = blockIdx.x * 256 + threadIdx.x;
    if (e < E) atomicAdd(&cnt_i[eidx[e]], 1);
}

__global__ __launch_bounds__(1024) void k_scanA(
    const int* __restrict__ cnt_i, int* __restrict__ rowstart,
    float* __restrict__ cntf, int* __restrict__ bsum, int Nn)
{
    __shared__ int sh[1024];
    const int t = threadIdx.x;
    const int i = blockIdx.x * 1024 + t;
    const int v = (i < Nn) ? cnt_i[i] : 0;
    sh[t] = v;
    __syncthreads();
    for (int off = 1; off < 1024; off <<= 1) {
        const int add = (t >= off) ? sh[t - off] : 0;
        __syncthreads();
        sh[t] += add;
        __syncthreads();
    }
    if (i < Nn) {
        rowstart[i + 1] = sh[t];
        cntf[i] = fmaxf((float)v, 1.0f);
    }
    if (t == 1023) bsum[blockIdx.x] = sh[t];
}

__global__ __launch_bounds__(64) void k_scanB(int* __restrict__ bsum, int nb)
{
    if (threadIdx.x == 0) {
        int s = 0;
        for (int i = 0; i < nb; ++i) { const int v = bsum[i]; bsum[i] = s; s += v; }
    }
}

__global__ __launch_bounds__(1024) void k_scanC(
    int* __restrict__ rowstart, const int* __restrict__ bsum, int Nn)
{
    const int i = blockIdx.x * 1024 + threadIdx.x;
    if (i < Nn) rowstart[i + 1] += bsum[blockIdx.x];
    if (i == 0) rowstart[0] = 0;
}

__global__ __launch_bounds__(256) void k_place(
    const int* __restrict__ eidx, const int* __restrict__ rowstart,
    int* __restrict__ cursor, int* __restrict__ elist, int E)
{
    const int e = blockIdx.x * 256 + threadIdx.x;
    if (e < E) {
        const int r = eidx[e];
        const int p = atomicAdd(&cursor[r], 1);
        elist[rowstart[r] + p] = e;
    }
}

// ---------------------------------------------------------------- k_wprep
__global__ __launch_bounds__(256) void k_wprep(
    const float* __restrict__ w1, const float* __restrict__ w2,
    const float* __restrict__ vrw1, const float* __restrict__ rvw1,
    const float* __restrict__ vrw2, const float* __restrict__ rvw2,
    const float* __restrict__ ftw1, const float* __restrict__ ftw2,
    const float* __restrict__ f2tw1, const float* __restrict__ f2tw2,
    const float* __restrict__ vfw1, const float* __restrict__ vfw2,
    ushort* __restrict__ wb)
{
    const int idx = blockIdx.x * 256 + threadIdx.x;
    if (idx >= OWTOT) return;
    ushort v;
    if (idx < OW2) {
        const int o = idx, f = o >> 9, l = (o >> 3) & 63, e = o & 7;
        const int nt = f / 13, ks = f % 13;
        const int col = nt * 16 + (l & 15);
        const int k = ks * 32 + ((l >> 4) << 3) + e;
        v = (k < 400) ? f2b(w1[(size_t)k * 256 + col]) : (ushort)0;
    } else if (idx < OVR1) {
        const int o = idx - OW2, f = o >> 9, l = (o >> 3) & 63, e = o & 7;
        const int col = (f >> 3) * 16 + (l & 15);
        const int k = (f & 7) * 32 + ((l >> 4) << 3) + e;
        v = f2b(w2[(size_t)k * 256 + col]);
    } else if (idx < ORV1) {
        const int o = idx - OVR1, f = o >> 9, l = (o >> 3) & 63, e = o & 7;
        const int col = (f >> 3) * 16 + (l & 15);
        const int k = (f & 7) * 32 + ((l >> 4) << 3) + e;
        v = f2b(vrw1[(size_t)k * 256 + col]);
    } else if (idx < OVR2) {
        const int o = idx - ORV1, f = o >> 9, l = (o >> 3) & 63, e = o & 7;
        const int col = (f >> 3) * 16 + (l & 15);
        const int k = (f & 7) * 32 + ((l >> 4) << 3) + e;
        v = f2b(rvw1[(size_t)k * 256 + col]);
    } else if (idx < ORV2) {
        const int o = idx - OVR2, f = o >> 9, l = (o >> 3) & 63, e = o & 7;
        const int col = l & 15;
        const int k = f * 32 + ((l >> 4) << 3) + e;
        v = (col < 4) ? f2b(vrw2[(size_t)k * 4 + col]) : (ushort)0;
    } else if (idx < OFT1) {
        const int o = idx - ORV2, f = o >> 9, l = (o >> 3) & 63, e = o & 7;
        const int col = l & 15;
        const int k = f * 32 + ((l >> 4) << 3) + e;
        v = f2b(rvw2[(size_t)k * 16 + col]);
    } else if (idx < OFT2) {
        const int o = idx - OFT1, f = o >> 9, l = (o >> 3) & 63, e = o & 7;
        const int col = (f >> 3) * 16 + (l & 15);
        const int k = (f & 7) * 32 + ((l >> 4) << 3) + e;
        v = f2b(ftw1[(size_t)k * 256 + col]);
    } else if (idx < OF2T1) {
        const int o = idx - OFT2, f = o >> 9, l = (o >> 3) & 63, e = o & 7;
        const int col = (f >> 3) * 16 + (l & 15);
        const int k = (f & 7) * 32 + ((l >> 4) << 3) + e;
        v = f2b(ftw2[(size_t)k * 256 + col]);
    } else if (idx < OF2T2) {
        const int o = idx - OF2T1, f = o >> 9, l = (o >> 3) & 63, e = o & 7;
        const int col = (f >> 3) * 16 + (l & 15);
        const int k = (f & 7) * 32 + ((l >> 4) << 3) + e;
        v = f2b(f2tw1[(size_t)k * 256 + col]);
    } else if (idx < OVF1) {
        const int o = idx - OF2T2, f = o >> 9, l = (o >> 3) & 63, e = o & 7;
        const int col = (f >> 3) * 16 + (l & 15);
        const int k = (f & 7) * 32 + ((l >> 4) << 3) + e;
        v = f2b(f2tw2[(size_t)k * 128 + col]);
    } else if (idx < OVF2) {
        const int o = idx - OVF1, f = o >> 9, l = (o >> 3) & 63, e = o & 7;
        const int col = (f >> 3) * 16 + (l & 15);
        const int k = (f & 7) * 32 + ((l >> 4) << 3) + e;
        v = f2b(vfw1[(size_t)k * 256 + col]);
    } else {
        const int o = idx - OVF2, f = o >> 9, l = (o >> 3) & 63, e = o & 7;
        const int col = (f >> 3) * 16 + (l & 15);
        const int k = (f & 7) * 32 + ((l >> 4) << 3) + e;
        v = f2b(vfw2[(size_t)k * 256 + col]);
    }
    wb[idx] = v;
}

// ---------------------------------------------------------------- k_vnb
__global__ __launch_bounds__(256) void k_vnb(
    const float* __restrict__ vn_feat, ushort* __restrict__ vnb, int total4)
{
    const int i = blockIdx.x * 256 + threadIdx.x;
    if (i >= total4) return;
    const float4 v = *(const float4*)&vn_feat[(size_t)i * 4];
    ushort4 o;
    o.x = f2b(v.x); o.y = f2b(v.y); o.z = f2b(v.z); o.w = f2b(v.w);
    *(ushort4*)&vnb[(size_t)i * 4] = o;
}

// ---------------------------------------------------------------- k_nfs
__global__ __launch_bounds__(256) void k_nfs(
    const float* __restrict__ node_feat, const float* __restrict__ w_scalar,
    ushort* __restrict__ nfsb)
{
    __shared__ float At[32][20];
    __shared__ float Wt[16][128];
    const int t  = threadIdx.x;
    const int m0 = blockIdx.x * 32;
    const int c4 = (t & 31) * 4;
    const int rg = t >> 5;
    float acc[4][4] = {};
    for (int k0 = 0; k0 < 128; k0 += 16) {
        if (t < 128) {
            const int r = t >> 2, kk = (t & 3) * 4;
            *(float4*)&At[r][kk] =
                *(const float4*)&node_feat[(size_t)(m0 + r) * FEAT + k0 + kk];
        }
        #pragma unroll
        for (int i = 0; i < 2; ++i) {
            const int p  = t + i * 256;
            const int wr = p >> 5, wc = (p & 31) * 4;
            *(float4*)&Wt[wr][wc] =
                *(const float4*)&w_scalar[(size_t)(k0 + wr) * SDIM + wc];
        }
        __syncthreads();
        #pragma unroll
        for (int kk = 0; kk < 16; ++kk) {
            const float4 w = *(const float4*)&Wt[kk][c4];
            #pragma unroll
            for (int j = 0; j < 4; ++j) {
                const float a = At[rg * 4 + j][kk];
                acc[j][0] = fmaf(a, w.x, acc[j][0]);
                acc[j][1] = fmaf(a, w.y, acc[j][1]);
                acc[j][2] = fmaf(a, w.z, acc[j][2]);
                acc[j][3] = fmaf(a, w.w, acc[j][3]);
            }
        }
        __syncthreads();
    }
    const float s = 0.08838834764831845f;
    #pragma unroll
    for (int j = 0; j < 4; ++j) {
        ushort4 o;
        o.x = f2b(acc[j][0] * s); o.y = f2b(acc[j][1] * s);
        o.z = f2b(acc[j][2] * s); o.w = f2b(acc[j][3] * s);
        *(ushort4*)&nfsb[(size_t)(m0 + rg * 4 + j) * SDIM + c4] = o;
    }
}

// ---------------------------------------------------------------- k_edge
// 64 row-sorted edges/block, 512 threads = 8 waves. LDS 78.3KB -> 2 blk/CU.
__global__ __launch_bounds__(512, 4) void k_edge(
    const ushort* __restrict__ nfsb, const ushort* __restrict__ vnb,
    const float* __restrict__ node_pos, const float* __restrict__ vn_pos,
    const int* __restrict__ eidx, const int* __restrict__ elist,
    const ushort* __restrict__ wb,
    const float* __restrict__ b1, const float* __restrict__ b2,
    const float* __restrict__ vrb1, const float* __restrict__ vrb2,
    const float* __restrict__ rvb1, const float* __restrict__ rvb2,
    float* __restrict__ agg_feat, float* __restrict__ agg_vr,
    float* __restrict__ agg_rv, int E)
{
    __shared__ ushort Mg[64 * MSTR];   // msg; later rv-hidden overlay
    __shared__ ushort Hd[64 * MSTR];   // cm hidden, then vr hidden
    __shared__ ushort ipB[64 * 16];
    __shared__ float dnS[64][12];
    __shared__ float wvrS[64][4];
    __shared__ float wrvS[64][16];
    __shared__ int rowi[64], coli[64];

    const int t  = threadIdx.x;
    const int e0 = blockIdx.x * 64;
    const int wv = t >> 6;             // 0..7
    const int lane = t & 63;
    const int lr = lane & 15;
    const int lk = lane >> 4;
    const int colBase = wv * 32;       // 2 n-tiles per wave

    // ---- geometry (t<64), row-sorted edges ----
    if (t < 64) {
        const int e = elist[e0 + t];
        const int r = eidx[e];
        const int c = eidx[E + e];
        rowi[t] = r; coli[t] = c;
        const float px = node_pos[r * 3 + 0];
        const float py = node_pos[r * 3 + 1];
        const float pz = node_pos[r * 3 + 2];
        float d[4][3];
        #pragma unroll
        for (int ch = 0; ch < 4; ++ch) {
            d[ch][0] = px - vn_pos[(size_t)c * 12 + ch * 3 + 0];
            d[ch][1] = py - vn_pos[(size_t)c * 12 + ch * 3 + 1];
            d[ch][2] = pz - vn_pos[(size_t)c * 12 + ch * 3 + 2];
        }
        float ss = 0.f, ipv[16];
        #pragma unroll
        for (int ci = 0; ci < 4; ++ci)
            #pragma unroll
            for (int ck = 0; ck < 4; ++ck) {
                const float v = d[ci][0]*d[ck][0] + d[ci][1]*d[ck][1] + d[ci][2]*d[ck][2];
                ipv[ci * 4 + ck] = v; ss += v * v;
            }
        const float inrm = rcp_f(fmaxf(sqrtf(ss), 1e-8f));
        #pragma unroll
        for (int i = 0; i < 16; ++i) ipB[t * 16 + i] = f2b(ipv[i] * inrm);
        #pragma unroll
        for (int ch = 0; ch < 4; ++ch) {
            const float nn = sqrtf(d[ch][0]*d[ch][0] + d[ch][1]*d[ch][1] + d[ch][2]*d[ch][2]);
            const float s = rcp_f(fmaxf(nn, 1e-8f));
            dnS[t][ch * 3 + 0] = d[ch][0] * s;
            dnS[t][ch * 3 + 1] = d[ch][1] * s;
            dnS[t][ch * 3 + 2] = d[ch][2] * s;
        }
    }
    __syncthreads();

    // per-lane A row pointers for cm1 (4 m-tiles)
    const ushort* nA[4]; const ushort* vA[4];
    #pragma unroll
    for (int mt = 0; mt < 4; ++mt) {
        nA[mt] = nfsb + (size_t)rowi[mt * 16 + lr] * SDIM + lk * 8;
        vA[mt] = vnb  + (size_t)coli[mt * 16 + lr] * HDIM + lk * 8;
    }
    const ushort* w1t = wb + OW1;

    f32x4 acc[4][2];

    // ===== cm layer 1 (K=416: 128 nfs | 256 vn | 16 ip | 16 zero) =====
    #pragma unroll
    for (int mt = 0; mt < 4; ++mt)
        #pragma unroll
        for (int nt = 0; nt < 2; ++nt) acc[mt][nt] = (f32x4)0.f;
    #pragma unroll
    for (int ks = 0; ks < 13; ++ks) {
        bf16x8 a_[4];
        #pragma unroll
        for (int mt = 0; mt < 4; ++mt) {
            if (ks < 4)       a_[mt] = *(const bf16x8*)(nA[mt] + ks * 32);
            else if (ks < 12) a_[mt] = *(const bf16x8*)(vA[mt] + ks * 32 - 128);
            else if (lk < 2)  a_[mt] = *(const bf16x8*)&ipB[(mt * 16 + lr) * 16 + lk * 8];
            else              a_[mt] = (bf16x8)(short)0;
        }
        #pragma unroll
        for (int nt = 0; nt < 2; ++nt) {
            const bf16x8 b = *(const bf16x8*)&w1t[(size_t)(((wv * 2 + nt) * 13 + ks) * 512) + lane * 8];
            #pragma unroll
            for (int mt = 0; mt < 4; ++mt)
                acc[mt][nt] = __builtin_amdgcn_mfma_f32_16x16x32_bf16(a_[mt], b, acc[mt][nt], 0, 0, 0);
        }
    }
    EPI_SILU2(Hd, b1);
    __syncthreads();

    // ===== cm layer 2 -> msg =====
    KLOOP2(Hd, wb + OW2);
    #pragma unroll
    for (int nt = 0; nt < 2; ++nt) {
        const int col = colBase + nt * 16 + lr;
        const float bb = b2[col];
        #pragma unroll
        for (int mt = 0; mt < 4; ++mt)
            #pragma unroll
            for (int r = 0; r < 4; ++r) {
                const int row = mt * 16 + lk * 4 + r;
                Mg[row * MSTR + col] = f2b(acc[mt][nt][r] + bb);
            }
    }
    __syncthreads();

    // ===== segmented reduction msg -> agg_feat (two 32-row halves) =====
    {
        const int col = t & 255;
        const int r0 = (t >> 8) * 32;
        float s = 0.f;
        int prev = rowi[r0];
        for (int r = r0; r < r0 + 32; ++r) {
            const int rr = rowi[r];
            if (rr != prev) {
                atomicAdd(&agg_feat[(size_t)prev * HDIM + col], s);
                s = 0.f; prev = rr;
            }
            s += b2f(Mg[r * MSTR + col]);
        }
        atomicAdd(&agg_feat[(size_t)prev * HDIM + col], s);
    }

    // ===== vr layer 1 (reads Mg, writes Hd; no barrier needed after —
    //        rv1's internal barrier provides visibility before vr2) =====
    KLOOP2(Mg, wb + OVR1);
    EPI_SILU2(Hd, vrb1);

    // ===== rv layer 1 (reads Mg; barrier; epilogue overwrites Mg) =====
    KLOOP2(Mg, wb + ORV1);
    __syncthreads();                   // all Mg reads done + Hd writes visible
    #pragma unroll
    for (int nt = 0; nt < 2; ++nt) {
        const int col = colBase + nt * 16 + lr;
        const float br = rvb1[col];
        #pragma unroll
        for (int mt = 0; mt < 4; ++mt)
            #pragma unroll
            for (int r = 0; r < 4; ++r) {
                const int row = mt * 16 + lk * 4 + r;
                Mg[row * MSTR + col] = f2b(silu_f(acc[mt][nt][r] + br));  // rv hidden
            }
    }
    __syncthreads();

    // ===== vr2 (waves 0,4 from Hd) CONCURRENT with rv2 (waves 1,5 from Mg) =====
    if ((wv & 3) == 0) {
        const int rb = (wv >> 2) * 32;
        const ushort* vrw2t = wb + OVR2;
        f32x4 a2[2]; a2[0] = (f32x4)0.f; a2[1] = (f32x4)0.f;
        #pragma unroll
        for (int ks = 0; ks < 8; ++ks) {
            const bf16x8 a0 = *(const bf16x8*)&Hd[(rb + lr) * MSTR + ks * 32 + lk * 8];
            const bf16x8 a1 = *(const bf16x8*)&Hd[(rb + 16 + lr) * MSTR + ks * 32 + lk * 8];
            const bf16x8 b  = *(const bf16x8*)&vrw2t[(size_t)(ks * 512) + lane * 8];
            a2[0] = __builtin_amdgcn_mfma_f32_16x16x32_bf16(a0, b, a2[0], 0, 0, 0);
            a2[1] = __builtin_amdgcn_mfma_f32_16x16x32_bf16(a1, b, a2[1], 0, 0, 0);
        }
        if (lr < 4) {
            const float bb = vrb2[lr];
            #pragma unroll
            for (int mt = 0; mt < 2; ++mt)
                #pragma unroll
                for (int r = 0; r < 4; ++r)
                    wvrS[rb + mt * 16 + lk * 4 + r][lr] = a2[mt][r] + bb;
        }
    } else if ((wv & 3) == 1) {
        const int rb = (wv >> 2) * 32;
        const ushort* rvw2t = wb + ORV2;
        f32x4 a2[2]; a2[0] = (f32x4)0.f; a2[1] = (f32x4)0.f;
        #pragma unroll
        for (int ks = 0; ks < 8; ++ks) {
            const bf16x8 a0 = *(const bf16x8*)&Mg[(rb + lr) * MSTR + ks * 32 + lk * 8];
            const bf16x8 a1 = *(const bf16x8*)&Mg[(rb + 16 + lr) * MSTR + ks * 32 + lk * 8];
            const bf16x8 b  = *(const bf16x8*)&rvw2t[(size_t)(ks * 512) + lane * 8];
            a2[0] = __builtin_amdgcn_mfma_f32_16x16x32_bf16(a0, b, a2[0], 0, 0, 0);
            a2[1] = __builtin_amdgcn_mfma_f32_16x16x32_bf16(a1, b, a2[1], 0, 0, 0);
        }
        const float bb = rvb2[lr];
        #pragma unroll
        for (int mt = 0; mt < 2; ++mt)
            #pragma unroll
            for (int r = 0; r < 4; ++r)
                wrvS[rb + mt * 16 + lk * 4 + r][lr] = a2[mt][r] + bb;
    }
    __syncthreads();

    // ===== per-edge geometric update (t<64) =====
    if (t < 64) {
        float wvv[4], wrr[16], dn[12], ev[15];
        #pragma unroll
        for (int c = 0; c < 4; ++c)  wvv[c] = wvrS[t][c];
        #pragma unroll
        for (int i = 0; i < 16; ++i) wrr[i] = wrvS[t][i];
        #pragma unroll
        for (int i = 0; i < 12; ++i) dn[i]  = dnS[t][i];
        #pragma unroll
        for (int j = 0; j < 3; ++j) {
            float v = 0.f;
            #pragma unroll
            for (int c = 0; c < 4; ++c) v = fmaf(wvv[c], dn[c * 3 + j], v);
            ev[j] = 0.5f * v;
        }
        #pragma unroll
        for (int u = 0; u < 4; ++u)
            #pragma unroll
            for (int j = 0; j < 3; ++j) {
                float v = 0.f;
                #pragma unroll
                for (int c = 0; c < 4; ++c) v = fmaf(wrr[c * 4 + u], dn[c * 3 + j], v);
                ev[3 + u * 3 + j] = -0.5f * v;
            }
        #pragma unroll
        for (int i = 0; i < 15; ++i) wrvS[t][i] = ev[i];
    }
    __syncthreads();

    // ===== segmented reduction vr/rv (two halves) =====
    if ((t & 255) < 15) {
        const int comp = t & 255;
        const int r0 = (t >> 8) * 32;
        float s = 0.f;
        int prev = rowi[r0];
        for (int r = r0; r < r0 + 32; ++r) {
            const int rr = rowi[r];
            if (rr != prev) {
                if (comp < 3) atomicAdd(&agg_vr[(size_t)prev * 3 + comp], s);
                else          atomicAdd(&agg_rv[(size_t)prev * 12 + (comp - 3)], s);
                s = 0.f; prev = rr;
            }
            s += wrvS[r][comp];
        }
        if (comp < 3) atomicAdd(&agg_vr[(size_t)prev * 3 + comp], s);
        else          atomicAdd(&agg_rv[(size_t)prev * 12 + (comp - 3)], s);
    }
}

// ---------------------------------------------------------------- k_node
// 32 nodes/block (625 blocks), 256 threads = 4 waves (round-8 form).
__global__ __launch_bounds__(256, 4) void k_node(
    const float* __restrict__ node_feat, const float* __restrict__ node_pos,
    const float* __restrict__ vn_feat, const float* __restrict__ vn_pos,
    const float* __restrict__ agg_feat, const float* __restrict__ agg_vr,
    const float* __restrict__ agg_rv, const float* __restrict__ cntf,
    const ushort* __restrict__ wb,
    const float* __restrict__ ftb1, const float* __restrict__ ftb2,
    const float* __restrict__ f2tb1, const float* __restrict__ f2tb2,
    const float* __restrict__ vfb1, const float* __restrict__ vfb2,
    float* __restrict__ out, int Nn)
{
    __shared__ ushort Ab[32 * MSTR];
    __shared__ ushort Hd[32 * MSTR];
    __shared__ float rc[32];
    const int t  = threadIdx.x;
    const int n0 = blockIdx.x * 32;
    const int wv = t >> 6;
    const int lane = t & 63;
    const int lr = lane & 15;
    const int lk = lane >> 4;
    const int colBase = wv * 64;

    float* nf_out = out;
    float* np_out = out + (size_t)Nn * FEAT;
    float* vf_out = np_out + (size_t)Nn * 3;
    float* vp_out = vf_out + (size_t)Nn * HDIM;

    if (t < 32) rc[t] = rcp_f(fmaxf(cntf[n0 + t], 1.0f));
    __syncthreads();
    #pragma unroll
    for (int i = 0; i < 8; ++i) {
        const int p = t + i * 256;
        const int r = p >> 6, cc = (p & 63) * 4;
        float4 v = *(const float4*)&agg_feat[(size_t)(n0 + r) * HDIM + cc];
        const float s = rc[r];
        ushort4 o;
        o.x = f2b(v.x * s); o.y = f2b(v.y * s);
        o.z = f2b(v.z * s); o.w = f2b(v.w * s);
        *(ushort4*)&Ab[r * MSTR + cc] = o;
    }
    __syncthreads();

    f32x4 accn[2][4];

    // ---- vf MLP ----
    KLOOP_FR(Ab, wb + OVF1);
    EPI_SILUN(Hd, vfb1);
    __syncthreads();
    KLOOP_FR(Hd, wb + OVF2);
    #pragma unroll
    for (int nt = 0; nt < 4; ++nt) {
        const int col = colBase + nt * 16 + lr;
        const float bb = vfb2[col];
        #pragma unroll
        for (int mt = 0; mt < 2; ++mt)
            #pragma unroll
            for (int r = 0; r < 4; ++r) {
                const int row = mt * 16 + lk * 4 + r;
                const size_t o = (size_t)(n0 + row) * HDIM + col;
                vf_out[o] = vn_feat[o] + accn[mt][nt][r] + bb;
            }
    }
    __syncthreads();

    // ---- ft MLP ----
    KLOOP_FR(Ab, wb + OFT1);
    EPI_SILUN(Hd, ftb1);
    __syncthreads();
    KLOOP_FR(Hd, wb + OFT2);
    #pragma unroll
    for (int nt = 0; nt < 4; ++nt) {
        const int col = colBase + nt * 16 + lr;
        const float bb = ftb2[col];
        #pragma unroll
        for (int mt = 0; mt < 2; ++mt)
            #pragma unroll
            for (int r = 0; r < 4; ++r) {
                const int row = mt * 16 + lk * 4 + r;
                Ab[row * MSTR + col] = f2b(accn[mt][nt][r] + bb);
            }
    }
    __syncthreads();

    // ---- f2t MLP ----
    KLOOP_FR(Ab, wb + OF2T1);
    EPI_SILUN(Hd, f2tb1);
    __syncthreads();
    {
        const ushort* w2p = wb + OF2T2;
        f32x4 a2[2][2];
        #pragma unroll
        for (int mt = 0; mt < 2; ++mt)
            #pragma unroll
            for (int nt = 0; nt < 2; ++nt) a2[mt][nt] = (f32x4)0.f;
        #pragma unroll
        for (int ks = 0; ks < 8; ++ks) {
            const int k0 = ks * 32 + lk * 8;
            const bf16x8 a0 = *(const bf16x8*)&Hd[lr * MSTR + k0];
            const bf16x8 a1 = *(const bf16x8*)&Hd[(lr + 16) * MSTR + k0];
            const bf16x8 w0 = *(const bf16x8*)&w2p[(size_t)(((wv * 2 + 0) * 8 + ks) * 512) + lane * 8];
            const bf16x8 w1v = *(const bf16x8*)&w2p[(size_t)(((wv * 2 + 1) * 8 + ks) * 512) + lane * 8];
            a2[0][0] = __builtin_amdgcn_mfma_f32_16x16x32_bf16(a0, w0, a2[0][0], 0, 0, 0);
            a2[1][0] = __builtin_amdgcn_mfma_f32_16x16x32_bf16(a1, w0, a2[1][0], 0, 0, 0);
            a2[0][1] = __builtin_amdgcn_mfma_f32_16x16x32_bf16(a0, w1v, a2[0][1], 0, 0, 0);
            a2[1][1] = __builtin_amdgcn_mfma_f32_16x16x32_bf16(a1, w1v, a2[1][1], 0, 0, 0);
        }
        #pragma unroll
        for (int nt = 0; nt < 2; ++nt) {
            const int col = wv * 32 + nt * 16 + lr;
            const float bb = f2tb2[col];
            #pragma unroll
            for (int mt = 0; mt < 2; ++mt)
                #pragma unroll
                for (int r = 0; r < 4; ++r) {
                    const int row = mt * 16 + lk * 4 + r;
                    const size_t o = (size_t)(n0 + row) * FEAT + col;
                    nf_out[o] = node_feat[o] + a2[mt][nt][r] + bb;
                }
        }
    }

    // passthrough cols 128..479
    for (int p = t; p < 32 * 88; p += 256) {
        const int r = p / 88;
        const int cc = 128 + (p % 88) * 4;
        const size_t o = (size_t)(n0 + r) * FEAT + cc;
        *(float4*)&nf_out[o] = *(const float4*)&node_feat[o];
    }
    if (t < 32) {
        const int n = n0 + t;
        const float s = rc[t];
        #pragma unroll
        for (int j = 0; j < 3; ++j)
            np_out[(size_t)n * 3 + j] = node_pos[(size_t)n * 3 + j] + agg_vr[(size_t)n * 3 + j] * s;
        #pragma unroll
        for (int j = 0; j < 12; ++j)
            vp_out[(size_t)n * 12 + j] = vn_pos[(size_t)n * 12 + j] + agg_rv[(size_t)n * 12 + j] * s;
    }
}

// ---------------------------------------------------------------- launch
extern "C" void kernel_launch(void* const* d_in, const int* in_sizes, int n_in,
                              void* d_out, int out_size, void* d_ws, size_t ws_size,
                              hipStream_t stream)
{
    (void)n_in; (void)out_size; (void)ws_size;
    const float* node_feat = (const float*)d_in[0];
    const float* node_pos  = (const float*)d_in[1];
    const float* vn_feat   = (const float*)d_in[2];
    const float* vn_pos    = (const float*)d_in[3];
    const int*   eidx      = (const int*)d_in[4];
    const float* w_scalar  = (const float*)d_in[5];
    const float* cm_w1  = (const float*)d_in[6];
    const float* cm_b1  = (const float*)d_in[7];
    const float* cm_w2  = (const float*)d_in[8];
    const float* cm_b2  = (const float*)d_in[9];
    const float* vr_w1  = (const float*)d_in[10];
    const float* vr_b1  = (const float*)d_in[11];
    const float* vr_w2  = (const float*)d_in[12];
    const float* vr_b2  = (const float*)d_in[13];
    const float* rv_w1  = (const float*)d_in[14];
    const float* rv_b1  = (const float*)d_in[15];
    const float* rv_w2  = (const float*)d_in[16];
    const float* rv_b2  = (const float*)d_in[17];
    const float* ft_w1  = (const float*)d_in[18];
    const float* ft_b1  = (const float*)d_in[19];
    const float* ft_w2  = (const float*)d_in[20];
    const float* ft_b2  = (const float*)d_in[21];
    const float* f2t_w1 = (const float*)d_in[22];
    const float* f2t_b1 = (const float*)d_in[23];
    const float* f2t_w2 = (const float*)d_in[24];
    const float* f2t_b2 = (const float*)d_in[25];
    const float* vf_w1  = (const float*)d_in[26];
    const float* vf_b1  = (const float*)d_in[27];
    const float* vf_w2  = (const float*)d_in[28];
    const float* vf_b2  = (const float*)d_in[29];

    const int Nn = in_sizes[0] / FEAT;        // 20000
    const int E  = in_sizes[4] / 2;           // 240000

    // workspace layout
    float* ws       = (float*)d_ws;
    float* agg_feat = ws;                                // Nn*256 (zeroed)
    float* agg_vr   = agg_feat + (size_t)Nn * HDIM;      // Nn*3   (zeroed)
    float* agg_rv   = agg_vr   + (size_t)Nn * 3;         // Nn*12  (zeroed)
    float* cntf     = agg_rv   + (size_t)Nn * 12;        // Nn     (zeroed)
    int*   cnt_i    = (int*)(cntf + Nn);                 // Nn     (zeroed)
    int*   cursor   = cnt_i + Nn;                        // Nn     (zeroed)
    int*   rowstart = cursor + Nn;                       // Nn+8
    int*   bsum     = rowstart + Nn + 8;                 // 64
    int*   elist    = bsum + 64;                         // E
    ushort* nfsb = (ushort*)(elist + E);                 // Nn*128
    ushort* vnb  = nfsb + (size_t)Nn * SDIM;             // Nn*256
    ushort* wb   = vnb  + (size_t)Nn * HDIM;             // OWTOT

    const size_t zero_bytes = (size_t)Nn * (HDIM + 3 + 12 + 1 + 2) * sizeof(float);
    hipMemsetAsync(agg_feat, 0, zero_bytes, stream);

    const int eg = (E + 255) / 256;
    const int sb = (Nn + 1023) / 1024;        // 20 scan blocks
    k_count<<<eg, 256, 0, stream>>>(eidx, cnt_i, E);
    k_scanA<<<sb, 1024, 0, stream>>>(cnt_i, rowstart, cntf, bsum, Nn);
    k_scanB<<<1, 64, 0, stream>>>(bsum, sb);
    k_scanC<<<sb, 1024, 0, stream>>>(rowstart, bsum, Nn);
    k_place<<<eg, 256, 0, stream>>>(eidx, rowstart, cursor, elist, E);
    k_wprep<<<(OWTOT + 255) / 256, 256, 0, stream>>>(
        cm_w1, cm_w2, vr_w1, rv_w1, vr_w2, rv_w2,
        ft_w1, ft_w2, f2t_w1, f2t_w2, vf_w1, vf_w2, wb);
    k_vnb<<<(Nn * 64 + 255) / 256, 256, 0, stream>>>(vn_feat, vnb, Nn * 64);
    k_nfs<<<Nn / 32, 256, 0, stream>>>(node_feat, w_scalar, nfsb);
    k_edge<<<E / 64, 512, 0, stream>>>(nfsb, vnb, node_pos, vn_pos, eidx, elist,
                                       wb, cm_b1, cm_b2, vr_b1, vr_b2, rv_b1, rv_b2,
                                       agg_feat, agg_vr, agg_rv, E);
    k_node<<<Nn / 32, 256, 0, stream>>>(node_feat, node_pos, vn_feat, vn_pos,
                                        agg_feat, agg_vr, agg_rv, cntf, wb,
                                        ft_b1, ft_b2, f2t_b1, f2t_b2, vf_b1, vf_b2,
                                        (float*)d_out, Nn);
}

// Round 13
// 423.366 us; speedup vs baseline: 3.3308x; 1.0200x over previous
//
#include <hip/hip_runtime.h>
#include <hip/hip_bf16.h>
#include <math.h>

// VNLayer: N=20000 nodes, E=240000 edges, H=256, SD=128, C=4, FEAT=480
// Round 13: tail consolidation on top of round-12 (432us best).
//  - k_prep = k_wprep + k_vnb + k_nfs + k_count merged (blockIdx ranges);
//    four independent prep workloads in ONE dispatch.
//  - k_scanB folded into k_scanC (each block sums its own carry; 20 ints).
//  - k_edge / k_node byte-identical to round 12.

#define FEAT 480
#define HDIM 256
#define SDIM 128
#define MSTR 264    // LDS A row stride (ushorts)

// bf16 weight arena offsets (ushort elements) -- frag-packed regions
#define OW1   0          // cm1 : 16 nt x 13 ks x 512
#define OW2   106496     // cm2 : 16 x 8 x 512
#define OVR1  172032
#define ORV1  237568
#define OVR2  303104     // vr2 : 1 x 8 x 512 (cols>=4 zero)
#define ORV2  307200     // rv2 : 1 x 8 x 512
#define OFT1  311296
#define OFT2  376832
#define OF2T1 442368
#define OF2T2 507904     // f2t2: 8 nt x 8 ks x 512
#define OVF1  540672
#define OVF2  606208
#define OWTOT 671744

#define NB_WPREP 2624    // OWTOT/256
#define NB_VNB   5000    // Nn*64/256
#define NB_NFS   625     // Nn/32

typedef __attribute__((ext_vector_type(8))) short bf16x8;
typedef __attribute__((ext_vector_type(4))) float f32x4;

__device__ __forceinline__ float rcp_f(float x) {
    return __builtin_amdgcn_rcpf(x);
}
__device__ __forceinline__ float silu_f(float x) {
    return x * rcp_f(1.0f + __expf(-x));
}
__device__ __forceinline__ ushort f2b(float v) {
    __hip_bfloat16 h = __float2bfloat16(v);
    return *(ushort*)&h;
}
__device__ __forceinline__ float b2f(ushort u) {
    union { unsigned int i; float f; } c;
    c.i = ((unsigned int)u) << 16;
    return c.f;
}

// k_edge K=256 GEMM: 4 m-tiles x 2 n-tiles per wave. A from LDS, B frag-packed.
#define KLOOP2(SRC, WP)                                                        \
    {                                                                          \
        _Pragma("unroll")                                                      \
        for (int mt = 0; mt < 4; ++mt)                                         \
            _Pragma("unroll")                                                  \
            for (int nt = 0; nt < 2; ++nt) acc[mt][nt] = (f32x4)0.f;           \
        _Pragma("unroll")                                                      \
        for (int ks = 0; ks < 8; ++ks) {                                       \
            bf16x8 a_[4];                                                      \
            _Pragma("unroll")                                                  \
            for (int mt = 0; mt < 4; ++mt)                                     \
                a_[mt] = *(const bf16x8*)&(SRC)[(mt * 16 + lr) * MSTR + ks * 32 + lk * 8]; \
            _Pragma("unroll")                                                  \
            for (int nt = 0; nt < 2; ++nt) {                                   \
                const bf16x8 b = *(const bf16x8*)&(WP)[(size_t)(((wv * 2 + nt) * 8 + ks) * 512) + lane * 8]; \
                _Pragma("unroll")                                              \
                for (int mt = 0; mt < 4; ++mt)                                 \
                    acc[mt][nt] = __builtin_amdgcn_mfma_f32_16x16x32_bf16(a_[mt], b, acc[mt][nt], 0, 0, 0); \
            }                                                                  \
        }                                                                      \
    }

#define EPI_SILU2(DST, BIAS)                                                   \
    _Pragma("unroll")                                                          \
    for (int nt = 0; nt < 2; ++nt) {                                           \
        const int col = colBase + nt * 16 + lr;                                \
        const float bb = (BIAS)[col];                                          \
        _Pragma("unroll")                                                      \
        for (int mt = 0; mt < 4; ++mt)                                         \
            _Pragma("unroll")                                                  \
            for (int r = 0; r < 4; ++r) {                                      \
                const int row = mt * 16 + lk * 4 + r;                          \
                (DST)[row * MSTR + col] = f2b(silu_f(acc[mt][nt][r] + bb));    \
            }                                                                  \
    }

// k_node K=256 GEMM (round-8 form): 2 m-tiles x 4 n-tiles per wave.
#define KLOOP_FR(SRC, WP)                                                      \
    {                                                                          \
        _Pragma("unroll")                                                      \
        for (int mt = 0; mt < 2; ++mt)                                         \
            _Pragma("unroll")                                                  \
            for (int nt = 0; nt < 4; ++nt) accn[mt][nt] = (f32x4)0.f;          \
        _Pragma("unroll")                                                      \
        for (int ks = 0; ks < 8; ++ks) {                                       \
            const bf16x8 a0 = *(const bf16x8*)&(SRC)[lr * MSTR + ks * 32 + lk * 8];        \
            const bf16x8 a1 = *(const bf16x8*)&(SRC)[(lr + 16) * MSTR + ks * 32 + lk * 8]; \
            _Pragma("unroll")                                                  \
            for (int nt = 0; nt < 4; ++nt) {                                   \
                const bf16x8 b = *(const bf16x8*)&(WP)[(size_t)(((wv * 4 + nt) * 8 + ks) * 512) + lane * 8]; \
                accn[0][nt] = __builtin_amdgcn_mfma_f32_16x16x32_bf16(a0, b, accn[0][nt], 0, 0, 0); \
                accn[1][nt] = __builtin_amdgcn_mfma_f32_16x16x32_bf16(a1, b, accn[1][nt], 0, 0, 0); \
            }                                                                  \
        }                                                                      \
    }

#define EPI_SILUN(DST, BIAS)                                                   \
    _Pragma("unroll")                                                          \
    for (int nt = 0; nt < 4; ++nt) {                                           \
        const int col = colBase + nt * 16 + lr;                                \
        const float bb = (BIAS)[col];                                          \
        _Pragma("unroll")                                                      \
        for (int mt = 0; mt < 2; ++mt)                                         \
            _Pragma("unroll")                                                  \
            for (int r = 0; r < 4; ++r) {                                      \
                const int row = mt * 16 + lk * 4 + r;                          \
                (DST)[row * MSTR + col] = f2b(silu_f(accn[mt][nt][r] + bb));   \
            }                                                                  \
    }

// ---------------------------------------------------------------- k_prep
// Merged: wprep [0,2624) | vnb [2624,7624) | nfs [7624,8249) | count [8249,..)
__global__ __launch_bounds__(256) void k_prep(
    const float* __restrict__ w1, const float* __restrict__ w2,
    const float* __restrict__ vrw1, const float* __restrict__ rvw1,
    const float* __restrict__ vrw2, const float* __restrict__ rvw2,
    const float* __restrict__ ftw1, const float* __restrict__ ftw2,
    const float* __restrict__ f2tw1, const float* __restrict__ f2tw2,
    const float* __restrict__ vfw1, const float* __restrict__ vfw2,
    ushort* __restrict__ wb,
    const float* __restrict__ vn_feat, ushort* __restrict__ vnb,
    const float* __restrict__ node_feat, const float* __restrict__ w_scalar,
    ushort* __restrict__ nfsb,
    const int* __restrict__ eidx, int* __restrict__ cnt_i, int E)
{
    __shared__ float At[32][20];
    __shared__ float Wt[16][128];
    const int bid = blockIdx.x;
    const int t = threadIdx.x;

    if (bid < NB_WPREP) {
        const int idx = bid * 256 + t;
        ushort v;
        if (idx < OW2) {
            const int o = idx, f = o >> 9, l = (o >> 3) & 63, e = o & 7;
            const int nt = f / 13, ks = f % 13;
            const int col = nt * 16 + (l & 15);
            const int k = ks * 32 + ((l >> 4) << 3) + e;
            v = (k < 400) ? f2b(w1[(size_t)k * 256 + col]) : (ushort)0;
        } else if (idx < OVR1) {
            const int o = idx - OW2, f = o >> 9, l = (o >> 3) & 63, e = o & 7;
            const int col = (f >> 3) * 16 + (l & 15);
            const int k = (f & 7) * 32 + ((l >> 4) << 3) + e;
            v = f2b(w2[(size_t)k * 256 + col]);
        } else if (idx < ORV1) {
            const int o = idx - OVR1, f = o >> 9, l = (o >> 3) & 63, e = o & 7;
            const int col = (f >> 3) * 16 + (l & 15);
            const int k = (f & 7) * 32 + ((l >> 4) << 3) + e;
            v = f2b(vrw1[(size_t)k * 256 + col]);
        } else if (idx < OVR2) {
            const int o = idx - ORV1, f = o >> 9, l = (o >> 3) & 63, e = o & 7;
            const int col = (f >> 3) * 16 + (l & 15);
            const int k = (f & 7) * 32 + ((l >> 4) << 3) + e;
            v = f2b(rvw1[(size_t)k * 256 + col]);
        } else if (idx < ORV2) {
            const int o = idx - OVR2, f = o >> 9, l = (o >> 3) & 63, e = o & 7;
            const int col = l & 15;
            const int k = f * 32 + ((l >> 4) << 3) + e;
            v = (col < 4) ? f2b(vrw2[(size_t)k * 4 + col]) : (ushort)0;
        } else if (idx < OFT1) {
            const int o = idx - ORV2, f = o >> 9, l = (o >> 3) & 63, e = o & 7;
            const int col = l & 15;
            const int k = f * 32 + ((l >> 4) << 3) + e;
            v = f2b(rvw2[(size_t)k * 16 + col]);
        } else if (idx < OFT2) {
            const int o = idx - OFT1, f = o >> 9, l = (o >> 3) & 63, e = o & 7;
            const int col = (f >> 3) * 16 + (l & 15);
            const int k = (f & 7) * 32 + ((l >> 4) << 3) + e;
            v = f2b(ftw1[(size_t)k * 256 + col]);
        } else if (idx < OF2T1) {
            const int o = idx - OFT2, f = o >> 9, l = (o >> 3) & 63, e = o & 7;
            const int col = (f >> 3) * 16 + (l & 15);
            const int k = (f & 7) * 32 + ((l >> 4) << 3) + e;
            v = f2b(ftw2[(size_t)k * 256 + col]);
        } else if (idx < OF2T2) {
            const int o = idx - OF2T1, f = o >> 9, l = (o >> 3) & 63, e = o & 7;
            const int col = (f >> 3) * 16 + (l & 15);
            const int k = (f & 7) * 32 + ((l >> 4) << 3) + e;
            v = f2b(f2tw1[(size_t)k * 256 + col]);
        } else if (idx < OVF1) {
            const int o = idx - OF2T2, f = o >> 9, l = (o >> 3) & 63, e = o & 7;
            const int col = (f >> 3) * 16 + (l & 15);
            const int k = (f & 7) * 32 + ((l >> 4) << 3) + e;
            v = f2b(f2tw2[(size_t)k * 128 + col]);
        } else if (idx < OVF2) {
            const int o = idx - OVF1, f = o >> 9, l = (o >> 3) & 63, e = o & 7;
            const int col = (f >> 3) * 16 + (l & 15);
            const int k = (f & 7) * 32 + ((l >> 4) << 3) + e;
            v = f2b(vfw1[(size_t)k * 256 + col]);
        } else {
            const int o = idx - OVF2, f = o >> 9, l = (o >> 3) & 63, e = o & 7;
            const int col = (f >> 3) * 16 + (l & 15);
            const int k = (f & 7) * 32 + ((l >> 4) << 3) + e;
            v = f2b(vfw2[(size_t)k * 256 + col]);
        }
        wb[idx] = v;
    } else if (bid < NB_WPREP + NB_VNB) {
        const int i = (bid - NB_WPREP) * 256 + t;
        const float4 v = *(const float4*)&vn_feat[(size_t)i * 4];
        ushort4 o;
        o.x = f2b(v.x); o.y = f2b(v.y); o.z = f2b(v.z); o.w = f2b(v.w);
        *(ushort4*)&vnb[(size_t)i * 4] = o;
    } else if (bid < NB_WPREP + NB_VNB + NB_NFS) {
        const int m0 = (bid - NB_WPREP - NB_VNB) * 32;
        const int c4 = (t & 31) * 4;
        const int rg = t >> 5;
        float acc[4][4] = {};
        for (int k0 = 0; k0 < 128; k0 += 16) {
            if (t < 128) {
                const int r = t >> 2, kk = (t & 3) * 4;
                *(float4*)&At[r][kk] =
                    *(const float4*)&node_feat[(size_t)(m0 + r) * FEAT + k0 + kk];
            }
            #pragma unroll
            for (int i = 0; i < 2; ++i) {
                const int p  = t + i * 256;
                const int wr = p >> 5, wc = (p & 31) * 4;
                *(float4*)&Wt[wr][wc] =
                    *(const float4*)&w_scalar[(size_t)(k0 + wr) * SDIM + wc];
            }
            __syncthreads();
            #pragma unroll
            for (int kk = 0; kk < 16; ++kk) {
                const float4 w = *(const float4*)&Wt[kk][c4];
                #pragma unroll
                for (int j = 0; j < 4; ++j) {
                    const float a = At[rg * 4 + j][kk];
                    acc[j][0] = fmaf(a, w.x, acc[j][0]);
                    acc[j][1] = fmaf(a, w.y, acc[j][1]);
                    acc[j][2] = fmaf(a, w.z, acc[j][2]);
                    acc[j][3] = fmaf(a, w.w, acc[j][3]);
                }
            }
            __syncthreads();
        }
        const float s = 0.08838834764831845f;
        #pragma unroll
        for (int j = 0; j < 4; ++j) {
            ushort4 o;
            o.x = f2b(acc[j][0] * s); o.y = f2b(acc[j][1] * s);
            o.z = f2b(acc[j][2] * s); o.w = f2b(acc[j][3] * s);
            *(ushort4*)&nfsb[(size_t)(m0 + rg * 4 + j) * SDIM + c4] = o;
        }
    } else {
        const int e = (bid - NB_WPREP - NB_VNB - NB_NFS) * 256 + t;
        if (e < E) atomicAdd(&cnt_i[eidx[e]], 1);
    }
}

// ---------------------------------------------------------------- scan
__global__ __launch_bounds__(1024) void k_scanA(
    const int* __restrict__ cnt_i, int* __restrict__ rowstart,
    float* __restrict__ cntf, int* __restrict__ bsum, int Nn)
{
    __shared__ int sh[1024];
    const int t = threadIdx.x;
    const int i = blockIdx.x * 1024 + t;
    const int v = (i < Nn) ? cnt_i[i] : 0;
    sh[t] = v;
    __syncthreads();
    for (int off = 1; off < 1024; off <<= 1) {
        const int add = (t >= off) ? sh[t - off] : 0;
        __syncthreads();
        sh[t] += add;
        __syncthreads();
    }
    if (i < Nn) {
        rowstart[i + 1] = sh[t];
        cntf[i] = fmaxf((float)v, 1.0f);
    }
    if (t == 1023) bsum[blockIdx.x] = sh[t];
}

__global__ __launch_bounds__(1024) void k_scanC(
    int* __restrict__ rowstart, const int* __restrict__ bsum, int Nn)
{
    __shared__ int carry_s;
    const int t = threadIdx.x;
    if (t == 0) {
        int s = 0;
        for (int b = 0; b < (int)blockIdx.x; ++b) s += bsum[b];
        carry_s = s;
    }
    __syncthreads();
    const int i = blockIdx.x * 1024 + t;
    if (i < Nn) rowstart[i + 1] += carry_s;
    if (i == 0) rowstart[0] = 0;
}

__global__ __launch_bounds__(256) void k_place(
    const int* __restrict__ eidx, const int* __restrict__ rowstart,
    int* __restrict__ cursor, int* __restrict__ elist, int E)
{
    const int e = blockIdx.x * 256 + threadIdx.x;
    if (e < E) {
        const int r = eidx[e];
        const int p = atomicAdd(&cursor[r], 1);
        elist[rowstart[r] + p] = e;
    }
}

// ---------------------------------------------------------------- k_edge
// 64 row-sorted edges/block, 512 threads = 8 waves. LDS 78.3KB -> 2 blk/CU.
__global__ __launch_bounds__(512, 4) void k_edge(
    const ushort* __restrict__ nfsb, const ushort* __restrict__ vnb,
    const float* __restrict__ node_pos, const float* __restrict__ vn_pos,
    const int* __restrict__ eidx, const int* __restrict__ elist,
    const ushort* __restrict__ wb,
    const float* __restrict__ b1, const float* __restrict__ b2,
    const float* __restrict__ vrb1, const float* __restrict__ vrb2,
    const float* __restrict__ rvb1, const float* __restrict__ rvb2,
    float* __restrict__ agg_feat, float* __restrict__ agg_vr,
    float* __restrict__ agg_rv, int E)
{
    __shared__ ushort Mg[64 * MSTR];   // msg; later rv-hidden overlay
    __shared__ ushort Hd[64 * MSTR];   // cm hidden, then vr hidden
    __shared__ ushort ipB[64 * 16];
    __shared__ float dnS[64][12];
    __shared__ float wvrS[64][4];
    __shared__ float wrvS[64][16];
    __shared__ int rowi[64], coli[64];

    const int t  = threadIdx.x;
    const int e0 = blockIdx.x * 64;
    const int wv = t >> 6;             // 0..7
    const int lane = t & 63;
    const int lr = lane & 15;
    const int lk = lane >> 4;
    const int colBase = wv * 32;       // 2 n-tiles per wave

    // ---- geometry (t<64), row-sorted edges ----
    if (t < 64) {
        const int e = elist[e0 + t];
        const int r = eidx[e];
        const int c = eidx[E + e];
        rowi[t] = r; coli[t] = c;
        const float px = node_pos[r * 3 + 0];
        const float py = node_pos[r * 3 + 1];
        const float pz = node_pos[r * 3 + 2];
        float d[4][3];
        #pragma unroll
        for (int ch = 0; ch < 4; ++ch) {
            d[ch][0] = px - vn_pos[(size_t)c * 12 + ch * 3 + 0];
            d[ch][1] = py - vn_pos[(size_t)c * 12 + ch * 3 + 1];
            d[ch][2] = pz - vn_pos[(size_t)c * 12 + ch * 3 + 2];
        }
        float ss = 0.f, ipv[16];
        #pragma unroll
        for (int ci = 0; ci < 4; ++ci)
            #pragma unroll
            for (int ck = 0; ck < 4; ++ck) {
                const float v = d[ci][0]*d[ck][0] + d[ci][1]*d[ck][1] + d[ci][2]*d[ck][2];
                ipv[ci * 4 + ck] = v; ss += v * v;
            }
        const float inrm = rcp_f(fmaxf(sqrtf(ss), 1e-8f));
        #pragma unroll
        for (int i = 0; i < 16; ++i) ipB[t * 16 + i] = f2b(ipv[i] * inrm);
        #pragma unroll
        for (int ch = 0; ch < 4; ++ch) {
            const float nn = sqrtf(d[ch][0]*d[ch][0] + d[ch][1]*d[ch][1] + d[ch][2]*d[ch][2]);
            const float s = rcp_f(fmaxf(nn, 1e-8f));
            dnS[t][ch * 3 + 0] = d[ch][0] * s;
            dnS[t][ch * 3 + 1] = d[ch][1] * s;
            dnS[t][ch * 3 + 2] = d[ch][2] * s;
        }
    }
    __syncthreads();

    // per-lane A row pointers for cm1 (4 m-tiles)
    const ushort* nA[4]; const ushort* vA[4];
    #pragma unroll
    for (int mt = 0; mt < 4; ++mt) {
        nA[mt] = nfsb + (size_t)rowi[mt * 16 + lr] * SDIM + lk * 8;
        vA[mt] = vnb  + (size_t)coli[mt * 16 + lr] * HDIM + lk * 8;
    }
    const ushort* w1t = wb + OW1;

    f32x4 acc[4][2];

    // ===== cm layer 1 (K=416: 128 nfs | 256 vn | 16 ip | 16 zero) =====
    #pragma unroll
    for (int mt = 0; mt < 4; ++mt)
        #pragma unroll
        for (int nt = 0; nt < 2; ++nt) acc[mt][nt] = (f32x4)0.f;
    #pragma unroll
    for (int ks = 0; ks < 13; ++ks) {
        bf16x8 a_[4];
        #pragma unroll
        for (int mt = 0; mt < 4; ++mt) {
            if (ks < 4)       a_[mt] = *(const bf16x8*)(nA[mt] + ks * 32);
            else if (ks < 12) a_[mt] = *(const bf16x8*)(vA[mt] + ks * 32 - 128);
            else if (lk < 2)  a_[mt] = *(const bf16x8*)&ipB[(mt * 16 + lr) * 16 + lk * 8];
            else              a_[mt] = (bf16x8)(short)0;
        }
        #pragma unroll
        for (int nt = 0; nt < 2; ++nt) {
            const bf16x8 b = *(const bf16x8*)&w1t[(size_t)(((wv * 2 + nt) * 13 + ks) * 512) + lane * 8];
            #pragma unroll
            for (int mt = 0; mt < 4; ++mt)
                acc[mt][nt] = __builtin_amdgcn_mfma_f32_16x16x32_bf16(a_[mt], b, acc[mt][nt], 0, 0, 0);
        }
    }
    EPI_SILU2(Hd, b1);
    __syncthreads();

    // ===== cm layer 2 -> msg =====
    KLOOP2(Hd, wb + OW2);
    #pragma unroll
    for (int nt = 0; nt < 2; ++nt) {
        const int col = colBase + nt * 16 + lr;
        const float bb = b2[col];
        #pragma unroll
        for (int mt = 0; mt < 4; ++mt)
            #pragma unroll
            for (int r = 0; r < 4; ++r) {
                const int row = mt * 16 + lk * 4 + r;
                Mg[row * MSTR + col] = f2b(acc[mt][nt][r] + bb);
            }
    }
    __syncthreads();

    // ===== segmented reduction msg -> agg_feat (two 32-row halves) =====
    {
        const int col = t & 255;
        const int r0 = (t >> 8) * 32;
        float s = 0.f;
        int prev = rowi[r0];
        for (int r = r0; r < r0 + 32; ++r) {
            const int rr = rowi[r];
            if (rr != prev) {
                atomicAdd(&agg_feat[(size_t)prev * HDIM + col], s);
                s = 0.f; prev = rr;
            }
            s += b2f(Mg[r * MSTR + col]);
        }
        atomicAdd(&agg_feat[(size_t)prev * HDIM + col], s);
    }

    // ===== vr layer 1 (reads Mg, writes Hd) =====
    KLOOP2(Mg, wb + OVR1);
    EPI_SILU2(Hd, vrb1);

    // ===== rv layer 1 (reads Mg; barrier; epilogue overwrites Mg) =====
    KLOOP2(Mg, wb + ORV1);
    __syncthreads();                   // all Mg reads done + Hd writes visible
    #pragma unroll
    for (int nt = 0; nt < 2; ++nt) {
        const int col = colBase + nt * 16 + lr;
        const float br = rvb1[col];
        #pragma unroll
        for (int mt = 0; mt < 4; ++mt)
            #pragma unroll
            for (int r = 0; r < 4; ++r) {
                const int row = mt * 16 + lk * 4 + r;
                Mg[row * MSTR + col] = f2b(silu_f(acc[mt][nt][r] + br));  // rv hidden
            }
    }
    __syncthreads();

    // ===== vr2 (waves 0,4 from Hd) CONCURRENT with rv2 (waves 1,5 from Mg) =====
    if ((wv & 3) == 0) {
        const int rb = (wv >> 2) * 32;
        const ushort* vrw2t = wb + OVR2;
        f32x4 a2[2]; a2[0] = (f32x4)0.f; a2[1] = (f32x4)0.f;
        #pragma unroll
        for (int ks = 0; ks < 8; ++ks) {
            const bf16x8 a0 = *(const bf16x8*)&Hd[(rb + lr) * MSTR + ks * 32 + lk * 8];
            const bf16x8 a1 = *(const bf16x8*)&Hd[(rb + 16 + lr) * MSTR + ks * 32 + lk * 8];
            const bf16x8 b  = *(const bf16x8*)&vrw2t[(size_t)(ks * 512) + lane * 8];
            a2[0] = __builtin_amdgcn_mfma_f32_16x16x32_bf16(a0, b, a2[0], 0, 0, 0);
            a2[1] = __builtin_amdgcn_mfma_f32_16x16x32_bf16(a1, b, a2[1], 0, 0, 0);
        }
        if (lr < 4) {
            const float bb = vrb2[lr];
            #pragma unroll
            for (int mt = 0; mt < 2; ++mt)
                #pragma unroll
                for (int r = 0; r < 4; ++r)
                    wvrS[rb + mt * 16 + lk * 4 + r][lr] = a2[mt][r] + bb;
        }
    } else if ((wv & 3) == 1) {
        const int rb = (wv >> 2) * 32;
        const ushort* rvw2t = wb + ORV2;
        f32x4 a2[2]; a2[0] = (f32x4)0.f; a2[1] = (f32x4)0.f;
        #pragma unroll
        for (int ks = 0; ks < 8; ++ks) {
            const bf16x8 a0 = *(const bf16x8*)&Mg[(rb + lr) * MSTR + ks * 32 + lk * 8];
            const bf16x8 a1 = *(const bf16x8*)&Mg[(rb + 16 + lr) * MSTR + ks * 32 + lk * 8];
            const bf16x8 b  = *(const bf16x8*)&rvw2t[(size_t)(ks * 512) + lane * 8];
            a2[0] = __builtin_amdgcn_mfma_f32_16x16x32_bf16(a0, b, a2[0], 0, 0, 0);
            a2[1] = __builtin_amdgcn_mfma_f32_16x16x32_bf16(a1, b, a2[1], 0, 0, 0);
        }
        const float bb = rvb2[lr];
        #pragma unroll
        for (int mt = 0; mt < 2; ++mt)
            #pragma unroll
            for (int r = 0; r < 4; ++r)
                wrvS[rb + mt * 16 + lk * 4 + r][lr] = a2[mt][r] + bb;
    }
    __syncthreads();

    // ===== per-edge geometric update (t<64) =====
    if (t < 64) {
        float wvv[4], wrr[16], dn[12], ev[15];
        #pragma unroll
        for (int c = 0; c < 4; ++c)  wvv[c] = wvrS[t][c];
        #pragma unroll
        for (int i = 0; i < 16; ++i) wrr[i] = wrvS[t][i];
        #pragma unroll
        for (int i = 0; i < 12; ++i) dn[i]  = dnS[t][i];
        #pragma unroll
        for (int j = 0; j < 3; ++j) {
            float v = 0.f;
            #pragma unroll
            for (int c = 0; c < 4; ++c) v = fmaf(wvv[c], dn[c * 3 + j], v);
            ev[j] = 0.5f * v;
        }
        #pragma unroll
        for (int u = 0; u < 4; ++u)
            #pragma unroll
            for (int j = 0; j < 3; ++j) {
                float v = 0.f;
                #pragma unroll
                for (int c = 0; c < 4; ++c) v = fmaf(wrr[c * 4 + u], dn[c * 3 + j], v);
                ev[3 + u * 3 + j] = -0.5f * v;
            }
        #pragma unroll
        for (int i = 0; i < 15; ++i) wrvS[t][i] = ev[i];
    }
    __syncthreads();

    // ===== segmented reduction vr/rv (two halves) =====
    if ((t & 255) < 15) {
        const int comp = t & 255;
        const int r0 = (t >> 8) * 32;
        float s = 0.f;
        int prev = rowi[r0];
        for (int r = r0; r < r0 + 32; ++r) {
            const int rr = rowi[r];
            if (rr != prev) {
                if (comp < 3) atomicAdd(&agg_vr[(size_t)prev * 3 + comp], s);
                else          atomicAdd(&agg_rv[(size_t)prev * 12 + (comp - 3)], s);
                s = 0.f; prev = rr;
            }
            s += wrvS[r][comp];
        }
        if (comp < 3) atomicAdd(&agg_vr[(size_t)prev * 3 + comp], s);
        else          atomicAdd(&agg_rv[(size_t)prev * 12 + (comp - 3)], s);
    }
}

// ---------------------------------------------------------------- k_node
// 32 nodes/block (625 blocks), 256 threads = 4 waves (round-8 form).
__global__ __launch_bounds__(256, 4) void k_node(
    const float* __restrict__ node_feat, const float* __restrict__ node_pos,
    const float* __restrict__ vn_feat, const float* __restrict__ vn_pos,
    const float* __restrict__ agg_feat, const float* __restrict__ agg_vr,
    const float* __restrict__ agg_rv, const float* __restrict__ cntf,
    const ushort* __restrict__ wb,
    const float* __restrict__ ftb1, const float* __restrict__ ftb2,
    const float* __restrict__ f2tb1, const float* __restrict__ f2tb2,
    const float* __restrict__ vfb1, const float* __restrict__ vfb2,
    float* __restrict__ out, int Nn)
{
    __shared__ ushort Ab[32 * MSTR];
    __shared__ ushort Hd[32 * MSTR];
    __shared__ float rc[32];
    const int t  = threadIdx.x;
    const int n0 = blockIdx.x * 32;
    const int wv = t >> 6;
    const int lane = t & 63;
    const int lr = lane & 15;
    const int lk = lane >> 4;
    const int colBase = wv * 64;

    float* nf_out = out;
    float* np_out = out + (size_t)Nn * FEAT;
    float* vf_out = np_out + (size_t)Nn * 3;
    float* vp_out = vf_out + (size_t)Nn * HDIM;

    if (t < 32) rc[t] = rcp_f(fmaxf(cntf[n0 + t], 1.0f));
    __syncthreads();
    #pragma unroll
    for (int i = 0; i < 8; ++i) {
        const int p = t + i * 256;
        const int r = p >> 6, cc = (p & 63) * 4;
        float4 v = *(const float4*)&agg_feat[(size_t)(n0 + r) * HDIM + cc];
        const float s = rc[r];
        ushort4 o;
        o.x = f2b(v.x * s); o.y = f2b(v.y * s);
        o.z = f2b(v.z * s); o.w = f2b(v.w * s);
        *(ushort4*)&Ab[r * MSTR + cc] = o;
    }
    __syncthreads();

    f32x4 accn[2][4];

    // ---- vf MLP ----
    KLOOP_FR(Ab, wb + OVF1);
    EPI_SILUN(Hd, vfb1);
    __syncthreads();
    KLOOP_FR(Hd, wb + OVF2);
    #pragma unroll
    for (int nt = 0; nt < 4; ++nt) {
        const int col = colBase + nt * 16 + lr;
        const float bb = vfb2[col];
        #pragma unroll
        for (int mt = 0; mt < 2; ++mt)
            #pragma unroll
            for (int r = 0; r < 4; ++r) {
                const int row = mt * 16 + lk * 4 + r;
                const size_t o = (size_t)(n0 + row) * HDIM + col;
                vf_out[o] = vn_feat[o] + accn[mt][nt][r] + bb;
            }
    }
    __syncthreads();

    // ---- ft MLP ----
    KLOOP_FR(Ab, wb + OFT1);
    EPI_SILUN(Hd, ftb1);
    __syncthreads();
    KLOOP_FR(Hd, wb + OFT2);
    #pragma unroll
    for (int nt = 0; nt < 4; ++nt) {
        const int col = colBase + nt * 16 + lr;
        const float bb = ftb2[col];
        #pragma unroll
        for (int mt = 0; mt < 2; ++mt)
            #pragma unroll
            for (int r = 0; r < 4; ++r) {
                const int row = mt * 16 + lk * 4 + r;
                Ab[row * MSTR + col] = f2b(accn[mt][nt][r] + bb);
            }
    }
    __syncthreads();

    // ---- f2t MLP ----
    KLOOP_FR(Ab, wb + OF2T1);
    EPI_SILUN(Hd, f2tb1);
    __syncthreads();
    {
        const ushort* w2p = wb + OF2T2;
        f32x4 a2[2][2];
        #pragma unroll
        for (int mt = 0; mt < 2; ++mt)
            #pragma unroll
            for (int nt = 0; nt < 2; ++nt) a2[mt][nt] = (f32x4)0.f;
        #pragma unroll
        for (int ks = 0; ks < 8; ++ks) {
            const int k0 = ks * 32 + lk * 8;
            const bf16x8 a0 = *(const bf16x8*)&Hd[lr * MSTR + k0];
            const bf16x8 a1 = *(const bf16x8*)&Hd[(lr + 16) * MSTR + k0];
            const bf16x8 w0 = *(const bf16x8*)&w2p[(size_t)(((wv * 2 + 0) * 8 + ks) * 512) + lane * 8];
            const bf16x8 w1v = *(const bf16x8*)&w2p[(size_t)(((wv * 2 + 1) * 8 + ks) * 512) + lane * 8];
            a2[0][0] = __builtin_amdgcn_mfma_f32_16x16x32_bf16(a0, w0, a2[0][0], 0, 0, 0);
            a2[1][0] = __builtin_amdgcn_mfma_f32_16x16x32_bf16(a1, w0, a2[1][0], 0, 0, 0);
            a2[0][1] = __builtin_amdgcn_mfma_f32_16x16x32_bf16(a0, w1v, a2[0][1], 0, 0, 0);
            a2[1][1] = __builtin_amdgcn_mfma_f32_16x16x32_bf16(a1, w1v, a2[1][1], 0, 0, 0);
        }
        #pragma unroll
        for (int nt = 0; nt < 2; ++nt) {
            const int col = wv * 32 + nt * 16 + lr;
            const float bb = f2tb2[col];
            #pragma unroll
            for (int mt = 0; mt < 2; ++mt)
                #pragma unroll
                for (int r = 0; r < 4; ++r) {
                    const int row = mt * 16 + lk * 4 + r;
                    const size_t o = (size_t)(n0 + row) * FEAT + col;
                    nf_out[o] = node_feat[o] + a2[mt][nt][r] + bb;
                }
        }
    }

    // passthrough cols 128..479
    for (int p = t; p < 32 * 88; p += 256) {
        const int r = p / 88;
        const int cc = 128 + (p % 88) * 4;
        const size_t o = (size_t)(n0 + r) * FEAT + cc;
        *(float4*)&nf_out[o] = *(const float4*)&node_feat[o];
    }
    if (t < 32) {
        const int n = n0 + t;
        const float s = rc[t];
        #pragma unroll
        for (int j = 0; j < 3; ++j)
            np_out[(size_t)n * 3 + j] = node_pos[(size_t)n * 3 + j] + agg_vr[(size_t)n * 3 + j] * s;
        #pragma unroll
        for (int j = 0; j < 12; ++j)
            vp_out[(size_t)n * 12 + j] = vn_pos[(size_t)n * 12 + j] + agg_rv[(size_t)n * 12 + j] * s;
    }
}

// ---------------------------------------------------------------- launch
extern "C" void kernel_launch(void* const* d_in, const int* in_sizes, int n_in,
                              void* d_out, int out_size, void* d_ws, size_t ws_size,
                              hipStream_t stream)
{
    (void)n_in; (void)out_size; (void)ws_size;
    const float* node_feat = (const float*)d_in[0];
    const float* node_pos  = (const float*)d_in[1];
    const float* vn_feat   = (const float*)d_in[2];
    const float* vn_pos    = (const float*)d_in[3];
    const int*   eidx      = (const int*)d_in[4];
    const float* w_scalar  = (const float*)d_in[5];
    const float* cm_w1  = (const float*)d_in[6];
    const float* cm_b1  = (const float*)d_in[7];
    const float* cm_w2  = (const float*)d_in[8];
    const float* cm_b2  = (const float*)d_in[9];
    const float* vr_w1  = (const float*)d_in[10];
    const float* vr_b1  = (const float*)d_in[11];
    const float* vr_w2  = (const float*)d_in[12];
    const float* vr_b2  = (const float*)d_in[13];
    const float* rv_w1  = (const float*)d_in[14];
    const float* rv_b1  = (const float*)d_in[15];
    const float* rv_w2  = (const float*)d_in[16];
    const float* rv_b2  = (const float*)d_in[17];
    const float* ft_w1  = (const float*)d_in[18];
    const float* ft_b1  = (const float*)d_in[19];
    const float* ft_w2  = (const float*)d_in[20];
    const float* ft_b2  = (const float*)d_in[21];
    const float* f2t_w1 = (const float*)d_in[22];
    const float* f2t_b1 = (const float*)d_in[23];
    const float* f2t_w2 = (const float*)d_in[24];
    const float* f2t_b2 = (const float*)d_in[25];
    const float* vf_w1  = (const float*)d_in[26];
    const float* vf_b1  = (const float*)d_in[27];
    const float* vf_w2  = (const float*)d_in[28];
    const float* vf_b2  = (const float*)d_in[29];

    const int Nn = in_sizes[0] / FEAT;        // 20000
    const int E  = in_sizes[4] / 2;           // 240000

    // workspace layout
    float* ws       = (float*)d_ws;
    float* agg_feat = ws;                                // Nn*256 (zeroed)
    float* agg_vr   = agg_feat + (size_t)Nn * HDIM;      // Nn*3   (zeroed)
    float* agg_rv   = agg_vr   + (size_t)Nn * 3;         // Nn*12  (zeroed)
    float* cntf     = agg_rv   + (size_t)Nn * 12;        // Nn     (zeroed)
    int*   cnt_i    = (int*)(cntf + Nn);                 // Nn     (zeroed)
    int*   cursor   = cnt_i + Nn;                        // Nn     (zeroed)
    int*   rowstart = cursor + Nn;                       // Nn+8
    int*   bsum     = rowstart + Nn + 8;                 // 64
    int*   elist    = bsum + 64;                         // E
    ushort* nfsb = (ushort*)(elist + E);                 // Nn*128
    ushort* vnb  = nfsb + (size_t)Nn * SDIM;             // Nn*256
    ushort* wb   = vnb  + (size_t)Nn * HDIM;             // OWTOT

    const size_t zero_bytes = (size_t)Nn * (HDIM + 3 + 12 + 1 + 2) * sizeof(float);
    hipMemsetAsync(agg_feat, 0, zero_bytes, stream);

    const int eg = (E + 255) / 256;           // 938
    const int sb = (Nn + 1023) / 1024;        // 20 scan blocks
    k_prep<<<NB_WPREP + NB_VNB + NB_NFS + eg, 256, 0, stream>>>(
        cm_w1, cm_w2, vr_w1, rv_w1, vr_w2, rv_w2,
        ft_w1, ft_w2, f2t_w1, f2t_w2, vf_w1, vf_w2, wb,
        vn_feat, vnb, node_feat, w_scalar, nfsb,
        eidx, cnt_i, E);
    k_scanA<<<sb, 1024, 0, stream>>>(cnt_i, rowstart, cntf, bsum, Nn);
    k_scanC<<<sb, 1024, 0, stream>>>(rowstart, bsum, Nn);
    k_place<<<eg, 256, 0, stream>>>(eidx, rowstart, cursor, elist, E);
    k_edge<<<E / 64, 512, 0, stream>>>(nfsb, vnb, node_pos, vn_pos, eidx, elist,
                                       wb, cm_b1, cm_b2, vr_b1, vr_b2, rv_b1, rv_b2,
                                       agg_feat, agg_vr, agg_rv, E);
    k_node<<<Nn / 32, 256, 0, stream>>>(node_feat, node_pos, vn_feat, vn_pos,
                                        agg_feat, agg_vr, agg_rv, cntf, wb,
                                        ft_b1, ft_b2, f2t_b1, f2t_b2, vf_b1, vf_b2,
                                        (float*)d_out, Nn);
}

// Round 14
// 409.778 us; speedup vs baseline: 3.4412x; 1.0332x over previous
//
#include <hip/hip_runtime.h>
#include <hip/hip_bf16.h>
#include <math.h>

// VNLayer: N=20000 nodes, E=240000 edges, H=256, SD=128, C=4, FEAT=480
// Round 14: round-13 (423us) + two k_edge-only tweaks:
//  - bijective XCD swizzle of blockIdx (row-sorted blocks -> L2-local
//    nfsb panels / weight lines per XCD)
//  - s_setprio(1) around MFMA clusters (wave role-diversity exists
//    across gather/MFMA phases)

#define FEAT 480
#define HDIM 256
#define SDIM 128
#define MSTR 264    // LDS A row stride (ushorts)

// bf16 weight arena offsets (ushort elements) -- frag-packed regions
#define OW1   0          // cm1 : 16 nt x 13 ks x 512
#define OW2   106496     // cm2 : 16 x 8 x 512
#define OVR1  172032
#define ORV1  237568
#define OVR2  303104     // vr2 : 1 x 8 x 512 (cols>=4 zero)
#define ORV2  307200     // rv2 : 1 x 8 x 512
#define OFT1  311296
#define OFT2  376832
#define OF2T1 442368
#define OF2T2 507904     // f2t2: 8 nt x 8 ks x 512
#define OVF1  540672
#define OVF2  606208
#define OWTOT 671744

#define NB_WPREP 2624    // OWTOT/256
#define NB_VNB   5000    // Nn*64/256
#define NB_NFS   625     // Nn/32

typedef __attribute__((ext_vector_type(8))) short bf16x8;
typedef __attribute__((ext_vector_type(4))) float f32x4;

__device__ __forceinline__ float rcp_f(float x) {
    return __builtin_amdgcn_rcpf(x);
}
__device__ __forceinline__ float silu_f(float x) {
    return x * rcp_f(1.0f + __expf(-x));
}
__device__ __forceinline__ ushort f2b(float v) {
    __hip_bfloat16 h = __float2bfloat16(v);
    return *(ushort*)&h;
}
__device__ __forceinline__ float b2f(ushort u) {
    union { unsigned int i; float f; } c;
    c.i = ((unsigned int)u) << 16;
    return c.f;
}

// k_edge K=256 GEMM: 4 m-tiles x 2 n-tiles per wave. A from LDS, B frag-packed.
#define KLOOP2(SRC, WP)                                                        \
    {                                                                          \
        _Pragma("unroll")                                                      \
        for (int mt = 0; mt < 4; ++mt)                                         \
            _Pragma("unroll")                                                  \
            for (int nt = 0; nt < 2; ++nt) acc[mt][nt] = (f32x4)0.f;           \
        __builtin_amdgcn_s_setprio(1);                                         \
        _Pragma("unroll")                                                      \
        for (int ks = 0; ks < 8; ++ks) {                                       \
            bf16x8 a_[4];                                                      \
            _Pragma("unroll")                                                  \
            for (int mt = 0; mt < 4; ++mt)                                     \
                a_[mt] = *(const bf16x8*)&(SRC)[(mt * 16 + lr) * MSTR + ks * 32 + lk * 8]; \
            _Pragma("unroll")                                                  \
            for (int nt = 0; nt < 2; ++nt) {                                   \
                const bf16x8 b = *(const bf16x8*)&(WP)[(size_t)(((wv * 2 + nt) * 8 + ks) * 512) + lane * 8]; \
                _Pragma("unroll")                                              \
                for (int mt = 0; mt < 4; ++mt)                                 \
                    acc[mt][nt] = __builtin_amdgcn_mfma_f32_16x16x32_bf16(a_[mt], b, acc[mt][nt], 0, 0, 0); \
            }                                                                  \
        }                                                                      \
        __builtin_amdgcn_s_setprio(0);                                         \
    }

#define EPI_SILU2(DST, BIAS)                                                   \
    _Pragma("unroll")                                                          \
    for (int nt = 0; nt < 2; ++nt) {                                           \
        const int col = colBase + nt * 16 + lr;                                \
        const float bb = (BIAS)[col];                                          \
        _Pragma("unroll")                                                      \
        for (int mt = 0; mt < 4; ++mt)                                         \
            _Pragma("unroll")                                                  \
            for (int r = 0; r < 4; ++r) {                                      \
                const int row = mt * 16 + lk * 4 + r;                          \
                (DST)[row * MSTR + col] = f2b(silu_f(acc[mt][nt][r] + bb));    \
            }                                                                  \
    }

// k_node K=256 GEMM (round-8 form): 2 m-tiles x 4 n-tiles per wave.
#define KLOOP_FR(SRC, WP)                                                      \
    {                                                                          \
        _Pragma("unroll")                                                      \
        for (int mt = 0; mt < 2; ++mt)                                         \
            _Pragma("unroll")                                                  \
            for (int nt = 0; nt < 4; ++nt) accn[mt][nt] = (f32x4)0.f;          \
        _Pragma("unroll")                                                      \
        for (int ks = 0; ks < 8; ++ks) {                                       \
            const bf16x8 a0 = *(const bf16x8*)&(SRC)[lr * MSTR + ks * 32 + lk * 8];        \
            const bf16x8 a1 = *(const bf16x8*)&(SRC)[(lr + 16) * MSTR + ks * 32 + lk * 8]; \
            _Pragma("unroll")                                                  \
            for (int nt = 0; nt < 4; ++nt) {                                   \
                const bf16x8 b = *(const bf16x8*)&(WP)[(size_t)(((wv * 4 + nt) * 8 + ks) * 512) + lane * 8]; \
                accn[0][nt] = __builtin_amdgcn_mfma_f32_16x16x32_bf16(a0, b, accn[0][nt], 0, 0, 0); \
                accn[1][nt] = __builtin_amdgcn_mfma_f32_16x16x32_bf16(a1, b, accn[1][nt], 0, 0, 0); \
            }                                                                  \
        }                                                                      \
    }

#define EPI_SILUN(DST, BIAS)                                                   \
    _Pragma("unroll")                                                          \
    for (int nt = 0; nt < 4; ++nt) {                                           \
        const int col = colBase + nt * 16 + lr;                                \
        const float bb = (BIAS)[col];                                          \
        _Pragma("unroll")                                                      \
        for (int mt = 0; mt < 2; ++mt)                                         \
            _Pragma("unroll")                                                  \
            for (int r = 0; r < 4; ++r) {                                      \
                const int row = mt * 16 + lk * 4 + r;                          \
                (DST)[row * MSTR + col] = f2b(silu_f(accn[mt][nt][r] + bb));   \
            }                                                                  \
    }

// ---------------------------------------------------------------- k_prep
// Merged: wprep [0,2624) | vnb [2624,7624) | nfs [7624,8249) | count [8249,..)
__global__ __launch_bounds__(256) void k_prep(
    const float* __restrict__ w1, const float* __restrict__ w2,
    const float* __restrict__ vrw1, const float* __restrict__ rvw1,
    const float* __restrict__ vrw2, const float* __restrict__ rvw2,
    const float* __restrict__ ftw1, const float* __restrict__ ftw2,
    const float* __restrict__ f2tw1, const float* __restrict__ f2tw2,
    const float* __restrict__ vfw1, const float* __restrict__ vfw2,
    ushort* __restrict__ wb,
    const float* __restrict__ vn_feat, ushort* __restrict__ vnb,
    const float* __restrict__ node_feat, const float* __restrict__ w_scalar,
    ushort* __restrict__ nfsb,
    const int* __restrict__ eidx, int* __restrict__ cnt_i, int E)
{
    __shared__ float At[32][20];
    __shared__ float Wt[16][128];
    const int bid = blockIdx.x;
    const int t = threadIdx.x;

    if (bid < NB_WPREP) {
        const int idx = bid * 256 + t;
        ushort v;
        if (idx < OW2) {
            const int o = idx, f = o >> 9, l = (o >> 3) & 63, e = o & 7;
            const int nt = f / 13, ks = f % 13;
            const int col = nt * 16 + (l & 15);
            const int k = ks * 32 + ((l >> 4) << 3) + e;
            v = (k < 400) ? f2b(w1[(size_t)k * 256 + col]) : (ushort)0;
        } else if (idx < OVR1) {
            const int o = idx - OW2, f = o >> 9, l = (o >> 3) & 63, e = o & 7;
            const int col = (f >> 3) * 16 + (l & 15);
            const int k = (f & 7) * 32 + ((l >> 4) << 3) + e;
            v = f2b(w2[(size_t)k * 256 + col]);
        } else if (idx < ORV1) {
            const int o = idx - OVR1, f = o >> 9, l = (o >> 3) & 63, e = o & 7;
            const int col = (f >> 3) * 16 + (l & 15);
            const int k = (f & 7) * 32 + ((l >> 4) << 3) + e;
            v = f2b(vrw1[(size_t)k * 256 + col]);
        } else if (idx < OVR2) {
            const int o = idx - ORV1, f = o >> 9, l = (o >> 3) & 63, e = o & 7;
            const int col = (f >> 3) * 16 + (l & 15);
            const int k = (f & 7) * 32 + ((l >> 4) << 3) + e;
            v = f2b(rvw1[(size_t)k * 256 + col]);
        } else if (idx < ORV2) {
            const int o = idx - OVR2, f = o >> 9, l = (o >> 3) & 63, e = o & 7;
            const int col = l & 15;
            const int k = f * 32 + ((l >> 4) << 3) + e;
            v = (col < 4) ? f2b(vrw2[(size_t)k * 4 + col]) : (ushort)0;
        } else if (idx < OFT1) {
            const int o = idx - ORV2, f = o >> 9, l = (o >> 3) & 63, e = o & 7;
            const int col = l & 15;
            const int k = f * 32 + ((l >> 4) << 3) + e;
            v = f2b(rvw2[(size_t)k * 16 + col]);
        } else if (idx < OFT2) {
            const int o = idx - OFT1, f = o >> 9, l = (o >> 3) & 63, e = o & 7;
            const int col = (f >> 3) * 16 + (l & 15);
            const int k = (f & 7) * 32 + ((l >> 4) << 3) + e;
            v = f2b(ftw1[(size_t)k * 256 + col]);
        } else if (idx < OF2T1) {
            const int o = idx - OFT2, f = o >> 9, l = (o >> 3) & 63, e = o & 7;
            const int col = (f >> 3) * 16 + (l & 15);
            const int k = (f & 7) * 32 + ((l >> 4) << 3) + e;
            v = f2b(ftw2[(size_t)k * 256 + col]);
        } else if (idx < OF2T2) {
            const int o = idx - OF2T1, f = o >> 9, l = (o >> 3) & 63, e = o & 7;
            const int col = (f >> 3) * 16 + (l & 15);
            const int k = (f & 7) * 32 + ((l >> 4) << 3) + e;
            v = f2b(f2tw1[(size_t)k * 256 + col]);
        } else if (idx < OVF1) {
            const int o = idx - OF2T2, f = o >> 9, l = (o >> 3) & 63, e = o & 7;
            const int col = (f >> 3) * 16 + (l & 15);
            const int k = (f & 7) * 32 + ((l >> 4) << 3) + e;
            v = f2b(f2tw2[(size_t)k * 128 + col]);
        } else if (idx < OVF2) {
            const int o = idx - OVF1, f = o >> 9, l = (o >> 3) & 63, e = o & 7;
            const int col = (f >> 3) * 16 + (l & 15);
            const int k = (f & 7) * 32 + ((l >> 4) << 3) + e;
            v = f2b(vfw1[(size_t)k * 256 + col]);
        } else {
            const int o = idx - OVF2, f = o >> 9, l = (o >> 3) & 63, e = o & 7;
            const int col = (f >> 3) * 16 + (l & 15);
            const int k = (f & 7) * 32 + ((l >> 4) << 3) + e;
            v = f2b(vfw2[(size_t)k * 256 + col]);
        }
        wb[idx] = v;
    } else if (bid < NB_WPREP + NB_VNB) {
        const int i = (bid - NB_WPREP) * 256 + t;
        const float4 v = *(const float4*)&vn_feat[(size_t)i * 4];
        ushort4 o;
        o.x = f2b(v.x); o.y = f2b(v.y); o.z = f2b(v.z); o.w = f2b(v.w);
        *(ushort4*)&vnb[(size_t)i * 4] = o;
    } else if (bid < NB_WPREP + NB_VNB + NB_NFS) {
        const int m0 = (bid - NB_WPREP - NB_VNB) * 32;
        const int c4 = (t & 31) * 4;
        const int rg = t >> 5;
        float acc[4][4] = {};
        for (int k0 = 0; k0 < 128; k0 += 16) {
            if (t < 128) {
                const int r = t >> 2, kk = (t & 3) * 4;
                *(float4*)&At[r][kk] =
                    *(const float4*)&node_feat[(size_t)(m0 + r) * FEAT + k0 + kk];
            }
            #pragma unroll
            for (int i = 0; i < 2; ++i) {
                const int p  = t + i * 256;
                const int wr = p >> 5, wc = (p & 31) * 4;
                *(float4*)&Wt[wr][wc] =
                    *(const float4*)&w_scalar[(size_t)(k0 + wr) * SDIM + wc];
            }
            __syncthreads();
            #pragma unroll
            for (int kk = 0; kk < 16; ++kk) {
                const float4 w = *(const float4*)&Wt[kk][c4];
                #pragma unroll
                for (int j = 0; j < 4; ++j) {
                    const float a = At[rg * 4 + j][kk];
                    acc[j][0] = fmaf(a, w.x, acc[j][0]);
                    acc[j][1] = fmaf(a, w.y, acc[j][1]);
                    acc[j][2] = fmaf(a, w.z, acc[j][2]);
                    acc[j][3] = fmaf(a, w.w, acc[j][3]);
                }
            }
            __syncthreads();
        }
        const float s = 0.08838834764831845f;
        #pragma unroll
        for (int j = 0; j < 4; ++j) {
            ushort4 o;
            o.x = f2b(acc[j][0] * s); o.y = f2b(acc[j][1] * s);
            o.z = f2b(acc[j][2] * s); o.w = f2b(acc[j][3] * s);
            *(ushort4*)&nfsb[(size_t)(m0 + rg * 4 + j) * SDIM + c4] = o;
        }
    } else {
        const int e = (bid - NB_WPREP - NB_VNB - NB_NFS) * 256 + t;
        if (e < E) atomicAdd(&cnt_i[eidx[e]], 1);
    }
}

// ---------------------------------------------------------------- scan
__global__ __launch_bounds__(1024) void k_scanA(
    const int* __restrict__ cnt_i, int* __restrict__ rowstart,
    float* __restrict__ cntf, int* __restrict__ bsum, int Nn)
{
    __shared__ int sh[1024];
    const int t = threadIdx.x;
    const int i = blockIdx.x * 1024 + t;
    const int v = (i < Nn) ? cnt_i[i] : 0;
    sh[t] = v;
    __syncthreads();
    for (int off = 1; off < 1024; off <<= 1) {
        const int add = (t >= off) ? sh[t - off] : 0;
        __syncthreads();
        sh[t] += add;
        __syncthreads();
    }
    if (i < Nn) {
        rowstart[i + 1] = sh[t];
        cntf[i] = fmaxf((float)v, 1.0f);
    }
    if (t == 1023) bsum[blockIdx.x] = sh[t];
}

__global__ __launch_bounds__(1024) void k_scanC(
    int* __restrict__ rowstart, const int* __restrict__ bsum, int Nn)
{
    __shared__ int carry_s;
    const int t = threadIdx.x;
    if (t == 0) {
        int s = 0;
        for (int b = 0; b < (int)blockIdx.x; ++b) s += bsum[b];
        carry_s = s;
    }
    __syncthreads();
    const int i = blockIdx.x * 1024 + t;
    if (i < Nn) rowstart[i + 1] += carry_s;
    if (i == 0) rowstart[0] = 0;
}

__global__ __launch_bounds__(256) void k_place(
    const int* __restrict__ eidx, const int* __restrict__ rowstart,
    int* __restrict__ cursor, int* __restrict__ elist, int E)
{
    const int e = blockIdx.x * 256 + threadIdx.x;
    if (e < E) {
        const int r = eidx[e];
        const int p = atomicAdd(&cursor[r], 1);
        elist[rowstart[r] + p] = e;
    }
}

// ---------------------------------------------------------------- k_edge
// 64 row-sorted edges/block, 512 threads = 8 waves. LDS 78.3KB -> 2 blk/CU.
// Bijective XCD swizzle: nwg=3750, q=468, r=6.
__global__ __launch_bounds__(512, 4) void k_edge(
    const ushort* __restrict__ nfsb, const ushort* __restrict__ vnb,
    const float* __restrict__ node_pos, const float* __restrict__ vn_pos,
    const int* __restrict__ eidx, const int* __restrict__ elist,
    const ushort* __restrict__ wb,
    const float* __restrict__ b1, const float* __restrict__ b2,
    const float* __restrict__ vrb1, const float* __restrict__ vrb2,
    const float* __restrict__ rvb1, const float* __restrict__ rvb2,
    float* __restrict__ agg_feat, float* __restrict__ agg_vr,
    float* __restrict__ agg_rv, int E)
{
    __shared__ ushort Mg[64 * MSTR];   // msg; later rv-hidden overlay
    __shared__ ushort Hd[64 * MSTR];   // cm hidden, then vr hidden
    __shared__ ushort ipB[64 * 16];
    __shared__ float dnS[64][12];
    __shared__ float wvrS[64][4];
    __shared__ float wrvS[64][16];
    __shared__ int rowi[64], coli[64];

    const int t  = threadIdx.x;
    // bijective XCD swizzle of blockIdx (nwg = E/64 = 3750; q=468, r=6)
    const int nwg = E / 64;
    const int q = nwg >> 3, rr8 = nwg & 7;
    const int xcd = blockIdx.x & 7, pos = blockIdx.x >> 3;
    const int bswz = (xcd < rr8 ? xcd * (q + 1) : rr8 * (q + 1) + (xcd - rr8) * q) + pos;
    const int e0 = bswz * 64;
    const int wv = t >> 6;             // 0..7
    const int lane = t & 63;
    const int lr = lane & 15;
    const int lk = lane >> 4;
    const int colBase = wv * 32;       // 2 n-tiles per wave

    // ---- geometry (t<64), row-sorted edges ----
    if (t < 64) {
        const int e = elist[e0 + t];
        const int r = eidx[e];
        const int c = eidx[E + e];
        rowi[t] = r; coli[t] = c;
        const float px = node_pos[r * 3 + 0];
        const float py = node_pos[r * 3 + 1];
        const float pz = node_pos[r * 3 + 2];
        float d[4][3];
        #pragma unroll
        for (int ch = 0; ch < 4; ++ch) {
            d[ch][0] = px - vn_pos[(size_t)c * 12 + ch * 3 + 0];
            d[ch][1] = py - vn_pos[(size_t)c * 12 + ch * 3 + 1];
            d[ch][2] = pz - vn_pos[(size_t)c * 12 + ch * 3 + 2];
        }
        float ss = 0.f, ipv[16];
        #pragma unroll
        for (int ci = 0; ci < 4; ++ci)
            #pragma unroll
            for (int ck = 0; ck < 4; ++ck) {
                const float v = d[ci][0]*d[ck][0] + d[ci][1]*d[ck][1] + d[ci][2]*d[ck][2];
                ipv[ci * 4 + ck] = v; ss += v * v;
            }
        const float inrm = rcp_f(fmaxf(sqrtf(ss), 1e-8f));
        #pragma unroll
        for (int i = 0; i < 16; ++i) ipB[t * 16 + i] = f2b(ipv[i] * inrm);
        #pragma unroll
        for (int ch = 0; ch < 4; ++ch) {
            const float nn = sqrtf(d[ch][0]*d[ch][0] + d[ch][1]*d[ch][1] + d[ch][2]*d[ch][2]);
            const float s = rcp_f(fmaxf(nn, 1e-8f));
            dnS[t][ch * 3 + 0] = d[ch][0] * s;
            dnS[t][ch * 3 + 1] = d[ch][1] * s;
            dnS[t][ch * 3 + 2] = d[ch][2] * s;
        }
    }
    __syncthreads();

    // per-lane A row pointers for cm1 (4 m-tiles)
    const ushort* nA[4]; const ushort* vA[4];
    #pragma unroll
    for (int mt = 0; mt < 4; ++mt) {
        nA[mt] = nfsb + (size_t)rowi[mt * 16 + lr] * SDIM + lk * 8;
        vA[mt] = vnb  + (size_t)coli[mt * 16 + lr] * HDIM + lk * 8;
    }
    const ushort* w1t = wb + OW1;

    f32x4 acc[4][2];

    // ===== cm layer 1 (K=416: 128 nfs | 256 vn | 16 ip | 16 zero) =====
    #pragma unroll
    for (int mt = 0; mt < 4; ++mt)
        #pragma unroll
        for (int nt = 0; nt < 2; ++nt) acc[mt][nt] = (f32x4)0.f;
    __builtin_amdgcn_s_setprio(1);
    #pragma unroll
    for (int ks = 0; ks < 13; ++ks) {
        bf16x8 a_[4];
        #pragma unroll
        for (int mt = 0; mt < 4; ++mt) {
            if (ks < 4)       a_[mt] = *(const bf16x8*)(nA[mt] + ks * 32);
            else if (ks < 12) a_[mt] = *(const bf16x8*)(vA[mt] + ks * 32 - 128);
            else if (lk < 2)  a_[mt] = *(const bf16x8*)&ipB[(mt * 16 + lr) * 16 + lk * 8];
            else              a_[mt] = (bf16x8)(short)0;
        }
        #pragma unroll
        for (int nt = 0; nt < 2; ++nt) {
            const bf16x8 b = *(const bf16x8*)&w1t[(size_t)(((wv * 2 + nt) * 13 + ks) * 512) + lane * 8];
            #pragma unroll
            for (int mt = 0; mt < 4; ++mt)
                acc[mt][nt] = __builtin_amdgcn_mfma_f32_16x16x32_bf16(a_[mt], b, acc[mt][nt], 0, 0, 0);
        }
    }
    __builtin_amdgcn_s_setprio(0);
    EPI_SILU2(Hd, b1);
    __syncthreads();

    // ===== cm layer 2 -> msg =====
    KLOOP2(Hd, wb + OW2);
    #pragma unroll
    for (int nt = 0; nt < 2; ++nt) {
        const int col = colBase + nt * 16 + lr;
        const float bb = b2[col];
        #pragma unroll
        for (int mt = 0; mt < 4; ++mt)
            #pragma unroll
            for (int r = 0; r < 4; ++r) {
                const int row = mt * 16 + lk * 4 + r;
                Mg[row * MSTR + col] = f2b(acc[mt][nt][r] + bb);
            }
    }
    __syncthreads();

    // ===== segmented reduction msg -> agg_feat (two 32-row halves) =====
    {
        const int col = t & 255;
        const int r0 = (t >> 8) * 32;
        float s = 0.f;
        int prev = rowi[r0];
        for (int r = r0; r < r0 + 32; ++r) {
            const int rr = rowi[r];
            if (rr != prev) {
                atomicAdd(&agg_feat[(size_t)prev * HDIM + col], s);
                s = 0.f; prev = rr;
            }
            s += b2f(Mg[r * MSTR + col]);
        }
        atomicAdd(&agg_feat[(size_t)prev * HDIM + col], s);
    }

    // ===== vr layer 1 (reads Mg, writes Hd) =====
    KLOOP2(Mg, wb + OVR1);
    EPI_SILU2(Hd, vrb1);

    // ===== rv layer 1 (reads Mg; barrier; epilogue overwrites Mg) =====
    KLOOP2(Mg, wb + ORV1);
    __syncthreads();                   // all Mg reads done + Hd writes visible
    #pragma unroll
    for (int nt = 0; nt < 2; ++nt) {
        const int col = colBase + nt * 16 + lr;
        const float br = rvb1[col];
        #pragma unroll
        for (int mt = 0; mt < 4; ++mt)
            #pragma unroll
            for (int r = 0; r < 4; ++r) {
                const int row = mt * 16 + lk * 4 + r;
                Mg[row * MSTR + col] = f2b(silu_f(acc[mt][nt][r] + br));  // rv hidden
            }
    }
    __syncthreads();

    // ===== vr2 (waves 0,4 from Hd) CONCURRENT with rv2 (waves 1,5 from Mg) =====
    if ((wv & 3) == 0) {
        const int rb = (wv >> 2) * 32;
        const ushort* vrw2t = wb + OVR2;
        f32x4 a2[2]; a2[0] = (f32x4)0.f; a2[1] = (f32x4)0.f;
        #pragma unroll
        for (int ks = 0; ks < 8; ++ks) {
            const bf16x8 a0 = *(const bf16x8*)&Hd[(rb + lr) * MSTR + ks * 32 + lk * 8];
            const bf16x8 a1 = *(const bf16x8*)&Hd[(rb + 16 + lr) * MSTR + ks * 32 + lk * 8];
            const bf16x8 b  = *(const bf16x8*)&vrw2t[(size_t)(ks * 512) + lane * 8];
            a2[0] = __builtin_amdgcn_mfma_f32_16x16x32_bf16(a0, b, a2[0], 0, 0, 0);
            a2[1] = __builtin_amdgcn_mfma_f32_16x16x32_bf16(a1, b, a2[1], 0, 0, 0);
        }
        if (lr < 4) {
            const float bb = vrb2[lr];
            #pragma unroll
            for (int mt = 0; mt < 2; ++mt)
                #pragma unroll
                for (int r = 0; r < 4; ++r)
                    wvrS[rb + mt * 16 + lk * 4 + r][lr] = a2[mt][r] + bb;
        }
    } else if ((wv & 3) == 1) {
        const int rb = (wv >> 2) * 32;
        const ushort* rvw2t = wb + ORV2;
        f32x4 a2[2]; a2[0] = (f32x4)0.f; a2[1] = (f32x4)0.f;
        #pragma unroll
        for (int ks = 0; ks < 8; ++ks) {
            const bf16x8 a0 = *(const bf16x8*)&Mg[(rb + lr) * MSTR + ks * 32 + lk * 8];
            const bf16x8 a1 = *(const bf16x8*)&Mg[(rb + 16 + lr) * MSTR + ks * 32 + lk * 8];
            const bf16x8 b  = *(const bf16x8*)&rvw2t[(size_t)(ks * 512) + lane * 8];
            a2[0] = __builtin_amdgcn_mfma_f32_16x16x32_bf16(a0, b, a2[0], 0, 0, 0);
            a2[1] = __builtin_amdgcn_mfma_f32_16x16x32_bf16(a1, b, a2[1], 0, 0, 0);
        }
        const float bb = rvb2[lr];
        #pragma unroll
        for (int mt = 0; mt < 2; ++mt)
            #pragma unroll
            for (int r = 0; r < 4; ++r)
                wrvS[rb + mt * 16 + lk * 4 + r][lr] = a2[mt][r] + bb;
    }
    __syncthreads();

    // ===== per-edge geometric update (t<64) =====
    if (t < 64) {
        float wvv[4], wrr[16], dn[12], ev[15];
        #pragma unroll
        for (int c = 0; c < 4; ++c)  wvv[c] = wvrS[t][c];
        #pragma unroll
        for (int i = 0; i < 16; ++i) wrr[i] = wrvS[t][i];
        #pragma unroll
        for (int i = 0; i < 12; ++i) dn[i]  = dnS[t][i];
        #pragma unroll
        for (int j = 0; j < 3; ++j) {
            float v = 0.f;
            #pragma unroll
            for (int c = 0; c < 4; ++c) v = fmaf(wvv[c], dn[c * 3 + j], v);
            ev[j] = 0.5f * v;
        }
        #pragma unroll
        for (int u = 0; u < 4; ++u)
            #pragma unroll
            for (int j = 0; j < 3; ++j) {
                float v = 0.f;
                #pragma unroll
                for (int c = 0; c < 4; ++c) v = fmaf(wrr[c * 4 + u], dn[c * 3 + j], v);
                ev[3 + u * 3 + j] = -0.5f * v;
            }
        #pragma unroll
        for (int i = 0; i < 15; ++i) wrvS[t][i] = ev[i];
    }
    __syncthreads();

    // ===== segmented reduction vr/rv (two halves) =====
    if ((t & 255) < 15) {
        const int comp = t & 255;
        const int r0 = (t >> 8) * 32;
        float s = 0.f;
        int prev = rowi[r0];
        for (int r = r0; r < r0 + 32; ++r) {
            const int rr = rowi[r];
            if (rr != prev) {
                if (comp < 3) atomicAdd(&agg_vr[(size_t)prev * 3 + comp], s);
                else          atomicAdd(&agg_rv[(size_t)prev * 12 + (comp - 3)], s);
                s = 0.f; prev = rr;
            }
            s += wrvS[r][comp];
        }
        if (comp < 3) atomicAdd(&agg_vr[(size_t)prev * 3 + comp], s);
        else          atomicAdd(&agg_rv[(size_t)prev * 12 + (comp - 3)], s);
    }
}

// ---------------------------------------------------------------- k_node
// 32 nodes/block (625 blocks), 256 threads = 4 waves (round-8 form).
__global__ __launch_bounds__(256, 4) void k_node(
    const float* __restrict__ node_feat, const float* __restrict__ node_pos,
    const float* __restrict__ vn_feat, const float* __restrict__ vn_pos,
    const float* __restrict__ agg_feat, const float* __restrict__ agg_vr,
    const float* __restrict__ agg_rv, const float* __restrict__ cntf,
    const ushort* __restrict__ wb,
    const float* __restrict__ ftb1, const float* __restrict__ ftb2,
    const float* __restrict__ f2tb1, const float* __restrict__ f2tb2,
    const float* __restrict__ vfb1, const float* __restrict__ vfb2,
    float* __restrict__ out, int Nn)
{
    __shared__ ushort Ab[32 * MSTR];
    __shared__ ushort Hd[32 * MSTR];
    __shared__ float rc[32];
    const int t  = threadIdx.x;
    const int n0 = blockIdx.x * 32;
    const int wv = t >> 6;
    const int lane = t & 63;
    const int lr = lane & 15;
    const int lk = lane >> 4;
    const int colBase = wv * 64;

    float* nf_out = out;
    float* np_out = out + (size_t)Nn * FEAT;
    float* vf_out = np_out + (size_t)Nn * 3;
    float* vp_out = vf_out + (size_t)Nn * HDIM;

    if (t < 32) rc[t] = rcp_f(fmaxf(cntf[n0 + t], 1.0f));
    __syncthreads();
    #pragma unroll
    for (int i = 0; i < 8; ++i) {
        const int p = t + i * 256;
        const int r = p >> 6, cc = (p & 63) * 4;
        float4 v = *(const float4*)&agg_feat[(size_t)(n0 + r) * HDIM + cc];
        const float s = rc[r];
        ushort4 o;
        o.x = f2b(v.x * s); o.y = f2b(v.y * s);
        o.z = f2b(v.z * s); o.w = f2b(v.w * s);
        *(ushort4*)&Ab[r * MSTR + cc] = o;
    }
    __syncthreads();

    f32x4 accn[2][4];

    // ---- vf MLP ----
    KLOOP_FR(Ab, wb + OVF1);
    EPI_SILUN(Hd, vfb1);
    __syncthreads();
    KLOOP_FR(Hd, wb + OVF2);
    #pragma unroll
    for (int nt = 0; nt < 4; ++nt) {
        const int col = colBase + nt * 16 + lr;
        const float bb = vfb2[col];
        #pragma unroll
        for (int mt = 0; mt < 2; ++mt)
            #pragma unroll
            for (int r = 0; r < 4; ++r) {
                const int row = mt * 16 + lk * 4 + r;
                const size_t o = (size_t)(n0 + row) * HDIM + col;
                vf_out[o] = vn_feat[o] + accn[mt][nt][r] + bb;
            }
    }
    __syncthreads();

    // ---- ft MLP ----
    KLOOP_FR(Ab, wb + OFT1);
    EPI_SILUN(Hd, ftb1);
    __syncthreads();
    KLOOP_FR(Hd, wb + OFT2);
    #pragma unroll
    for (int nt = 0; nt < 4; ++nt) {
        const int col = colBase + nt * 16 + lr;
        const float bb = ftb2[col];
        #pragma unroll
        for (int mt = 0; mt < 2; ++mt)
            #pragma unroll
            for (int r = 0; r < 4; ++r) {
                const int row = mt * 16 + lk * 4 + r;
                Ab[row * MSTR + col] = f2b(accn[mt][nt][r] + bb);
            }
    }
    __syncthreads();

    // ---- f2t MLP ----
    KLOOP_FR(Ab, wb + OF2T1);
    EPI_SILUN(Hd, f2tb1);
    __syncthreads();
    {
        const ushort* w2p = wb + OF2T2;
        f32x4 a2[2][2];
        #pragma unroll
        for (int mt = 0; mt < 2; ++mt)
            #pragma unroll
            for (int nt = 0; nt < 2; ++nt) a2[mt][nt] = (f32x4)0.f;
        #pragma unroll
        for (int ks = 0; ks < 8; ++ks) {
            const int k0 = ks * 32 + lk * 8;
            const bf16x8 a0 = *(const bf16x8*)&Hd[lr * MSTR + k0];
            const bf16x8 a1 = *(const bf16x8*)&Hd[(lr + 16) * MSTR + k0];
            const bf16x8 w0 = *(const bf16x8*)&w2p[(size_t)(((wv * 2 + 0) * 8 + ks) * 512) + lane * 8];
            const bf16x8 w1v = *(const bf16x8*)&w2p[(size_t)(((wv * 2 + 1) * 8 + ks) * 512) + lane * 8];
            a2[0][0] = __builtin_amdgcn_mfma_f32_16x16x32_bf16(a0, w0, a2[0][0], 0, 0, 0);
            a2[1][0] = __builtin_amdgcn_mfma_f32_16x16x32_bf16(a1, w0, a2[1][0], 0, 0, 0);
            a2[0][1] = __builtin_amdgcn_mfma_f32_16x16x32_bf16(a0, w1v, a2[0][1], 0, 0, 0);
            a2[1][1] = __builtin_amdgcn_mfma_f32_16x16x32_bf16(a1, w1v, a2[1][1], 0, 0, 0);
        }
        #pragma unroll
        for (int nt = 0; nt < 2; ++nt) {
            const int col = wv * 32 + nt * 16 + lr;
            const float bb = f2tb2[col];
            #pragma unroll
            for (int mt = 0; mt < 2; ++mt)
                #pragma unroll
                for (int r = 0; r < 4; ++r) {
                    const int row = mt * 16 + lk * 4 + r;
                    const size_t o = (size_t)(n0 + row) * FEAT + col;
                    nf_out[o] = node_feat[o] + a2[mt][nt][r] + bb;
                }
        }
    }

    // passthrough cols 128..479
    for (int p = t; p < 32 * 88; p += 256) {
        const int r = p / 88;
        const int cc = 128 + (p % 88) * 4;
        const size_t o = (size_t)(n0 + r) * FEAT + cc;
        *(float4*)&nf_out[o] = *(const float4*)&node_feat[o];
    }
    if (t < 32) {
        const int n = n0 + t;
        const float s = rc[t];
        #pragma unroll
        for (int j = 0; j < 3; ++j)
            np_out[(size_t)n * 3 + j] = node_pos[(size_t)n * 3 + j] + agg_vr[(size_t)n * 3 + j] * s;
        #pragma unroll
        for (int j = 0; j < 12; ++j)
            vp_out[(size_t)n * 12 + j] = vn_pos[(size_t)n * 12 + j] + agg_rv[(size_t)n * 12 + j] * s;
    }
}

// ---------------------------------------------------------------- launch
extern "C" void kernel_launch(void* const* d_in, const int* in_sizes, int n_in,
                              void* d_out, int out_size, void* d_ws, size_t ws_size,
                              hipStream_t stream)
{
    (void)n_in; (void)out_size; (void)ws_size;
    const float* node_feat = (const float*)d_in[0];
    const float* node_pos  = (const float*)d_in[1];
    const float* vn_feat   = (const float*)d_in[2];
    const float* vn_pos    = (const float*)d_in[3];
    const int*   eidx      = (const int*)d_in[4];
    const float* w_scalar  = (const float*)d_in[5];
    const float* cm_w1  = (const float*)d_in[6];
    const float* cm_b1  = (const float*)d_in[7];
    const float* cm_w2  = (const float*)d_in[8];
    const float* cm_b2  = (const float*)d_in[9];
    const float* vr_w1  = (const float*)d_in[10];
    const float* vr_b1  = (const float*)d_in[11];
    const float* vr_w2  = (const float*)d_in[12];
    const float* vr_b2  = (const float*)d_in[13];
    const float* rv_w1  = (const float*)d_in[14];
    const float* rv_b1  = (const float*)d_in[15];
    const float* rv_w2  = (const float*)d_in[16];
    const float* rv_b2  = (const float*)d_in[17];
    const float* ft_w1  = (const float*)d_in[18];
    const float* ft_b1  = (const float*)d_in[19];
    const float* ft_w2  = (const float*)d_in[20];
    const float* ft_b2  = (const float*)d_in[21];
    const float* f2t_w1 = (const float*)d_in[22];
    const float* f2t_b1 = (const float*)d_in[23];
    const float* f2t_w2 = (const float*)d_in[24];
    const float* f2t_b2 = (const float*)d_in[25];
    const float* vf_w1  = (const float*)d_in[26];
    const float* vf_b1  = (const float*)d_in[27];
    const float* vf_w2  = (const float*)d_in[28];
    const float* vf_b2  = (const float*)d_in[29];

    const int Nn = in_sizes[0] / FEAT;        // 20000
    const int E  = in_sizes[4] / 2;           // 240000

    // workspace layout
    float* ws       = (float*)d_ws;
    float* agg_feat = ws;                                // Nn*256 (zeroed)
    float* agg_vr   = agg_feat + (size_t)Nn * HDIM;      // Nn*3   (zeroed)
    float* agg_rv   = agg_vr   + (size_t)Nn * 3;         // Nn*12  (zeroed)
    float* cntf     = agg_rv   + (size_t)Nn * 12;        // Nn     (zeroed)
    int*   cnt_i    = (int*)(cntf + Nn);                 // Nn     (zeroed)
    int*   cursor   = cnt_i + Nn;                        // Nn     (zeroed)
    int*   rowstart = cursor + Nn;                       // Nn+8
    int*   bsum     = rowstart + Nn + 8;                 // 64
    int*   elist    = bsum + 64;                         // E
    ushort* nfsb = (ushort*)(elist + E);                 // Nn*128
    ushort* vnb  = nfsb + (size_t)Nn * SDIM;             // Nn*256
    ushort* wb   = vnb  + (size_t)Nn * HDIM;             // OWTOT

    const size_t zero_bytes = (size_t)Nn * (HDIM + 3 + 12 + 1 + 2) * sizeof(float);
    hipMemsetAsync(agg_feat, 0, zero_bytes, stream);

    const int eg = (E + 255) / 256;           // 938
    const int sb = (Nn + 1023) / 1024;        // 20 scan blocks
    k_prep<<<NB_WPREP + NB_VNB + NB_NFS + eg, 256, 0, stream>>>(
        cm_w1, cm_w2, vr_w1, rv_w1, vr_w2, rv_w2,
        ft_w1, ft_w2, f2t_w1, f2t_w2, vf_w1, vf_w2, wb,
        vn_feat, vnb, node_feat, w_scalar, nfsb,
        eidx, cnt_i, E);
    k_scanA<<<sb, 1024, 0, stream>>>(cnt_i, rowstart, cntf, bsum, Nn);
    k_scanC<<<sb, 1024, 0, stream>>>(rowstart, bsum, Nn);
    k_place<<<eg, 256, 0, stream>>>(eidx, rowstart, cursor, elist, E);
    k_edge<<<E / 64, 512, 0, stream>>>(nfsb, vnb, node_pos, vn_pos, eidx, elist,
                                       wb, cm_b1, cm_b2, vr_b1, vr_b2, rv_b1, rv_b2,
                                       agg_feat, agg_vr, agg_rv, E);
    k_node<<<Nn / 32, 256, 0, stream>>>(node_feat, node_pos, vn_feat, vn_pos,
                                        agg_feat, agg_vr, agg_rv, cntf, wb,
                                        ft_b1, ft_b2, f2t_b1, f2t_b2, vf_b1, vf_b2,
                                        (float*)d_out, Nn);
}